// Round 14
// baseline (293.089 us; speedup 1.0000x reference)
//
#include <hip/hip_runtime.h>
#include <math.h>

#define DEVI __device__ __forceinline__

typedef __attribute__((ext_vector_type(4))) float f32x4;
typedef __attribute__((ext_vector_type(8))) short bf16x8;

// ---------- helpers ----------
DEVI short f2bf(float f) {                    // f32 -> bf16 (RNE)
    union { float f; unsigned u; } v; v.f = f;
    unsigned r = v.u + 0x7fffu + ((v.u >> 16) & 1u);
    return (short)(r >> 16);
}
DEVI float bf2f(short s) {
    union { unsigned u; float f; } v; v.u = ((unsigned)(unsigned short)s) << 16;
    return v.f;
}

DEVI f32x4 mfma16(bf16x8 a, bf16x8 b, f32x4 c) {
    return __builtin_amdgcn_mfma_f32_16x16x32_bf16(a, b, c, 0, 0, 0);
}

DEVI void gload16(const short* g, short* l) {  // async global->LDS, 16B/lane
    __builtin_amdgcn_global_load_lds((__attribute__((address_space(1))) void*)(g),
                                     (__attribute__((address_space(3))) void*)(l),
                                     16, 0, 0);
}

// ---------- merged preprocessing: cvt + freqs + all 7 weight transposes ----------
DEVI void trans_tile(const float* in, short* out, int R, int C, int Rpad, int Cpad,
                     int rmul, int radd, int bx, int by) {
    __shared__ float tile[32][33];
    int c0 = bx * 32, r0 = by * 32;
    int tx = threadIdx.x & 31, ty = threadIdx.x >> 5;
#pragma unroll
    for (int i = 0; i < 4; i++) {
        int r = r0 + ty + 8 * i, c = c0 + tx;
        tile[ty + 8 * i][tx] = (r < R && c < C) ? in[(size_t)r * C + c] : 0.0f;
    }
    __syncthreads();
#pragma unroll
    for (int i = 0; i < 4; i++) {
        int oc = c0 + ty + 8 * i;
        int orr = r0 + tx;
        if (oc < Cpad && orr < Rpad)
            out[(size_t)(oc * rmul + radd) * Rpad + orr] = f2bf(tile[tx][ty + 8 * i]);
    }
}

__global__ void k_prep(const float* __restrict__ x, short* __restrict__ xbf,
                       float* __restrict__ cost, float* __restrict__ sint,
                       const float* __restrict__ Wq, const float* __restrict__ Wk,
                       const float* __restrict__ Wv, const float* __restrict__ Wo,
                       const float* __restrict__ Wup, const float* __restrict__ Wg,
                       const float* __restrict__ Wd,
                       short* __restrict__ wqkvT, short* __restrict__ woT,
                       short* __restrict__ wugT, short* __restrict__ wdownT) {
    int b = blockIdx.x;
    if (b < 4096) {                         // x f32 -> bf16
        int i = (b * 256 + threadIdx.x) * 4;
        float4 v = *(const float4*)(x + i);
        short4 o;
        o.x = f2bf(v.x); o.y = f2bf(v.y); o.z = f2bf(v.z); o.w = f2bf(v.w);
        *(short4*)(xbf + i) = o;
    } else if (b < 4352) {                  // rope tables (f64 fidelity)
        int i = (b - 4096) * 256 + threadIdx.x;
        int s = i >> 5, j = i & 31;
        double inv = pow(10000.0, -(double)j / 32.0);
        double f = (double)s * inv;
        cost[i] = (float)cos(f);
        sint[i] = (float)sin(f);
    } else {
        int bb = b - 4352;
        if (bb < 4096) {                    // Wq/Wk/Wv/Wo
            int seg = bb >> 10, idx = bb & 1023;
            const float* in = seg == 0 ? Wq : seg == 1 ? Wk : seg == 2 ? Wv : Wo;
            short* out = seg == 0 ? wqkvT : seg == 1 ? wqkvT + 1048576
                       : seg == 2 ? wqkvT + 2097152 : woT;
            trans_tile(in, out, 1024, 1024, 1024, 1024, 1, 0, idx & 31, idx >> 5);
        } else if (bb < 9600) {             // Wup/Wg -> interleaved [5504][1024]
            int idx = bb - 4096;
            int seg = idx >= 2752;
            idx -= seg * 2752;
            trans_tile(seg ? Wg : Wup, wugT, 1024, 2730, 1024, 2752, 2, seg, idx % 86, idx / 86);
        } else {                            // Wd -> [1024][2752]
            int idx = bb - 9600;
            trans_tile(Wd, wdownT, 2730, 1024, 2752, 1024, 1, 0, idx & 31, idx >> 5);
        }
    }
}

// ---------- GEMM 128x128x32: 3-buffer ring, counted vmcnt (T4), bank-swizzled ----------
// Pipeline: stage tile t+2 each iter; wait `vmcnt(4)` (tile t resident, t+1/t+2 in
// flight ACROSS the raw s_barrier), vmcnt(0) only at the last iter. Buffer (t+2)%3 was
// last read at iter t-1 (pre-barrier) -> WAR safe. Swizzle: row r, chunk c at c^((r>>1)&3),
// both-sides. EPI: 0 f32, 1 bf16 (honor nsplit=2 -> Cv1), 2 SwiGLU-interleaved,
// 3 fused QKV epilogue. Grid 1D, gridDim.x % 8 == 0.
template <int EPI>
__launch_bounds__(256)
__global__ void k_gemm128(const short* __restrict__ A, const short* __restrict__ BT,
                          void* __restrict__ Cv, void* __restrict__ Cv1,
                          int M, int N, int K, int nkblk, int nsplit,
                          const float* __restrict__ s_u, const float* __restrict__ s_v,
                          const float* __restrict__ cost, const float* __restrict__ sint,
                          const float* __restrict__ sqk,
                          short* __restrict__ qn, short* __restrict__ kn,
                          short* __restrict__ vraw) {
    __shared__ __align__(16) short As[3 * 128 * 32];
    __shared__ __align__(16) short Bs[3 * 128 * 32];
    const int t = threadIdx.x;
    const int w = t >> 6;
    const int lane = t & 63;
    const int lr = lane & 15, lg = lane >> 4;
    const int nwg = (int)gridDim.x;
    int wg = ((int)blockIdx.x & 7) * (nwg >> 3) + ((int)blockIdx.x >> 3);
    int half = 0;
    if (nsplit == 2) {
        const int per = nwg >> 1;
        half = wg >= per;
        wg -= half * per;
    }
    const int MT = M >> 7;
    const int m0 = (wg % MT) << 7;
    const int n0 = (wg / MT) << 7;
    const int koff = half * nkblk * 32;
    const int wr = (w >> 1) * 64, wc = (w & 1) * 64;

    const int srow = t >> 2;
    const int scol = (((t & 3) ^ ((srow >> 1) & 3)) << 3);
    const short* Ap0 = A + (size_t)(m0 + srow) * K + koff + scol;
    const short* Ap1 = Ap0 + (size_t)64 * K;
    const short* Bp0 = BT + (size_t)(n0 + srow) * K + koff + scol;
    const short* Bp1 = Bp0 + (size_t)64 * K;
    const int d0 = (w * 64) * 8;
    const int d1 = (w * 64 + 256) * 8;

#define STAGE(bo)                                                     \
    {                                                                 \
        gload16(Ap0, As + (bo) + d0); gload16(Ap1, As + (bo) + d1);   \
        gload16(Bp0, Bs + (bo) + d0); gload16(Bp1, Bs + (bo) + d1);   \
        Ap0 += 32; Ap1 += 32; Bp0 += 32; Bp1 += 32;                   \
    }

    f32x4 acc[4][4];
#pragma unroll
    for (int m = 0; m < 4; m++)
#pragma unroll
        for (int n = 0; n < 4; n++)
            acc[m][n] = (f32x4){0.f, 0.f, 0.f, 0.f};

    // prologue: tiles 0 and 1 into buffers 0,1 (8 loads in flight)
    STAGE(0);
    if (nkblk > 1) STAGE(4096);

    int bcur = 0;                       // buffer (shorts offset / 4096) of tile kt
    for (int kt = 0; kt < nkblk; kt++) {
        if (kt + 1 < nkblk) {           // tile t done; t+1 (and t+2) stay in flight
            asm volatile("s_waitcnt vmcnt(4)" ::: "memory");
        } else {
            asm volatile("s_waitcnt vmcnt(0)" ::: "memory");
        }
        __builtin_amdgcn_sched_barrier(0);
        __builtin_amdgcn_s_barrier();
        if (kt + 2 < nkblk) {
            int bn = bcur + 2; if (bn >= 3) bn -= 3;
            STAGE(bn * 4096);
        }
        const short* asb = As + bcur * 4096;
        const short* bsb = Bs + bcur * 4096;
        bf16x8 af[4], bfr[4];
#pragma unroll
        for (int m = 0; m < 4; m++) {
            int rml = wr + m * 16 + lr;
            af[m] = *(const bf16x8*)&asb[rml * 32 + ((lg ^ ((rml >> 1) & 3)) << 3)];
        }
#pragma unroll
        for (int n = 0; n < 4; n++) {
            int rnl = wc + n * 16 + lr;
            bfr[n] = *(const bf16x8*)&bsb[rnl * 32 + ((lg ^ ((rnl >> 1) & 3)) << 3)];
        }
#pragma unroll
        for (int m = 0; m < 4; m++)
#pragma unroll
            for (int n = 0; n < 4; n++)
                acc[m][n] = mfma16(af[m], bfr[n], acc[m][n]);
        bcur = bcur == 2 ? 0 : bcur + 1;
    }
#undef STAGE

    if (EPI == 3) {
        const int sector = n0 >> 10;     // 0=q, 1=k, 2=v
        if (sector == 2) {
#pragma unroll
            for (int m = 0; m < 4; m++)
#pragma unroll
                for (int n = 0; n < 4; n++) {
                    int col = n0 + wc + n * 16 + lr - 2048;
                    int row = m0 + wr + m * 16 + lg * 4;
#pragma unroll
                    for (int i = 0; i < 4; i++)
                        vraw[(size_t)(row + i) * 1024 + col] = f2bf(acc[m][n][i]);
                }
        } else {
            const int h = ((n0 + wc) >> 6) & 15;
            float eff[4];
#pragma unroll
            for (int n = 0; n < 4; n++)
                eff[n] = sqk[h * 64 + n * 16 + lr] * 32.0f;   // s_qk * sqrt(DIM)
            short* dst = (sector == 0) ? qn : kn;
            const float extra = (sector == 0) ? 8.0f : 1.0f;  // sqrt(HD) folded into q
#pragma unroll
            for (int m = 0; m < 4; m++)
#pragma unroll
                for (int i = 0; i < 4; i++) {
                    int row = m0 + wr + m * 16 + lg * 4 + i;
                    int b = row >> 11, s = row & 2047;
                    float cs0 = cost[s * 32 + lr],      sn0 = sint[s * 32 + lr];
                    float cs1 = cost[s * 32 + 16 + lr], sn1 = sint[s * 32 + 16 + lr];
                    float vr0 = acc[m][0][i] * cs0 - acc[m][2][i] * sn0;
                    float vr1 = acc[m][1][i] * cs1 - acc[m][3][i] * sn1;
                    float vr2 = acc[m][2][i] * cs0 + acc[m][0][i] * sn0;
                    float vr3 = acc[m][3][i] * cs1 + acc[m][1][i] * sn1;
                    float ss = vr0 * vr0 + vr1 * vr1 + vr2 * vr2 + vr3 * vr3;
#pragma unroll
                    for (int o = 1; o < 16; o <<= 1)
                        ss += __shfl_xor(ss, o, 64);
                    float sc = extra / fmaxf(sqrtf(ss), 1e-6f);
                    size_t base = ((size_t)(b * 16 + h) * 2048 + s) * 64;
                    dst[base + lr]      = f2bf(vr0 * eff[0] * sc);
                    dst[base + 16 + lr] = f2bf(vr1 * eff[1] * sc);
                    dst[base + 32 + lr] = f2bf(vr2 * eff[2] * sc);
                    dst[base + 48 + lr] = f2bf(vr3 * eff[3] * sc);
                }
        }
        return;
    }

#pragma unroll
    for (int m = 0; m < 4; m++)
#pragma unroll
        for (int n = 0; n < 4; n++) {
            int row = m0 + wr + m * 16 + lg * 4;
            int col = n0 + wc + n * 16 + lr;
            if (EPI == 2) {
                int j = col >> 1;
                int jc = j < 2730 ? j : 2729;
                float su = s_u[jc];
                float sg = s_v[jc] * 32.0f;
#pragma unroll
                for (int i = 0; i < 4; i++) {
                    float own = acc[m][n][i];
                    float oth = __shfl_xor(own, 1, 64);
                    float u = (lr & 1) ? oth : own;
                    float g = (lr & 1) ? own : oth;
                    float uu = u * su;
                    float vv = g * sg;
                    float wv = uu * vv / (1.0f + expf(-vv));
                    if (!(lr & 1))
                        ((short*)Cv)[(size_t)(row + i) * (N >> 1) + j] = f2bf(wv);
                }
            } else {
                void* outp = half ? Cv1 : Cv;
#pragma unroll
                for (int i = 0; i < 4; i++) {
                    if (EPI == 1)
                        ((short*)outp)[(size_t)(row + i) * N + col] = f2bf(acc[m][n][i]);
                    else
                        ((float*)outp)[(size_t)(row + i) * N + col] = acc[m][n][i];
                }
            }
        }
}

// ---------- V transpose: vraw bf16 [4096][1024] -> vt bf16 [B][H][64][2048] ----------
__global__ void k_vtrans(const short* __restrict__ vraw, short* __restrict__ vt) {
    __shared__ short tile[64][72];
    int blk = blockIdx.x;
    int st = blk & 31, h = (blk >> 5) & 15, b = blk >> 9;
    int s0 = st * 64;
    int t = threadIdx.x;
    int sl = t >> 2, c0 = (t & 3) * 16;
    const short* src = vraw + (size_t)(b * 2048 + s0 + sl) * 1024 + h * 64 + c0;
    bf16x8 a0 = *(const bf16x8*)src;
    bf16x8 a1 = *(const bf16x8*)(src + 8);
#pragma unroll
    for (int jj = 0; jj < 8; jj++) { tile[sl][c0 + jj] = a0[jj]; tile[sl][c0 + 8 + jj] = a1[jj]; }
    __syncthreads();
    int hd = t >> 2, sc = (t & 3) * 16;
    bf16x8 p0, p1;
#pragma unroll
    for (int jj = 0; jj < 8; jj++) { p0[jj] = tile[sc + jj][hd]; p1[jj] = tile[sc + 8 + jj][hd]; }
    size_t obase = ((size_t)((b * 16 + h) * 64 + hd)) * 2048 + s0 + sc;
    *(bf16x8*)&vt[obase] = p0;
    *(bf16x8*)&vt[obase + 8] = p1;
}

// ---------- flash attention (causal), static-max softmax, balanced pair split ----------
__launch_bounds__(512)
__global__ void k_attn(const short* __restrict__ qn, const short* __restrict__ kn,
                       const short* __restrict__ vt, short* __restrict__ opart,
                       float* __restrict__ lsump) {
    __shared__ __align__(16) short Ks[2][64 * 64];
    __shared__ __align__(16) short Vs[2][64 * 64];
    __shared__ __align__(16) short Ps[8][32 * 64];
    const int t = threadIdx.x;
    const int w = t >> 6, lane = t & 63;
    const int bid = blockIdx.x;
    const int xcd = bid & 7, idx = bid >> 3;
    const int bhg = xcd + ((idx >> 3) << 3);          // 0..31
    const int pslot = idx & 7;
    const int h = bhg & 15, b = bhg >> 4;
    const int bh = b * 16 + h;
    const int lr = lane & 15, lg = lane >> 4;
    const short* Qb = qn + (size_t)bh * 2048 * 64;
    const short* Kb = kn + (size_t)bh * 2048 * 64;
    const short* Vb = vt + (size_t)bh * 64 * 2048;
    char* pwc = (char*)&Ps[w][0];

#define STAGE_KV(bi, kbase)                                                          \
    {                                                                                \
        int row = w * 8 + (lane >> 3);                                               \
        int scol = (lane & 7) ^ (row & 7);                                           \
        gload16(Kb + (size_t)((kbase) + row) * 64 + scol * 8,                        \
                &Ks[bi][(w * 8) * 64]);                                              \
        gload16(Vb + (size_t)row * 2048 + (kbase) + scol * 8,                        \
                &Vs[bi][(w * 8) * 64]);                                              \
    }

    for (int pc = 0; pc < 2; pc++) {
        const int qb = pc == 0 ? pslot : 7 - pslot;
        const int hf = pc;
        const int ktn = 2 * qb + 2;
        const int kt0 = hf * ktn, kt1 = kt0 + ktn;
        const int qw = qb * 256 + w * 32;

        bf16x8 qf[2][2];
#pragma unroll
        for (int mi = 0; mi < 2; mi++)
#pragma unroll
            for (int kk = 0; kk < 2; kk++)
                qf[mi][kk] = *(const bf16x8*)&Qb[(size_t)(qw + mi * 16 + lr) * 64 + kk * 32 + lg * 8];

        f32x4 oacc[2][4];
#pragma unroll
        for (int mi = 0; mi < 2; mi++)
#pragma unroll
            for (int ct = 0; ct < 4; ct++) oacc[mi][ct] = (f32x4){0.f, 0.f, 0.f, 0.f};
        float psum[2][4];
#pragma unroll
        for (int mi = 0; mi < 2; mi++)
#pragma unroll
            for (int i = 0; i < 4; i++) psum[mi][i] = 0.0f;

        if (pc) __syncthreads();          // all waves done with piece-0 LDS
        STAGE_KV(0, kt0 << 6);

        for (int kt = kt0; kt < kt1; kt++) {
            const int kbase = kt << 6;
            const int cur = (kt - kt0) & 1;
            __syncthreads();
            if (kt + 1 < kt1) STAGE_KV(cur ^ 1, (kt + 1) << 6);

            bf16x8 kf[4][2];
#pragma unroll
            for (int ni = 0; ni < 4; ni++)
#pragma unroll
                for (int kk = 0; kk < 2; kk++) {
                    int row = ni * 16 + lr;
                    kf[ni][kk] = *(const bf16x8*)&Ks[cur][row * 64 + (((kk * 4 + lg) ^ (row & 7)) << 3)];
                }
            f32x4 sv[2][4];
#pragma unroll
            for (int mi = 0; mi < 2; mi++)
#pragma unroll
                for (int ni = 0; ni < 4; ni++) {
                    f32x4 s = (f32x4){0.f, 0.f, 0.f, 0.f};
                    s = mfma16(qf[mi][0], kf[ni][0], s);
                    s = mfma16(qf[mi][1], kf[ni][1], s);
                    sv[mi][ni] = s;
                }
            if (kbase + 63 > qw) {
#pragma unroll
                for (int mi = 0; mi < 2; mi++)
#pragma unroll
                    for (int ni = 0; ni < 4; ni++)
#pragma unroll
                        for (int i = 0; i < 4; i++) {
                            int qg = qw + mi * 16 + lg * 4 + i;
                            int kg = kbase + ni * 16 + lr;
                            if (kg > qg) sv[mi][ni][i] = -3.0e38f;
                        }
            }
#pragma unroll
            for (int mi = 0; mi < 2; mi++) {
#pragma unroll
                for (int ni = 0; ni < 4; ni++)
#pragma unroll
                    for (int i = 0; i < 4; i++) {
                        float p = exp2f((sv[mi][ni][i] - 9.0f) * 1.44269504f);
                        sv[mi][ni][i] = p;
                        psum[mi][i] += p;
                    }
#pragma unroll
                for (int ni = 0; ni < 4; ni++)
#pragma unroll
                    for (int i = 0; i < 4; i++) {
                        int row = mi * 16 + lg * 4 + i;
                        int col = ni * 16 + lr;
                        unsigned off = (unsigned)(row * 128 + col * 2) ^ ((unsigned)(row & 7) << 4);
                        *(short*)(pwc + off) = f2bf(sv[mi][ni][i]);
                    }
            }
            bf16x8 pa[2][2];
#pragma unroll
            for (int mi = 0; mi < 2; mi++)
#pragma unroll
                for (int kk = 0; kk < 2; kk++) {
                    int row = mi * 16 + lr;
                    unsigned off = (unsigned)(row * 128 + kk * 64 + lg * 16) ^ ((unsigned)(row & 7) << 4);
                    pa[mi][kk] = *(const bf16x8*)(pwc + off);
                }
            bf16x8 vf[4][2];
#pragma unroll
            for (int ct = 0; ct < 4; ct++)
#pragma unroll
                for (int kk = 0; kk < 2; kk++) {
                    int row = ct * 16 + lr;
                    vf[ct][kk] = *(const bf16x8*)&Vs[cur][row * 64 + (((kk * 4 + lg) ^ (row & 7)) << 3)];
                }
#pragma unroll
            for (int mi = 0; mi < 2; mi++)
#pragma unroll
                for (int ct = 0; ct < 4; ct++) {
                    oacc[mi][ct] = mfma16(pa[mi][0], vf[ct][0], oacc[mi][ct]);
                    oacc[mi][ct] = mfma16(pa[mi][1], vf[ct][1], oacc[mi][ct]);
                }
        }

#pragma unroll
        for (int o = 1; o < 16; o <<= 1)
#pragma unroll
            for (int mi = 0; mi < 2; mi++)
#pragma unroll
                for (int i = 0; i < 4; i++)
                    psum[mi][i] += __shfl_xor(psum[mi][i], o, 64);

        short* aob = opart + (size_t)hf * 4096 * 1024 + ((size_t)(b * 2048 + qw) * 1024) + h * 64;
#pragma unroll
        for (int mi = 0; mi < 2; mi++)
#pragma unroll
            for (int ct = 0; ct < 4; ct++)
#pragma unroll
                for (int i = 0; i < 4; i++) {
                    int q = mi * 16 + lg * 4 + i;
                    aob[(size_t)q * 1024 + ct * 16 + lr] = f2bf(oacc[mi][ct][i]);
                }
        if (lr == 0) {
#pragma unroll
            for (int mi = 0; mi < 2; mi++)
#pragma unroll
                for (int i = 0; i < 4; i++)
                    lsump[hf * 65536 + bh * 2048 + qw + mi * 16 + lg * 4 + i] = psum[mi][i];
        }
    }
#undef STAGE_KV
}

// ---------- combine split-K partials: ao = (O0+O1)/(l0+l1), bf16 ----------
__global__ void k_comb(const short* __restrict__ op, const float* __restrict__ ls,
                       short* __restrict__ ao) {
    int i = (blockIdx.x * 256 + threadIdx.x) * 4;
    int row = i >> 10, col = i & 1023;
    int idx = ((row >> 11) * 16 + (col >> 6)) * 2048 + (row & 2047);
    float rl = 1.0f / (ls[idx] + ls[65536 + idx]);
    short4 a = *(const short4*)(op + i);
    short4 c = *(const short4*)(op + 4194304 + i);
    short4 o;
    o.x = f2bf((bf2f(a.x) + bf2f(c.x)) * rl);
    o.y = f2bf((bf2f(a.y) + bf2f(c.y)) * rl);
    o.z = f2bf((bf2f(a.z) + bf2f(c.z)) * rl);
    o.w = f2bf((bf2f(a.w) + bf2f(c.w)) * rl);
    *(short4*)(ao + i) = o;
}

// ---------- residual + double cosine_norm; pre = pre0 + pre1 ----------
// PM: 1 = two f32 partials, 2 = two bf16 partials. base/outf may alias.
template <int PM>
__global__ void k_resnorm(const float* base, const void* __restrict__ pre0v,
                          const void* __restrict__ pre1v,
                          const float* __restrict__ alpha, float* outf,
                          short* __restrict__ outb) {
    __shared__ float red1[4], red2[4];
    int row = blockIdx.x;
    int t = threadIdx.x;
    int w = t >> 6;
    float4 p;
    if (PM == 1) {
        float4 a = *(const float4*)((const float*)pre0v + (size_t)row * 1024 + t * 4);
        float4 c = *(const float4*)((const float*)pre1v + (size_t)row * 1024 + t * 4);
        p.x = a.x + c.x; p.y = a.y + c.y; p.z = a.z + c.z; p.w = a.w + c.w;
    } else {
        short4 a = *(const short4*)((const short*)pre0v + (size_t)row * 1024 + t * 4);
        short4 c = *(const short4*)((const short*)pre1v + (size_t)row * 1024 + t * 4);
        p.x = bf2f(a.x) + bf2f(c.x); p.y = bf2f(a.y) + bf2f(c.y);
        p.z = bf2f(a.z) + bf2f(c.z); p.w = bf2f(a.w) + bf2f(c.w);
    }
    float ss = p.x * p.x + p.y * p.y + p.z * p.z + p.w * p.w;
#pragma unroll
    for (int o = 1; o < 64; o <<= 1) ss += __shfl_xor(ss, o, 64);
    if ((t & 63) == 0) red1[w] = ss;
    __syncthreads();
    float inv1 = 1.0f / fmaxf(sqrtf(red1[0] + red1[1] + red1[2] + red1[3]), 1e-6f);
    const float4 bx = *(const float4*)(base + (size_t)row * 1024 + t * 4);
    const float4 av = *(const float4*)(alpha + t * 4);
    float4 tm;
    tm.x = bx.x + av.x * (p.x * inv1 - bx.x);
    tm.y = bx.y + av.y * (p.y * inv1 - bx.y);
    tm.z = bx.z + av.z * (p.z * inv1 - bx.z);
    tm.w = bx.w + av.w * (p.w * inv1 - bx.w);
    float ss2 = tm.x * tm.x + tm.y * tm.y + tm.z * tm.z + tm.w * tm.w;
#pragma unroll
    for (int o = 1; o < 64; o <<= 1) ss2 += __shfl_xor(ss2, o, 64);
    if ((t & 63) == 0) red2[w] = ss2;
    __syncthreads();
    float inv2 = 1.0f / fmaxf(sqrtf(red2[0] + red2[1] + red2[2] + red2[3]), 1e-6f);
    float4 hv;
    hv.x = tm.x * inv2; hv.y = tm.y * inv2; hv.z = tm.z * inv2; hv.w = tm.w * inv2;
    if (outf) *(float4*)(outf + (size_t)row * 1024 + t * 4) = hv;
    if (outb) {
        short4 o4;
        o4.x = f2bf(hv.x); o4.y = f2bf(hv.y); o4.z = f2bf(hv.z); o4.w = f2bf(hv.w);
        *(short4*)(outb + (size_t)row * 1024 + t * 4) = o4;
    }
}

// ---------- launch ----------
// Workspace (lifetime-overlaid, peak 76,152,832 B = known-safe):
//  [0, 25821184)  weights bf16^T + rope tables                       (whole launch)
//  25821184  xbf(prep->qkv) -> vt(vtrans->attn) -> h1bf(rn1->swiglu)           8 MB
//  34209792  qn(qkv->attn) -> ao(comb->wo) -> wmlp(swiglu->down, 22.5MB)
//  42598400  kn(qkv->attn) -> hA0 f32(wo->rn1, 16MB)
//  50987008  vraw(qkv->vtrans) -> lsum(attn->comb, 0.5MB)
//  59375616  opart[2] bf16 16MB(attn->comb) -> hA1 f32 16MB(wo->rn1) -> hM0 bf16 8MB
//  67764224  hM1 bf16 8MB(down->rn2)
extern "C" void kernel_launch(void* const* d_in, const int* in_sizes, int n_in,
                              void* d_out, int out_size, void* d_ws, size_t ws_size,
                              hipStream_t stream) {
    (void)in_sizes; (void)n_in; (void)out_size; (void)ws_size;
    const float* x   = (const float*)d_in[0];
    const float* Wq  = (const float*)d_in[1];
    const float* Wk  = (const float*)d_in[2];
    const float* Wv  = (const float*)d_in[3];
    const float* Wo  = (const float*)d_in[4];
    const float* sqk = (const float*)d_in[5];
    const float* aA  = (const float*)d_in[6];
    const float* Wup = (const float*)d_in[7];
    const float* Wg  = (const float*)d_in[8];
    const float* Wd  = (const float*)d_in[9];
    const float* su  = (const float*)d_in[10];
    const float* sv  = (const float*)d_in[11];
    const float* aM  = (const float*)d_in[12];

    char* ws = (char*)d_ws;
    short* wqkvT  = (short*)(ws + 0);          // [3072][1024]
    short* woT    = (short*)(ws + 6291456);    // [1024][1024]
    short* wugT   = (short*)(ws + 8388608);    // [5504][1024] interleaved up/gate
    short* wdownT = (short*)(ws + 19660800);   // [1024][2752]
    float* cost   = (float*)(ws + 25296896);
    float* sint   = (float*)(ws + 25559040);
    short* xbf    = (short*)(ws + 25821184);
    short* qn     = (short*)(ws + 34209792);
    short* kn     = (short*)(ws + 42598400);
    short* vraw   = (short*)(ws + 50987008);   // [4096][1024] bf16
    short* vt     = (short*)(ws + 25821184);   // reuse xbf
    short* opart  = (short*)(ws + 59375616);   // [2][4096][1024] bf16
    float* lsum   = (float*)(ws + 50987008);   // reuse vraw (dead after vtrans)
    short* ao     = (short*)(ws + 34209792);   // reuse qn
    float* hA0    = (float*)(ws + 42598400);   // reuse kn, 16MB
    float* hA1    = (float*)(ws + 59375616);   // reuse opart, 16MB
    float* h1f    = (float*)d_out;
    short* h1bf   = (short*)(ws + 25821184);   // reuse vt
    short* wmlp   = (short*)(ws + 34209792);   // [4096][2752] bf16
    short* hM0    = (short*)(ws + 59375616);   // bf16 8MB
    short* hM1    = (short*)(ws + 67764224);   // bf16 8MB

    k_prep<<<16704, 256, 0, stream>>>(x, xbf, cost, sint, Wq, Wk, Wv, Wo, Wup, Wg, Wd,
                                      wqkvT, woT, wugT, wdownT);

    // QKV GEMM with fused rope + cosine-norm epilogue
    k_gemm128<3><<<768, 256, 0, stream>>>(xbf, wqkvT, nullptr, nullptr, 4096, 3072, 1024,
                                          32, 1, nullptr, nullptr, cost, sint, sqk, qn, kn, vraw);
    k_vtrans<<<1024, 256, 0, stream>>>(vraw, vt);
    k_attn<<<256, 512, 0, stream>>>(qn, kn, vt, opart, lsum);
    k_comb<<<4096, 256, 0, stream>>>(opart, lsum, ao);
    // Wo: split-K x2, f32 partials
    k_gemm128<0><<<512, 256, 0, stream>>>(ao, woT, hA0, hA1, 4096, 1024, 1024,
                                          16, 2, nullptr, nullptr, nullptr, nullptr, nullptr,
                                          nullptr, nullptr, nullptr);
    k_resnorm<1><<<4096, 256, 0, stream>>>(x, hA0, hA1, aA, h1f, h1bf);
    // up+gate fused SwiGLU
    k_gemm128<2><<<1376, 256, 0, stream>>>(h1bf, wugT, wmlp, nullptr, 4096, 5504, 1024,
                                           32, 1, su, sv, nullptr, nullptr, nullptr,
                                           nullptr, nullptr, nullptr);
    // down: split-K x2, bf16 partials
    k_gemm128<1><<<512, 256, 0, stream>>>(wmlp, wdownT, hM0, hM1, 4096, 1024, 2752,
                                          43, 2, nullptr, nullptr, nullptr, nullptr, nullptr,
                                          nullptr, nullptr, nullptr);
    k_resnorm<2><<<4096, 256, 0, stream>>>(h1f, hM0, hM1, aM, (float*)d_out, (short*)nullptr);
}

// Round 15
// 279.018 us; speedup vs baseline: 1.0504x; 1.0504x over previous
//
#include <hip/hip_runtime.h>
#include <math.h>

#define DEVI __device__ __forceinline__

typedef __attribute__((ext_vector_type(4))) float f32x4;
typedef __attribute__((ext_vector_type(8))) short bf16x8;

// ---------- helpers ----------
DEVI short f2bf(float f) {                    // f32 -> bf16 (RNE)
    union { float f; unsigned u; } v; v.f = f;
    unsigned r = v.u + 0x7fffu + ((v.u >> 16) & 1u);
    return (short)(r >> 16);
}
DEVI float bf2f(short s) {
    union { unsigned u; float f; } v; v.u = ((unsigned)(unsigned short)s) << 16;
    return v.f;
}

DEVI f32x4 mfma16(bf16x8 a, bf16x8 b, f32x4 c) {
    return __builtin_amdgcn_mfma_f32_16x16x32_bf16(a, b, c, 0, 0, 0);
}

DEVI void gload16(const short* g, short* l) {  // async global->LDS, 16B/lane
    __builtin_amdgcn_global_load_lds((__attribute__((address_space(1))) void*)(g),
                                     (__attribute__((address_space(3))) void*)(l),
                                     16, 0, 0);
}

// ---------- merged preprocessing: cvt + freqs + all 7 weight transposes ----------
DEVI void trans_tile(const float* in, short* out, int R, int C, int Rpad, int Cpad,
                     int rmul, int radd, int bx, int by) {
    __shared__ float tile[32][33];
    int c0 = bx * 32, r0 = by * 32;
    int tx = threadIdx.x & 31, ty = threadIdx.x >> 5;
#pragma unroll
    for (int i = 0; i < 4; i++) {
        int r = r0 + ty + 8 * i, c = c0 + tx;
        tile[ty + 8 * i][tx] = (r < R && c < C) ? in[(size_t)r * C + c] : 0.0f;
    }
    __syncthreads();
#pragma unroll
    for (int i = 0; i < 4; i++) {
        int oc = c0 + ty + 8 * i;
        int orr = r0 + tx;
        if (oc < Cpad && orr < Rpad)
            out[(size_t)(oc * rmul + radd) * Rpad + orr] = f2bf(tile[tx][ty + 8 * i]);
    }
}

__global__ void k_prep(const float* __restrict__ x, short* __restrict__ xbf,
                       float* __restrict__ cost, float* __restrict__ sint,
                       const float* __restrict__ Wq, const float* __restrict__ Wk,
                       const float* __restrict__ Wv, const float* __restrict__ Wo,
                       const float* __restrict__ Wup, const float* __restrict__ Wg,
                       const float* __restrict__ Wd,
                       short* __restrict__ wqkvT, short* __restrict__ woT,
                       short* __restrict__ wugT, short* __restrict__ wdownT) {
    int b = blockIdx.x;
    if (b < 4096) {                         // x f32 -> bf16
        int i = (b * 256 + threadIdx.x) * 4;
        float4 v = *(const float4*)(x + i);
        short4 o;
        o.x = f2bf(v.x); o.y = f2bf(v.y); o.z = f2bf(v.z); o.w = f2bf(v.w);
        *(short4*)(xbf + i) = o;
    } else if (b < 4352) {                  // rope tables (f64 fidelity)
        int i = (b - 4096) * 256 + threadIdx.x;
        int s = i >> 5, j = i & 31;
        double inv = pow(10000.0, -(double)j / 32.0);
        double f = (double)s * inv;
        cost[i] = (float)cos(f);
        sint[i] = (float)sin(f);
    } else {
        int bb = b - 4352;
        if (bb < 4096) {                    // Wq/Wk/Wv/Wo
            int seg = bb >> 10, idx = bb & 1023;
            const float* in = seg == 0 ? Wq : seg == 1 ? Wk : seg == 2 ? Wv : Wo;
            short* out = seg == 0 ? wqkvT : seg == 1 ? wqkvT + 1048576
                       : seg == 2 ? wqkvT + 2097152 : woT;
            trans_tile(in, out, 1024, 1024, 1024, 1024, 1, 0, idx & 31, idx >> 5);
        } else if (bb < 9600) {             // Wup/Wg -> interleaved [5504][1024]
            int idx = bb - 4096;
            int seg = idx >= 2752;
            idx -= seg * 2752;
            trans_tile(seg ? Wg : Wup, wugT, 1024, 2730, 1024, 2752, 2, seg, idx % 86, idx / 86);
        } else {                            // Wd -> [1024][2752]
            int idx = bb - 9600;
            trans_tile(Wd, wdownT, 2730, 1024, 2752, 1024, 1, 0, idx & 31, idx >> 5);
        }
    }
}

// ---------- GEMM 128x128x32, dbuf LDS, bank-swizzled, XCD-chunked 1D grid, split-K ----------
// Swizzle: row r, 16B-chunk c stored at physical chunk c^((r>>1)&3); both-sides.
// EPI: 0 = f32 out, 1 = bf16 out (both honor nsplit=2 -> Cv1), 2 = SwiGLU-interleaved,
//      3 = fused QKV epilogue: rope+cosine-norm+s_qk for q/k; v written DIRECTLY into
//          vt[b][h][d][s] (short4 per lane, consecutive s) - no separate vtrans pass.
// Grid 1D, gridDim.x % 8 == 0.
template <int EPI>
__launch_bounds__(256)
__global__ void k_gemm128(const short* __restrict__ A, const short* __restrict__ BT,
                          void* __restrict__ Cv, void* __restrict__ Cv1,
                          int M, int N, int K, int nkblk, int nsplit,
                          const float* __restrict__ s_u, const float* __restrict__ s_v,
                          const float* __restrict__ cost, const float* __restrict__ sint,
                          const float* __restrict__ sqk,
                          short* __restrict__ qn, short* __restrict__ kn,
                          short* __restrict__ vtout) {
    __shared__ __align__(16) short As[2 * 128 * 32];
    __shared__ __align__(16) short Bs[2 * 128 * 32];
    const int t = threadIdx.x;
    const int w = t >> 6;
    const int lane = t & 63;
    const int lr = lane & 15, lg = lane >> 4;
    const int nwg = (int)gridDim.x;
    int wg = ((int)blockIdx.x & 7) * (nwg >> 3) + ((int)blockIdx.x >> 3);
    int half = 0;
    if (nsplit == 2) {
        const int per = nwg >> 1;
        half = wg >= per;
        wg -= half * per;
    }
    const int MT = M >> 7;
    const int m0 = (wg % MT) << 7;
    const int n0 = (wg / MT) << 7;
    const int koff = half * nkblk * 32;
    const int wr = (w >> 1) * 64, wc = (w & 1) * 64;

    const int srow = t >> 2;
    const int scol = (((t & 3) ^ ((srow >> 1) & 3)) << 3);
    const short* Ap0 = A + (size_t)(m0 + srow) * K + koff + scol;
    const short* Ap1 = Ap0 + (size_t)64 * K;
    const short* Bp0 = BT + (size_t)(n0 + srow) * K + koff + scol;
    const short* Bp1 = Bp0 + (size_t)64 * K;
    const int d0 = (w * 64) * 8;
    const int d1 = (w * 64 + 256) * 8;

    f32x4 acc[4][4];
#pragma unroll
    for (int m = 0; m < 4; m++)
#pragma unroll
        for (int n = 0; n < 4; n++)
            acc[m][n] = (f32x4){0.f, 0.f, 0.f, 0.f};

    gload16(Ap0, As + d0); gload16(Ap1, As + d1);
    gload16(Bp0, Bs + d0); gload16(Bp1, Bs + d1);
    Ap0 += 32; Ap1 += 32; Bp0 += 32; Bp1 += 32;

    for (int kt = 0; kt < nkblk; kt++) {
        __syncthreads();
        if (kt + 1 < nkblk) {
            const int bo = ((kt + 1) & 1) * 4096;
            gload16(Ap0, As + bo + d0); gload16(Ap1, As + bo + d1);
            gload16(Bp0, Bs + bo + d0); gload16(Bp1, Bs + bo + d1);
            Ap0 += 32; Ap1 += 32; Bp0 += 32; Bp1 += 32;
        }
        const short* asb = As + (kt & 1) * 4096;
        const short* bsb = Bs + (kt & 1) * 4096;
        bf16x8 af[4], bfr[4];
#pragma unroll
        for (int m = 0; m < 4; m++) {
            int rml = wr + m * 16 + lr;
            af[m] = *(const bf16x8*)&asb[rml * 32 + ((lg ^ ((rml >> 1) & 3)) << 3)];
        }
#pragma unroll
        for (int n = 0; n < 4; n++) {
            int rnl = wc + n * 16 + lr;
            bfr[n] = *(const bf16x8*)&bsb[rnl * 32 + ((lg ^ ((rnl >> 1) & 3)) << 3)];
        }
#pragma unroll
        for (int m = 0; m < 4; m++)
#pragma unroll
            for (int n = 0; n < 4; n++)
                acc[m][n] = mfma16(af[m], bfr[n], acc[m][n]);
    }

    if (EPI == 3) {
        const int sector = n0 >> 10;     // 0=q, 1=k, 2=v
        if (sector == 2) {
            // write v directly into vt[b][h][d][s]: lane stores short4 (4 consecutive s)
#pragma unroll
            for (int m = 0; m < 4; m++)
#pragma unroll
                for (int n = 0; n < 4; n++) {
                    int col = n0 + wc + n * 16 + lr - 2048;
                    int hh = col >> 6, d = col & 63;
                    int brow = m0 + wr + m * 16 + lg * 4;
                    int bb = brow >> 11, s = brow & 2047;
                    short4 o4;
                    o4.x = f2bf(acc[m][n][0]); o4.y = f2bf(acc[m][n][1]);
                    o4.z = f2bf(acc[m][n][2]); o4.w = f2bf(acc[m][n][3]);
                    *(short4*)&vtout[((size_t)((bb * 16 + hh) * 64 + d)) * 2048 + s] = o4;
                }
        } else {
            const int h = ((n0 + wc) >> 6) & 15;
            float eff[4];
#pragma unroll
            for (int n = 0; n < 4; n++)
                eff[n] = sqk[h * 64 + n * 16 + lr] * 32.0f;   // s_qk * sqrt(DIM)
            short* dst = (sector == 0) ? qn : kn;
            const float extra = (sector == 0) ? 8.0f : 1.0f;  // sqrt(HD) folded into q
#pragma unroll
            for (int m = 0; m < 4; m++)
#pragma unroll
                for (int i = 0; i < 4; i++) {
                    int row = m0 + wr + m * 16 + lg * 4 + i;
                    int b = row >> 11, s = row & 2047;
                    float cs0 = cost[s * 32 + lr],      sn0 = sint[s * 32 + lr];
                    float cs1 = cost[s * 32 + 16 + lr], sn1 = sint[s * 32 + 16 + lr];
                    float vr0 = acc[m][0][i] * cs0 - acc[m][2][i] * sn0;
                    float vr1 = acc[m][1][i] * cs1 - acc[m][3][i] * sn1;
                    float vr2 = acc[m][2][i] * cs0 + acc[m][0][i] * sn0;
                    float vr3 = acc[m][3][i] * cs1 + acc[m][1][i] * sn1;
                    float ss = vr0 * vr0 + vr1 * vr1 + vr2 * vr2 + vr3 * vr3;
#pragma unroll
                    for (int o = 1; o < 16; o <<= 1)
                        ss += __shfl_xor(ss, o, 64);
                    float sc = extra / fmaxf(sqrtf(ss), 1e-6f);
                    size_t base = ((size_t)(b * 16 + h) * 2048 + s) * 64;
                    dst[base + lr]      = f2bf(vr0 * eff[0] * sc);
                    dst[base + 16 + lr] = f2bf(vr1 * eff[1] * sc);
                    dst[base + 32 + lr] = f2bf(vr2 * eff[2] * sc);
                    dst[base + 48 + lr] = f2bf(vr3 * eff[3] * sc);
                }
        }
        return;
    }

#pragma unroll
    for (int m = 0; m < 4; m++)
#pragma unroll
        for (int n = 0; n < 4; n++) {
            int row = m0 + wr + m * 16 + lg * 4;
            int col = n0 + wc + n * 16 + lr;
            if (EPI == 2) {
                int j = col >> 1;
                int jc = j < 2730 ? j : 2729;
                float su = s_u[jc];
                float sg = s_v[jc] * 32.0f;
#pragma unroll
                for (int i = 0; i < 4; i++) {
                    float own = acc[m][n][i];
                    float oth = __shfl_xor(own, 1, 64);
                    float u = (lr & 1) ? oth : own;
                    float g = (lr & 1) ? own : oth;
                    float uu = u * su;
                    float vv = g * sg;
                    float wv = uu * vv / (1.0f + expf(-vv));
                    if (!(lr & 1))
                        ((short*)Cv)[(size_t)(row + i) * (N >> 1) + j] = f2bf(wv);
                }
            } else {
                void* outp = half ? Cv1 : Cv;
#pragma unroll
                for (int i = 0; i < 4; i++) {
                    if (EPI == 1)
                        ((short*)outp)[(size_t)(row + i) * N + col] = f2bf(acc[m][n][i]);
                    else
                        ((float*)outp)[(size_t)(row + i) * N + col] = acc[m][n][i];
                }
            }
        }
}

// ---------- flash attention (causal), static-max softmax, balanced pair split ----------
__launch_bounds__(512)
__global__ void k_attn(const short* __restrict__ qn, const short* __restrict__ kn,
                       const short* __restrict__ vt, short* __restrict__ opart,
                       float* __restrict__ lsump) {
    __shared__ __align__(16) short Ks[2][64 * 64];
    __shared__ __align__(16) short Vs[2][64 * 64];
    __shared__ __align__(16) short Ps[8][32 * 64];
    const int t = threadIdx.x;
    const int w = t >> 6, lane = t & 63;
    const int bid = blockIdx.x;
    const int xcd = bid & 7, idx = bid >> 3;
    const int bhg = xcd + ((idx >> 3) << 3);          // 0..31
    const int pslot = idx & 7;
    const int h = bhg & 15, b = bhg >> 4;
    const int bh = b * 16 + h;
    const int lr = lane & 15, lg = lane >> 4;
    const short* Qb = qn + (size_t)bh * 2048 * 64;
    const short* Kb = kn + (size_t)bh * 2048 * 64;
    const short* Vb = vt + (size_t)bh * 64 * 2048;
    char* pwc = (char*)&Ps[w][0];

#define STAGE_KV(bi, kbase)                                                          \
    {                                                                                \
        int row = w * 8 + (lane >> 3);                                               \
        int scol = (lane & 7) ^ (row & 7);                                           \
        gload16(Kb + (size_t)((kbase) + row) * 64 + scol * 8,                        \
                &Ks[bi][(w * 8) * 64]);                                              \
        gload16(Vb + (size_t)row * 2048 + (kbase) + scol * 8,                        \
                &Vs[bi][(w * 8) * 64]);                                              \
    }

    for (int pc = 0; pc < 2; pc++) {
        const int qb = pc == 0 ? pslot : 7 - pslot;
        const int hf = pc;
        const int ktn = 2 * qb + 2;
        const int kt0 = hf * ktn, kt1 = kt0 + ktn;
        const int qw = qb * 256 + w * 32;

        bf16x8 qf[2][2];
#pragma unroll
        for (int mi = 0; mi < 2; mi++)
#pragma unroll
            for (int kk = 0; kk < 2; kk++)
                qf[mi][kk] = *(const bf16x8*)&Qb[(size_t)(qw + mi * 16 + lr) * 64 + kk * 32 + lg * 8];

        f32x4 oacc[2][4];
#pragma unroll
        for (int mi = 0; mi < 2; mi++)
#pragma unroll
            for (int ct = 0; ct < 4; ct++) oacc[mi][ct] = (f32x4){0.f, 0.f, 0.f, 0.f};
        float psum[2][4];
#pragma unroll
        for (int mi = 0; mi < 2; mi++)
#pragma unroll
            for (int i = 0; i < 4; i++) psum[mi][i] = 0.0f;

        if (pc) __syncthreads();          // all waves done with piece-0 LDS
        STAGE_KV(0, kt0 << 6);

        for (int kt = kt0; kt < kt1; kt++) {
            const int kbase = kt << 6;
            const int cur = (kt - kt0) & 1;
            __syncthreads();
            if (kt + 1 < kt1) STAGE_KV(cur ^ 1, (kt + 1) << 6);

            bf16x8 kf[4][2];
#pragma unroll
            for (int ni = 0; ni < 4; ni++)
#pragma unroll
                for (int kk = 0; kk < 2; kk++) {
                    int row = ni * 16 + lr;
                    kf[ni][kk] = *(const bf16x8*)&Ks[cur][row * 64 + (((kk * 4 + lg) ^ (row & 7)) << 3)];
                }
            f32x4 sv[2][4];
#pragma unroll
            for (int mi = 0; mi < 2; mi++)
#pragma unroll
                for (int ni = 0; ni < 4; ni++) {
                    f32x4 s = (f32x4){0.f, 0.f, 0.f, 0.f};
                    s = mfma16(qf[mi][0], kf[ni][0], s);
                    s = mfma16(qf[mi][1], kf[ni][1], s);
                    sv[mi][ni] = s;
                }
            if (kbase + 63 > qw) {
#pragma unroll
                for (int mi = 0; mi < 2; mi++)
#pragma unroll
                    for (int ni = 0; ni < 4; ni++)
#pragma unroll
                        for (int i = 0; i < 4; i++) {
                            int qg = qw + mi * 16 + lg * 4 + i;
                            int kg = kbase + ni * 16 + lr;
                            if (kg > qg) sv[mi][ni][i] = -3.0e38f;
                        }
            }
#pragma unroll
            for (int mi = 0; mi < 2; mi++) {
#pragma unroll
                for (int ni = 0; ni < 4; ni++)
#pragma unroll
                    for (int i = 0; i < 4; i++) {
                        float p = exp2f((sv[mi][ni][i] - 9.0f) * 1.44269504f);
                        sv[mi][ni][i] = p;
                        psum[mi][i] += p;
                    }
#pragma unroll
                for (int ni = 0; ni < 4; ni++)
#pragma unroll
                    for (int i = 0; i < 4; i++) {
                        int row = mi * 16 + lg * 4 + i;
                        int col = ni * 16 + lr;
                        unsigned off = (unsigned)(row * 128 + col * 2) ^ ((unsigned)(row & 7) << 4);
                        *(short*)(pwc + off) = f2bf(sv[mi][ni][i]);
                    }
            }
            bf16x8 pa[2][2];
#pragma unroll
            for (int mi = 0; mi < 2; mi++)
#pragma unroll
                for (int kk = 0; kk < 2; kk++) {
                    int row = mi * 16 + lr;
                    unsigned off = (unsigned)(row * 128 + kk * 64 + lg * 16) ^ ((unsigned)(row & 7) << 4);
                    pa[mi][kk] = *(const bf16x8*)(pwc + off);
                }
            bf16x8 vf[4][2];
#pragma unroll
            for (int ct = 0; ct < 4; ct++)
#pragma unroll
                for (int kk = 0; kk < 2; kk++) {
                    int row = ct * 16 + lr;
                    vf[ct][kk] = *(const bf16x8*)&Vs[cur][row * 64 + (((kk * 4 + lg) ^ (row & 7)) << 3)];
                }
#pragma unroll
            for (int mi = 0; mi < 2; mi++)
#pragma unroll
                for (int ct = 0; ct < 4; ct++) {
                    oacc[mi][ct] = mfma16(pa[mi][0], vf[ct][0], oacc[mi][ct]);
                    oacc[mi][ct] = mfma16(pa[mi][1], vf[ct][1], oacc[mi][ct]);
                }
        }

#pragma unroll
        for (int o = 1; o < 16; o <<= 1)
#pragma unroll
            for (int mi = 0; mi < 2; mi++)
#pragma unroll
                for (int i = 0; i < 4; i++)
                    psum[mi][i] += __shfl_xor(psum[mi][i], o, 64);

        short* aob = opart + (size_t)hf * 4096 * 1024 + ((size_t)(b * 2048 + qw) * 1024) + h * 64;
#pragma unroll
        for (int mi = 0; mi < 2; mi++)
#pragma unroll
            for (int ct = 0; ct < 4; ct++)
#pragma unroll
                for (int i = 0; i < 4; i++) {
                    int q = mi * 16 + lg * 4 + i;
                    aob[(size_t)q * 1024 + ct * 16 + lr] = f2bf(oacc[mi][ct][i]);
                }
        if (lr == 0) {
#pragma unroll
            for (int mi = 0; mi < 2; mi++)
#pragma unroll
                for (int i = 0; i < 4; i++)
                    lsump[hf * 65536 + bh * 2048 + qw + mi * 16 + lg * 4 + i] = psum[mi][i];
        }
    }
#undef STAGE_KV
}

// ---------- combine split-K partials: ao = (O0+O1)/(l0+l1), bf16 ----------
__global__ void k_comb(const short* __restrict__ op, const float* __restrict__ ls,
                       short* __restrict__ ao) {
    int i = (blockIdx.x * 256 + threadIdx.x) * 4;
    int row = i >> 10, col = i & 1023;
    int idx = ((row >> 11) * 16 + (col >> 6)) * 2048 + (row & 2047);
    float rl = 1.0f / (ls[idx] + ls[65536 + idx]);
    short4 a = *(const short4*)(op + i);
    short4 c = *(const short4*)(op + 4194304 + i);
    short4 o;
    o.x = f2bf((bf2f(a.x) + bf2f(c.x)) * rl);
    o.y = f2bf((bf2f(a.y) + bf2f(c.y)) * rl);
    o.z = f2bf((bf2f(a.z) + bf2f(c.z)) * rl);
    o.w = f2bf((bf2f(a.w) + bf2f(c.w)) * rl);
    *(short4*)(ao + i) = o;
}

// ---------- residual + double cosine_norm; pre = pre0 + pre1 (bf16 partials) ----------
__global__ void k_resnorm(const float* base, const short* __restrict__ pre0,
                          const short* __restrict__ pre1,
                          const float* __restrict__ alpha, float* outf,
                          short* __restrict__ outb) {
    __shared__ float red1[4], red2[4];
    int row = blockIdx.x;
    int t = threadIdx.x;
    int w = t >> 6;
    float4 p;
    short4 a = *(const short4*)(pre0 + (size_t)row * 1024 + t * 4);
    short4 c = *(const short4*)(pre1 + (size_t)row * 1024 + t * 4);
    p.x = bf2f(a.x) + bf2f(c.x); p.y = bf2f(a.y) + bf2f(c.y);
    p.z = bf2f(a.z) + bf2f(c.z); p.w = bf2f(a.w) + bf2f(c.w);
    float ss = p.x * p.x + p.y * p.y + p.z * p.z + p.w * p.w;
#pragma unroll
    for (int o = 1; o < 64; o <<= 1) ss += __shfl_xor(ss, o, 64);
    if ((t & 63) == 0) red1[w] = ss;
    __syncthreads();
    float inv1 = 1.0f / fmaxf(sqrtf(red1[0] + red1[1] + red1[2] + red1[3]), 1e-6f);
    const float4 bx = *(const float4*)(base + (size_t)row * 1024 + t * 4);
    const float4 av = *(const float4*)(alpha + t * 4);
    float4 tm;
    tm.x = bx.x + av.x * (p.x * inv1 - bx.x);
    tm.y = bx.y + av.y * (p.y * inv1 - bx.y);
    tm.z = bx.z + av.z * (p.z * inv1 - bx.z);
    tm.w = bx.w + av.w * (p.w * inv1 - bx.w);
    float ss2 = tm.x * tm.x + tm.y * tm.y + tm.z * tm.z + tm.w * tm.w;
#pragma unroll
    for (int o = 1; o < 64; o <<= 1) ss2 += __shfl_xor(ss2, o, 64);
    if ((t & 63) == 0) red2[w] = ss2;
    __syncthreads();
    float inv2 = 1.0f / fmaxf(sqrtf(red2[0] + red2[1] + red2[2] + red2[3]), 1e-6f);
    float4 hv;
    hv.x = tm.x * inv2; hv.y = tm.y * inv2; hv.z = tm.z * inv2; hv.w = tm.w * inv2;
    if (outf) *(float4*)(outf + (size_t)row * 1024 + t * 4) = hv;
    if (outb) {
        short4 o4;
        o4.x = f2bf(hv.x); o4.y = f2bf(hv.y); o4.z = f2bf(hv.z); o4.w = f2bf(hv.w);
        *(short4*)(outb + (size_t)row * 1024 + t * 4) = o4;
    }
}

// ---------- launch ----------
// Workspace (lifetime-overlaid, peak ~75.9 MB; 76,152,832 known-safe):
//  [0, 25296896)  weights bf16^T                                     (whole launch)
//  25296896  cost/sint (prep->qkv) -> lsum 0.5MB (attn->comb)
//  25821184  xbf(prep->qkv) -> h1bf(rn1->swiglu)                               8 MB
//  34209792  qn(qkv->attn) -> ao(comb->wo) -> wmlp(swiglu->down, 22.5MB ..56754176)
//  42598400  kn(qkv->attn) -> hA0 bf16 8MB(wo->rn1)
//  50987008  vt(qkv->attn) -> hA1 bf16 8MB(wo->rn1)
//  59375616  opart[2] bf16 16MB(attn->comb) -> hM0 bf16 8MB(down->rn2)
//  67764224  hM1 bf16 8MB(down->rn2)
extern "C" void kernel_launch(void* const* d_in, const int* in_sizes, int n_in,
                              void* d_out, int out_size, void* d_ws, size_t ws_size,
                              hipStream_t stream) {
    (void)in_sizes; (void)n_in; (void)out_size; (void)ws_size;
    const float* x   = (const float*)d_in[0];
    const float* Wq  = (const float*)d_in[1];
    const float* Wk  = (const float*)d_in[2];
    const float* Wv  = (const float*)d_in[3];
    const float* Wo  = (const float*)d_in[4];
    const float* sqk = (const float*)d_in[5];
    const float* aA  = (const float*)d_in[6];
    const float* Wup = (const float*)d_in[7];
    const float* Wg  = (const float*)d_in[8];
    const float* Wd  = (const float*)d_in[9];
    const float* su  = (const float*)d_in[10];
    const float* sv  = (const float*)d_in[11];
    const float* aM  = (const float*)d_in[12];

    char* ws = (char*)d_ws;
    short* wqkvT  = (short*)(ws + 0);          // [3072][1024]
    short* woT    = (short*)(ws + 6291456);    // [1024][1024]
    short* wugT   = (short*)(ws + 8388608);    // [5504][1024] interleaved up/gate
    short* wdownT = (short*)(ws + 19660800);   // [1024][2752]
    float* cost   = (float*)(ws + 25296896);
    float* sint   = (float*)(ws + 25559040);
    short* xbf    = (short*)(ws + 25821184);
    short* qn     = (short*)(ws + 34209792);
    short* kn     = (short*)(ws + 42598400);
    short* vt     = (short*)(ws + 50987008);   // [B][H][64][2048] bf16, 8MB
    short* opart  = (short*)(ws + 59375616);   // [2][4096][1024] bf16
    float* lsum   = (float*)(ws + 25296896);   // overwrites cost/sint (dead after qkv)
    short* ao     = (short*)(ws + 34209792);   // reuse qn
    short* hA0    = (short*)(ws + 42598400);   // reuse kn, bf16 8MB
    short* hA1    = (short*)(ws + 50987008);   // reuse vt, bf16 8MB
    float* h1f    = (float*)d_out;
    short* h1bf   = (short*)(ws + 25821184);   // reuse xbf
    short* wmlp   = (short*)(ws + 34209792);   // [4096][2752] bf16
    short* hM0    = (short*)(ws + 59375616);   // bf16 8MB (opart dead)
    short* hM1    = (short*)(ws + 67764224);   // bf16 8MB

    k_prep<<<16704, 256, 0, stream>>>(x, xbf, cost, sint, Wq, Wk, Wv, Wo, Wup, Wg, Wd,
                                      wqkvT, woT, wugT, wdownT);

    // QKV GEMM with fused rope + cosine-norm epilogue; v written directly transposed
    k_gemm128<3><<<768, 256, 0, stream>>>(xbf, wqkvT, nullptr, nullptr, 4096, 3072, 1024,
                                          32, 1, nullptr, nullptr, cost, sint, sqk, qn, kn, vt);
    k_attn<<<256, 512, 0, stream>>>(qn, kn, vt, opart, lsum);
    k_comb<<<4096, 256, 0, stream>>>(opart, lsum, ao);
    // Wo: split-K x2, bf16 partials
    k_gemm128<1><<<512, 256, 0, stream>>>(ao, woT, hA0, hA1, 4096, 1024, 1024,
                                          16, 2, nullptr, nullptr, nullptr, nullptr, nullptr,
                                          nullptr, nullptr, nullptr);
    k_resnorm<<<4096, 256, 0, stream>>>(x, hA0, hA1, aA, h1f, h1bf);
    // up+gate fused SwiGLU
    k_gemm128<2><<<1376, 256, 0, stream>>>(h1bf, wugT, wmlp, nullptr, 4096, 5504, 1024,
                                           32, 1, su, sv, nullptr, nullptr, nullptr,
                                           nullptr, nullptr, nullptr);
    // down: split-K x2, bf16 partials
    k_gemm128<1><<<512, 256, 0, stream>>>(wmlp, wdownT, hM0, hM1, 4096, 1024, 2752,
                                          43, 2, nullptr, nullptr, nullptr, nullptr, nullptr,
                                          nullptr, nullptr, nullptr);
    k_resnorm<<<4096, 256, 0, stream>>>(h1f, hM0, hM1, aM, (float*)d_out, (short*)nullptr);
}

// Round 16
// 276.698 us; speedup vs baseline: 1.0592x; 1.0084x over previous
//
#include <hip/hip_runtime.h>
#include <math.h>

#define DEVI __device__ __forceinline__

typedef __attribute__((ext_vector_type(4))) float f32x4;
typedef __attribute__((ext_vector_type(8))) short bf16x8;

// ---------- helpers ----------
DEVI short f2bf(float f) {                    // f32 -> bf16 (RNE)
    union { float f; unsigned u; } v; v.f = f;
    unsigned r = v.u + 0x7fffu + ((v.u >> 16) & 1u);
    return (short)(r >> 16);
}
DEVI float bf2f(short s) {
    union { unsigned u; float f; } v; v.u = ((unsigned)(unsigned short)s) << 16;
    return v.f;
}

DEVI f32x4 mfma16(bf16x8 a, bf16x8 b, f32x4 c) {
    return __builtin_amdgcn_mfma_f32_16x16x32_bf16(a, b, c, 0, 0, 0);
}

DEVI void gload16(const short* g, short* l) {  // async global->LDS, 16B/lane
    __builtin_amdgcn_global_load_lds((__attribute__((address_space(1))) void*)(g),
                                     (__attribute__((address_space(3))) void*)(l),
                                     16, 0, 0);
}

// ---------- merged preprocessing: cvt + freqs + all 7 weight transposes ----------
DEVI void trans_tile(const float* in, short* out, int R, int C, int Rpad, int Cpad,
                     int rmul, int radd, int bx, int by) {
    __shared__ float tile[32][33];
    int c0 = bx * 32, r0 = by * 32;
    int tx = threadIdx.x & 31, ty = threadIdx.x >> 5;
#pragma unroll
    for (int i = 0; i < 4; i++) {
        int r = r0 + ty + 8 * i, c = c0 + tx;
        tile[ty + 8 * i][tx] = (r < R && c < C) ? in[(size_t)r * C + c] : 0.0f;
    }
    __syncthreads();
#pragma unroll
    for (int i = 0; i < 4; i++) {
        int oc = c0 + ty + 8 * i;
        int orr = r0 + tx;
        if (oc < Cpad && orr < Rpad)
            out[(size_t)(oc * rmul + radd) * Rpad + orr] = f2bf(tile[tx][ty + 8 * i]);
    }
}

__global__ void k_prep(const float* __restrict__ x, short* __restrict__ xbf,
                       float* __restrict__ cost, float* __restrict__ sint,
                       const float* __restrict__ Wq, const float* __restrict__ Wk,
                       const float* __restrict__ Wv, const float* __restrict__ Wo,
                       const float* __restrict__ Wup, const float* __restrict__ Wg,
                       const float* __restrict__ Wd,
                       short* __restrict__ wqkvT, short* __restrict__ woT,
                       short* __restrict__ wugT, short* __restrict__ wdownT) {
    int b = blockIdx.x;
    if (b < 4096) {                         // x f32 -> bf16
        int i = (b * 256 + threadIdx.x) * 4;
        float4 v = *(const float4*)(x + i);
        short4 o;
        o.x = f2bf(v.x); o.y = f2bf(v.y); o.z = f2bf(v.z); o.w = f2bf(v.w);
        *(short4*)(xbf + i) = o;
    } else if (b < 4352) {                  // rope tables (f64 fidelity)
        int i = (b - 4096) * 256 + threadIdx.x;
        int s = i >> 5, j = i & 31;
        double inv = pow(10000.0, -(double)j / 32.0);
        double f = (double)s * inv;
        cost[i] = (float)cos(f);
        sint[i] = (float)sin(f);
    } else {
        int bb = b - 4352;
        if (bb < 4096) {                    // Wq/Wk/Wv/Wo
            int seg = bb >> 10, idx = bb & 1023;
            const float* in = seg == 0 ? Wq : seg == 1 ? Wk : seg == 2 ? Wv : Wo;
            short* out = seg == 0 ? wqkvT : seg == 1 ? wqkvT + 1048576
                       : seg == 2 ? wqkvT + 2097152 : woT;
            trans_tile(in, out, 1024, 1024, 1024, 1024, 1, 0, idx & 31, idx >> 5);
        } else if (bb < 9600) {             // Wup/Wg -> interleaved [5504][1024]
            int idx = bb - 4096;
            int seg = idx >= 2752;
            idx -= seg * 2752;
            trans_tile(seg ? Wg : Wup, wugT, 1024, 2730, 1024, 2752, 2, seg, idx % 86, idx / 86);
        } else {                            // Wd -> [1024][2752]
            int idx = bb - 9600;
            trans_tile(Wd, wdownT, 2730, 1024, 2752, 1024, 1, 0, idx & 31, idx >> 5);
        }
    }
}

// ---------- GEMM 128x128x32, SINGLE-buffer 16KB LDS (m97 structure, max co-residency),
// bank-swizzled both-sides, XCD-chunked 1D grid, split-K ----------
// Per K-step: [loop-top barrier: all readers of prior tile done] -> stage tile ->
// barrier (vmcnt drain) -> frag reads + 16 MFMA. 16KB LDS -> ~7 blocks/CU resident;
// cross-block wave overlap hides the barrier drains (m114).
// EPI: 0 = f32 out, 1 = bf16 out (both honor nsplit=2 -> Cv1), 2 = SwiGLU-interleaved,
//      3 = fused QKV epilogue: rope+cosine-norm+s_qk for q/k; v written DIRECTLY into
//          vt[b][h][d][s]. Grid 1D, gridDim.x % 8 == 0.
template <int EPI>
__launch_bounds__(256)
__global__ void k_gemm128(const short* __restrict__ A, const short* __restrict__ BT,
                          void* __restrict__ Cv, void* __restrict__ Cv1,
                          int M, int N, int K, int nkblk, int nsplit,
                          const float* __restrict__ s_u, const float* __restrict__ s_v,
                          const float* __restrict__ cost, const float* __restrict__ sint,
                          const float* __restrict__ sqk,
                          short* __restrict__ qn, short* __restrict__ kn,
                          short* __restrict__ vtout) {
    __shared__ __align__(16) short As[128 * 32];
    __shared__ __align__(16) short Bs[128 * 32];
    const int t = threadIdx.x;
    const int w = t >> 6;
    const int lane = t & 63;
    const int lr = lane & 15, lg = lane >> 4;
    const int nwg = (int)gridDim.x;
    int wg = ((int)blockIdx.x & 7) * (nwg >> 3) + ((int)blockIdx.x >> 3);
    int half = 0;
    if (nsplit == 2) {
        const int per = nwg >> 1;
        half = wg >= per;
        wg -= half * per;
    }
    const int MT = M >> 7;
    const int m0 = (wg % MT) << 7;
    const int n0 = (wg / MT) << 7;
    const int koff = half * nkblk * 32;
    const int wr = (w >> 1) * 64, wc = (w & 1) * 64;

    const int srow = t >> 2;
    const int scol = (((t & 3) ^ ((srow >> 1) & 3)) << 3);
    const short* Ap0 = A + (size_t)(m0 + srow) * K + koff + scol;
    const short* Ap1 = Ap0 + (size_t)64 * K;
    const short* Bp0 = BT + (size_t)(n0 + srow) * K + koff + scol;
    const short* Bp1 = Bp0 + (size_t)64 * K;
    const int d0 = (w * 64) * 8;
    const int d1 = (w * 64 + 256) * 8;

    f32x4 acc[4][4];
#pragma unroll
    for (int m = 0; m < 4; m++)
#pragma unroll
        for (int n = 0; n < 4; n++)
            acc[m][n] = (f32x4){0.f, 0.f, 0.f, 0.f};

    for (int kt = 0; kt < nkblk; kt++) {
        if (kt) __syncthreads();          // all waves done reading tile kt-1
        gload16(Ap0, As + d0); gload16(Ap1, As + d1);
        gload16(Bp0, Bs + d0); gload16(Bp1, Bs + d1);
        Ap0 += 32; Ap1 += 32; Bp0 += 32; Bp1 += 32;
        __syncthreads();                  // vmcnt(0) drain -> tile resident
        bf16x8 af[4], bfr[4];
#pragma unroll
        for (int m = 0; m < 4; m++) {
            int rml = wr + m * 16 + lr;
            af[m] = *(const bf16x8*)&As[rml * 32 + ((lg ^ ((rml >> 1) & 3)) << 3)];
        }
#pragma unroll
        for (int n = 0; n < 4; n++) {
            int rnl = wc + n * 16 + lr;
            bfr[n] = *(const bf16x8*)&Bs[rnl * 32 + ((lg ^ ((rnl >> 1) & 3)) << 3)];
        }
#pragma unroll
        for (int m = 0; m < 4; m++)
#pragma unroll
            for (int n = 0; n < 4; n++)
                acc[m][n] = mfma16(af[m], bfr[n], acc[m][n]);
    }

    if (EPI == 3) {
        const int sector = n0 >> 10;     // 0=q, 1=k, 2=v
        if (sector == 2) {
            // write v directly into vt[b][h][d][s]: lane stores short4 (4 consecutive s)
#pragma unroll
            for (int m = 0; m < 4; m++)
#pragma unroll
                for (int n = 0; n < 4; n++) {
                    int col = n0 + wc + n * 16 + lr - 2048;
                    int hh = col >> 6, d = col & 63;
                    int brow = m0 + wr + m * 16 + lg * 4;
                    int bb = brow >> 11, s = brow & 2047;
                    short4 o4;
                    o4.x = f2bf(acc[m][n][0]); o4.y = f2bf(acc[m][n][1]);
                    o4.z = f2bf(acc[m][n][2]); o4.w = f2bf(acc[m][n][3]);
                    *(short4*)&vtout[((size_t)((bb * 16 + hh) * 64 + d)) * 2048 + s] = o4;
                }
        } else {
            const int h = ((n0 + wc) >> 6) & 15;
            float eff[4];
#pragma unroll
            for (int n = 0; n < 4; n++)
                eff[n] = sqk[h * 64 + n * 16 + lr] * 32.0f;   // s_qk * sqrt(DIM)
            short* dst = (sector == 0) ? qn : kn;
            const float extra = (sector == 0) ? 8.0f : 1.0f;  // sqrt(HD) folded into q
#pragma unroll
            for (int m = 0; m < 4; m++)
#pragma unroll
                for (int i = 0; i < 4; i++) {
                    int row = m0 + wr + m * 16 + lg * 4 + i;
                    int b = row >> 11, s = row & 2047;
                    float cs0 = cost[s * 32 + lr],      sn0 = sint[s * 32 + lr];
                    float cs1 = cost[s * 32 + 16 + lr], sn1 = sint[s * 32 + 16 + lr];
                    float vr0 = acc[m][0][i] * cs0 - acc[m][2][i] * sn0;
                    float vr1 = acc[m][1][i] * cs1 - acc[m][3][i] * sn1;
                    float vr2 = acc[m][2][i] * cs0 + acc[m][0][i] * sn0;
                    float vr3 = acc[m][3][i] * cs1 + acc[m][1][i] * sn1;
                    float ss = vr0 * vr0 + vr1 * vr1 + vr2 * vr2 + vr3 * vr3;
#pragma unroll
                    for (int o = 1; o < 16; o <<= 1)
                        ss += __shfl_xor(ss, o, 64);
                    float sc = extra / fmaxf(sqrtf(ss), 1e-6f);
                    size_t base = ((size_t)(b * 16 + h) * 2048 + s) * 64;
                    dst[base + lr]      = f2bf(vr0 * eff[0] * sc);
                    dst[base + 16 + lr] = f2bf(vr1 * eff[1] * sc);
                    dst[base + 32 + lr] = f2bf(vr2 * eff[2] * sc);
                    dst[base + 48 + lr] = f2bf(vr3 * eff[3] * sc);
                }
        }
        return;
    }

#pragma unroll
    for (int m = 0; m < 4; m++)
#pragma unroll
        for (int n = 0; n < 4; n++) {
            int row = m0 + wr + m * 16 + lg * 4;
            int col = n0 + wc + n * 16 + lr;
            if (EPI == 2) {
                int j = col >> 1;
                int jc = j < 2730 ? j : 2729;
                float su = s_u[jc];
                float sg = s_v[jc] * 32.0f;
#pragma unroll
                for (int i = 0; i < 4; i++) {
                    float own = acc[m][n][i];
                    float oth = __shfl_xor(own, 1, 64);
                    float u = (lr & 1) ? oth : own;
                    float g = (lr & 1) ? own : oth;
                    float uu = u * su;
                    float vv = g * sg;
                    float wv = uu * vv / (1.0f + expf(-vv));
                    if (!(lr & 1))
                        ((short*)Cv)[(size_t)(row + i) * (N >> 1) + j] = f2bf(wv);
                }
            } else {
                void* outp = half ? Cv1 : Cv;
#pragma unroll
                for (int i = 0; i < 4; i++) {
                    if (EPI == 1)
                        ((short*)outp)[(size_t)(row + i) * N + col] = f2bf(acc[m][n][i]);
                    else
                        ((float*)outp)[(size_t)(row + i) * N + col] = acc[m][n][i];
                }
            }
        }
}

// ---------- flash attention (causal), static-max softmax, balanced pair split ----------
__launch_bounds__(512)
__global__ void k_attn(const short* __restrict__ qn, const short* __restrict__ kn,
                       const short* __restrict__ vt, short* __restrict__ opart,
                       float* __restrict__ lsump) {
    __shared__ __align__(16) short Ks[2][64 * 64];
    __shared__ __align__(16) short Vs[2][64 * 64];
    __shared__ __align__(16) short Ps[8][32 * 64];
    const int t = threadIdx.x;
    const int w = t >> 6, lane = t & 63;
    const int bid = blockIdx.x;
    const int xcd = bid & 7, idx = bid >> 3;
    const int bhg = xcd + ((idx >> 3) << 3);          // 0..31
    const int pslot = idx & 7;
    const int h = bhg & 15, b = bhg >> 4;
    const int bh = b * 16 + h;
    const int lr = lane & 15, lg = lane >> 4;
    const short* Qb = qn + (size_t)bh * 2048 * 64;
    const short* Kb = kn + (size_t)bh * 2048 * 64;
    const short* Vb = vt + (size_t)bh * 64 * 2048;
    char* pwc = (char*)&Ps[w][0];

#define STAGE_KV(bi, kbase)                                                          \
    {                                                                                \
        int row = w * 8 + (lane >> 3);                                               \
        int scol = (lane & 7) ^ (row & 7);                                           \
        gload16(Kb + (size_t)((kbase) + row) * 64 + scol * 8,                        \
                &Ks[bi][(w * 8) * 64]);                                              \
        gload16(Vb + (size_t)row * 2048 + (kbase) + scol * 8,                        \
                &Vs[bi][(w * 8) * 64]);                                              \
    }

    for (int pc = 0; pc < 2; pc++) {
        const int qb = pc == 0 ? pslot : 7 - pslot;
        const int hf = pc;
        const int ktn = 2 * qb + 2;
        const int kt0 = hf * ktn, kt1 = kt0 + ktn;
        const int qw = qb * 256 + w * 32;

        bf16x8 qf[2][2];
#pragma unroll
        for (int mi = 0; mi < 2; mi++)
#pragma unroll
            for (int kk = 0; kk < 2; kk++)
                qf[mi][kk] = *(const bf16x8*)&Qb[(size_t)(qw + mi * 16 + lr) * 64 + kk * 32 + lg * 8];

        f32x4 oacc[2][4];
#pragma unroll
        for (int mi = 0; mi < 2; mi++)
#pragma unroll
            for (int ct = 0; ct < 4; ct++) oacc[mi][ct] = (f32x4){0.f, 0.f, 0.f, 0.f};
        float psum[2][4];
#pragma unroll
        for (int mi = 0; mi < 2; mi++)
#pragma unroll
            for (int i = 0; i < 4; i++) psum[mi][i] = 0.0f;

        if (pc) __syncthreads();          // all waves done with piece-0 LDS
        STAGE_KV(0, kt0 << 6);

        for (int kt = kt0; kt < kt1; kt++) {
            const int kbase = kt << 6;
            const int cur = (kt - kt0) & 1;
            __syncthreads();
            if (kt + 1 < kt1) STAGE_KV(cur ^ 1, (kt + 1) << 6);

            bf16x8 kf[4][2];
#pragma unroll
            for (int ni = 0; ni < 4; ni++)
#pragma unroll
                for (int kk = 0; kk < 2; kk++) {
                    int row = ni * 16 + lr;
                    kf[ni][kk] = *(const bf16x8*)&Ks[cur][row * 64 + (((kk * 4 + lg) ^ (row & 7)) << 3)];
                }
            f32x4 sv[2][4];
#pragma unroll
            for (int mi = 0; mi < 2; mi++)
#pragma unroll
                for (int ni = 0; ni < 4; ni++) {
                    f32x4 s = (f32x4){0.f, 0.f, 0.f, 0.f};
                    s = mfma16(qf[mi][0], kf[ni][0], s);
                    s = mfma16(qf[mi][1], kf[ni][1], s);
                    sv[mi][ni] = s;
                }
            if (kbase + 63 > qw) {
#pragma unroll
                for (int mi = 0; mi < 2; mi++)
#pragma unroll
                    for (int ni = 0; ni < 4; ni++)
#pragma unroll
                        for (int i = 0; i < 4; i++) {
                            int qg = qw + mi * 16 + lg * 4 + i;
                            int kg = kbase + ni * 16 + lr;
                            if (kg > qg) sv[mi][ni][i] = -3.0e38f;
                        }
            }
#pragma unroll
            for (int mi = 0; mi < 2; mi++) {
#pragma unroll
                for (int ni = 0; ni < 4; ni++)
#pragma unroll
                    for (int i = 0; i < 4; i++) {
                        float p = exp2f((sv[mi][ni][i] - 9.0f) * 1.44269504f);
                        sv[mi][ni][i] = p;
                        psum[mi][i] += p;
                    }
#pragma unroll
                for (int ni = 0; ni < 4; ni++)
#pragma unroll
                    for (int i = 0; i < 4; i++) {
                        int row = mi * 16 + lg * 4 + i;
                        int col = ni * 16 + lr;
                        unsigned off = (unsigned)(row * 128 + col * 2) ^ ((unsigned)(row & 7) << 4);
                        *(short*)(pwc + off) = f2bf(sv[mi][ni][i]);
                    }
            }
            bf16x8 pa[2][2];
#pragma unroll
            for (int mi = 0; mi < 2; mi++)
#pragma unroll
                for (int kk = 0; kk < 2; kk++) {
                    int row = mi * 16 + lr;
                    unsigned off = (unsigned)(row * 128 + kk * 64 + lg * 16) ^ ((unsigned)(row & 7) << 4);
                    pa[mi][kk] = *(const bf16x8*)(pwc + off);
                }
            bf16x8 vf[4][2];
#pragma unroll
            for (int ct = 0; ct < 4; ct++)
#pragma unroll
                for (int kk = 0; kk < 2; kk++) {
                    int row = ct * 16 + lr;
                    vf[ct][kk] = *(const bf16x8*)&Vs[cur][row * 64 + (((kk * 4 + lg) ^ (row & 7)) << 3)];
                }
#pragma unroll
            for (int mi = 0; mi < 2; mi++)
#pragma unroll
                for (int ct = 0; ct < 4; ct++) {
                    oacc[mi][ct] = mfma16(pa[mi][0], vf[ct][0], oacc[mi][ct]);
                    oacc[mi][ct] = mfma16(pa[mi][1], vf[ct][1], oacc[mi][ct]);
                }
        }

#pragma unroll
        for (int o = 1; o < 16; o <<= 1)
#pragma unroll
            for (int mi = 0; mi < 2; mi++)
#pragma unroll
                for (int i = 0; i < 4; i++)
                    psum[mi][i] += __shfl_xor(psum[mi][i], o, 64);

        short* aob = opart + (size_t)hf * 4096 * 1024 + ((size_t)(b * 2048 + qw) * 1024) + h * 64;
#pragma unroll
        for (int mi = 0; mi < 2; mi++)
#pragma unroll
            for (int ct = 0; ct < 4; ct++)
#pragma unroll
                for (int i = 0; i < 4; i++) {
                    int q = mi * 16 + lg * 4 + i;
                    aob[(size_t)q * 1024 + ct * 16 + lr] = f2bf(oacc[mi][ct][i]);
                }
        if (lr == 0) {
#pragma unroll
            for (int mi = 0; mi < 2; mi++)
#pragma unroll
                for (int i = 0; i < 4; i++)
                    lsump[hf * 65536 + bh * 2048 + qw + mi * 16 + lg * 4 + i] = psum[mi][i];
        }
    }
#undef STAGE_KV
}

// ---------- combine split-K partials: ao = (O0+O1)/(l0+l1), bf16 ----------
__global__ void k_comb(const short* __restrict__ op, const float* __restrict__ ls,
                       short* __restrict__ ao) {
    int i = (blockIdx.x * 256 + threadIdx.x) * 4;
    int row = i >> 10, col = i & 1023;
    int idx = ((row >> 11) * 16 + (col >> 6)) * 2048 + (row & 2047);
    float rl = 1.0f / (ls[idx] + ls[65536 + idx]);
    short4 a = *(const short4*)(op + i);
    short4 c = *(const short4*)(op + 4194304 + i);
    short4 o;
    o.x = f2bf((bf2f(a.x) + bf2f(c.x)) * rl);
    o.y = f2bf((bf2f(a.y) + bf2f(c.y)) * rl);
    o.z = f2bf((bf2f(a.z) + bf2f(c.z)) * rl);
    o.w = f2bf((bf2f(a.w) + bf2f(c.w)) * rl);
    *(short4*)(ao + i) = o;
}

// ---------- residual + double cosine_norm; pre = pre0 + pre1 (bf16 partials) ----------
__global__ void k_resnorm(const float* base, const short* __restrict__ pre0,
                          const short* __restrict__ pre1,
                          const float* __restrict__ alpha, float* outf,
                          short* __restrict__ outb) {
    __shared__ float red1[4], red2[4];
    int row = blockIdx.x;
    int t = threadIdx.x;
    int w = t >> 6;
    float4 p;
    short4 a = *(const short4*)(pre0 + (size_t)row * 1024 + t * 4);
    short4 c = *(const short4*)(pre1 + (size_t)row * 1024 + t * 4);
    p.x = bf2f(a.x) + bf2f(c.x); p.y = bf2f(a.y) + bf2f(c.y);
    p.z = bf2f(a.z) + bf2f(c.z); p.w = bf2f(a.w) + bf2f(c.w);
    float ss = p.x * p.x + p.y * p.y + p.z * p.z + p.w * p.w;
#pragma unroll
    for (int o = 1; o < 64; o <<= 1) ss += __shfl_xor(ss, o, 64);
    if ((t & 63) == 0) red1[w] = ss;
    __syncthreads();
    float inv1 = 1.0f / fmaxf(sqrtf(red1[0] + red1[1] + red1[2] + red1[3]), 1e-6f);
    const float4 bx = *(const float4*)(base + (size_t)row * 1024 + t * 4);
    const float4 av = *(const float4*)(alpha + t * 4);
    float4 tm;
    tm.x = bx.x + av.x * (p.x * inv1 - bx.x);
    tm.y = bx.y + av.y * (p.y * inv1 - bx.y);
    tm.z = bx.z + av.z * (p.z * inv1 - bx.z);
    tm.w = bx.w + av.w * (p.w * inv1 - bx.w);
    float ss2 = tm.x * tm.x + tm.y * tm.y + tm.z * tm.z + tm.w * tm.w;
#pragma unroll
    for (int o = 1; o < 64; o <<= 1) ss2 += __shfl_xor(ss2, o, 64);
    if ((t & 63) == 0) red2[w] = ss2;
    __syncthreads();
    float inv2 = 1.0f / fmaxf(sqrtf(red2[0] + red2[1] + red2[2] + red2[3]), 1e-6f);
    float4 hv;
    hv.x = tm.x * inv2; hv.y = tm.y * inv2; hv.z = tm.z * inv2; hv.w = tm.w * inv2;
    if (outf) *(float4*)(outf + (size_t)row * 1024 + t * 4) = hv;
    if (outb) {
        short4 o4;
        o4.x = f2bf(hv.x); o4.y = f2bf(hv.y); o4.z = f2bf(hv.z); o4.w = f2bf(hv.w);
        *(short4*)(outb + (size_t)row * 1024 + t * 4) = o4;
    }
}

// ---------- launch ----------
// Workspace (lifetime-overlaid, peak ~75.9 MB; 76,152,832 known-safe):
//  [0, 25296896)  weights bf16^T                                     (whole launch)
//  25296896  cost/sint (prep->qkv) -> lsum 0.5MB (attn->comb)
//  25821184  xbf(prep->qkv) -> h1bf(rn1->swiglu)                               8 MB
//  34209792  qn(qkv->attn) -> ao(comb->wo) -> wmlp(swiglu->down, 22.5MB ..56754176)
//  42598400  kn(qkv->attn) -> hA0 bf16 8MB(wo->rn1)
//  50987008  vt(qkv->attn) -> hA1 bf16 8MB(wo->rn1)
//  59375616  opart[2] bf16 16MB(attn->comb) -> hM0 bf16 8MB(down->rn2)
//  67764224  hM1 bf16 8MB(down->rn2)
extern "C" void kernel_launch(void* const* d_in, const int* in_sizes, int n_in,
                              void* d_out, int out_size, void* d_ws, size_t ws_size,
                              hipStream_t stream) {
    (void)in_sizes; (void)n_in; (void)out_size; (void)ws_size;
    const float* x   = (const float*)d_in[0];
    const float* Wq  = (const float*)d_in[1];
    const float* Wk  = (const float*)d_in[2];
    const float* Wv  = (const float*)d_in[3];
    const float* Wo  = (const float*)d_in[4];
    const float* sqk = (const float*)d_in[5];
    const float* aA  = (const float*)d_in[6];
    const float* Wup = (const float*)d_in[7];
    const float* Wg  = (const float*)d_in[8];
    const float* Wd  = (const float*)d_in[9];
    const float* su  = (const float*)d_in[10];
    const float* sv  = (const float*)d_in[11];
    const float* aM  = (const float*)d_in[12];

    char* ws = (char*)d_ws;
    short* wqkvT  = (short*)(ws + 0);          // [3072][1024]
    short* woT    = (short*)(ws + 6291456);    // [1024][1024]
    short* wugT   = (short*)(ws + 8388608);    // [5504][1024] interleaved up/gate
    short* wdownT = (short*)(ws + 19660800);   // [1024][2752]
    float* cost   = (float*)(ws + 25296896);
    float* sint   = (float*)(ws + 25559040);
    short* xbf    = (short*)(ws + 25821184);
    short* qn     = (short*)(ws + 34209792);
    short* kn     = (short*)(ws + 42598400);
    short* vt     = (short*)(ws + 50987008);   // [B][H][64][2048] bf16, 8MB
    short* opart  = (short*)(ws + 59375616);   // [2][4096][1024] bf16
    float* lsum   = (float*)(ws + 25296896);   // overwrites cost/sint (dead after qkv)
    short* ao     = (short*)(ws + 34209792);   // reuse qn
    short* hA0    = (short*)(ws + 42598400);   // reuse kn, bf16 8MB
    short* hA1    = (short*)(ws + 50987008);   // reuse vt, bf16 8MB
    float* h1f    = (float*)d_out;
    short* h1bf   = (short*)(ws + 25821184);   // reuse xbf
    short* wmlp   = (short*)(ws + 34209792);   // [4096][2752] bf16
    short* hM0    = (short*)(ws + 59375616);   // bf16 8MB (opart dead)
    short* hM1    = (short*)(ws + 67764224);   // bf16 8MB

    k_prep<<<16704, 256, 0, stream>>>(x, xbf, cost, sint, Wq, Wk, Wv, Wo, Wup, Wg, Wd,
                                      wqkvT, woT, wugT, wdownT);

    // QKV GEMM with fused rope + cosine-norm epilogue; v written directly transposed
    k_gemm128<3><<<768, 256, 0, stream>>>(xbf, wqkvT, nullptr, nullptr, 4096, 3072, 1024,
                                          32, 1, nullptr, nullptr, cost, sint, sqk, qn, kn, vt);
    k_attn<<<256, 512, 0, stream>>>(qn, kn, vt, opart, lsum);
    k_comb<<<4096, 256, 0, stream>>>(opart, lsum, ao);
    // Wo: split-K x2, bf16 partials
    k_gemm128<1><<<512, 256, 0, stream>>>(ao, woT, hA0, hA1, 4096, 1024, 1024,
                                          16, 2, nullptr, nullptr, nullptr, nullptr, nullptr,
                                          nullptr, nullptr, nullptr);
    k_resnorm<<<4096, 256, 0, stream>>>(x, hA0, hA1, aA, h1f, h1bf);
    // up+gate fused SwiGLU
    k_gemm128<2><<<1376, 256, 0, stream>>>(h1bf, wugT, wmlp, nullptr, 4096, 5504, 1024,
                                           32, 1, su, sv, nullptr, nullptr, nullptr,
                                           nullptr, nullptr, nullptr);
    // down: split-K x2, bf16 partials
    k_gemm128<1><<<512, 256, 0, stream>>>(wmlp, wdownT, hM0, hM1, 4096, 1024, 2752,
                                          43, 2, nullptr, nullptr, nullptr, nullptr, nullptr,
                                          nullptr, nullptr, nullptr);
    k_resnorm<<<4096, 256, 0, stream>>>(h1f, hM0, hM1, aM, (float*)d_out, (short*)nullptr);
}

// Round 17
// 262.114 us; speedup vs baseline: 1.1182x; 1.0556x over previous
//
#include <hip/hip_runtime.h>
#include <math.h>

#define DEVI __device__ __forceinline__

typedef __attribute__((ext_vector_type(4))) float f32x4;
typedef __attribute__((ext_vector_type(8))) short bf16x8;

// ---------- helpers ----------
DEVI short f2bf(float f) {                    // f32 -> bf16 (RNE)
    union { float f; unsigned u; } v; v.f = f;
    unsigned r = v.u + 0x7fffu + ((v.u >> 16) & 1u);
    return (short)(r >> 16);
}
DEVI float bf2f(short s) {
    union { unsigned u; float f; } v; v.u = ((unsigned)(unsigned short)s) << 16;
    return v.f;
}

DEVI f32x4 mfma16(bf16x8 a, bf16x8 b, f32x4 c) {
    return __builtin_amdgcn_mfma_f32_16x16x32_bf16(a, b, c, 0, 0, 0);
}

DEVI void gload16(const short* g, short* l) {  // async global->LDS, 16B/lane
    __builtin_amdgcn_global_load_lds((__attribute__((address_space(1))) void*)(g),
                                     (__attribute__((address_space(3))) void*)(l),
                                     16, 0, 0);
}

// ---------- merged preprocessing: cvt + freqs + all 7 weight transposes ----------
DEVI void trans_tile(const float* in, short* out, int R, int C, int Rpad, int Cpad,
                     int rmul, int radd, int bx, int by) {
    __shared__ float tile[32][33];
    int c0 = bx * 32, r0 = by * 32;
    int tx = threadIdx.x & 31, ty = threadIdx.x >> 5;
#pragma unroll
    for (int i = 0; i < 4; i++) {
        int r = r0 + ty + 8 * i, c = c0 + tx;
        tile[ty + 8 * i][tx] = (r < R && c < C) ? in[(size_t)r * C + c] : 0.0f;
    }
    __syncthreads();
#pragma unroll
    for (int i = 0; i < 4; i++) {
        int oc = c0 + ty + 8 * i;
        int orr = r0 + tx;
        if (oc < Cpad && orr < Rpad)
            out[(size_t)(oc * rmul + radd) * Rpad + orr] = f2bf(tile[tx][ty + 8 * i]);
    }
}

__global__ void k_prep(const float* __restrict__ x, short* __restrict__ xbf,
                       float* __restrict__ cost, float* __restrict__ sint,
                       const float* __restrict__ Wq, const float* __restrict__ Wk,
                       const float* __restrict__ Wv, const float* __restrict__ Wo,
                       const float* __restrict__ Wup, const float* __restrict__ Wg,
                       const float* __restrict__ Wd,
                       short* __restrict__ wqkvT, short* __restrict__ woT,
                       short* __restrict__ wugT, short* __restrict__ wdownT) {
    int b = blockIdx.x;
    if (b < 4096) {                         // x f32 -> bf16
        int i = (b * 256 + threadIdx.x) * 4;
        float4 v = *(const float4*)(x + i);
        short4 o;
        o.x = f2bf(v.x); o.y = f2bf(v.y); o.z = f2bf(v.z); o.w = f2bf(v.w);
        *(short4*)(xbf + i) = o;
    } else if (b < 4352) {                  // rope tables (f64 fidelity)
        int i = (b - 4096) * 256 + threadIdx.x;
        int s = i >> 5, j = i & 31;
        double inv = pow(10000.0, -(double)j / 32.0);
        double f = (double)s * inv;
        cost[i] = (float)cos(f);
        sint[i] = (float)sin(f);
    } else {
        int bb = b - 4352;
        if (bb < 4096) {                    // Wq/Wk/Wv/Wo
            int seg = bb >> 10, idx = bb & 1023;
            const float* in = seg == 0 ? Wq : seg == 1 ? Wk : seg == 2 ? Wv : Wo;
            short* out = seg == 0 ? wqkvT : seg == 1 ? wqkvT + 1048576
                       : seg == 2 ? wqkvT + 2097152 : woT;
            trans_tile(in, out, 1024, 1024, 1024, 1024, 1, 0, idx & 31, idx >> 5);
        } else if (bb < 9600) {             // Wup/Wg -> interleaved [5504][1024]
            int idx = bb - 4096;
            int seg = idx >= 2752;
            idx -= seg * 2752;
            trans_tile(seg ? Wg : Wup, wugT, 1024, 2730, 1024, 2752, 2, seg, idx % 86, idx / 86);
        } else {                            // Wd -> [1024][2752]
            int idx = bb - 9600;
            trans_tile(Wd, wdownT, 2730, 1024, 2752, 1024, 1, 0, idx & 31, idx >> 5);
        }
    }
}

// ---------- GEMM 128x128x32, single-buffer 16KB LDS, bank-swizzled, XCD-chunked, split-K ----------
// R17: __launch_bounds__(256, 4) caps regs at 128/wave (acc 64 AGPR + <=64 arch VGPR)
// -> 4 waves/SIMD resident (was 2 at 136 regs, the m69 128-reg granularity cliff).
// EPI: 0 = f32 out, 1 = bf16 out (both honor nsplit=2 -> Cv1), 2 = SwiGLU-interleaved,
//      3 = fused QKV epilogue: rope+cosine-norm+s_qk for q/k; v written DIRECTLY into
//          vt[b][h][d][s]. Grid 1D, gridDim.x % 8 == 0.
template <int EPI>
__launch_bounds__(256, 4)
__global__ void k_gemm128(const short* __restrict__ A, const short* __restrict__ BT,
                          void* __restrict__ Cv, void* __restrict__ Cv1,
                          int M, int N, int K, int nkblk, int nsplit,
                          const float* __restrict__ s_u, const float* __restrict__ s_v,
                          const float* __restrict__ cost, const float* __restrict__ sint,
                          const float* __restrict__ sqk,
                          short* __restrict__ qn, short* __restrict__ kn,
                          short* __restrict__ vtout) {
    __shared__ __align__(16) short As[128 * 32];
    __shared__ __align__(16) short Bs[128 * 32];
    const int t = threadIdx.x;
    const int w = t >> 6;
    const int lane = t & 63;
    const int lr = lane & 15, lg = lane >> 4;
    const int nwg = (int)gridDim.x;
    int wg = ((int)blockIdx.x & 7) * (nwg >> 3) + ((int)blockIdx.x >> 3);
    int half = 0;
    if (nsplit == 2) {
        const int per = nwg >> 1;
        half = wg >= per;
        wg -= half * per;
    }
    const int MT = M >> 7;
    const int m0 = (wg % MT) << 7;
    const int n0 = (wg / MT) << 7;
    const int koff = half * nkblk * 32;
    const int wr = (w >> 1) * 64, wc = (w & 1) * 64;

    const int srow = t >> 2;
    const int scol = (((t & 3) ^ ((srow >> 1) & 3)) << 3);
    const short* Ap0 = A + (size_t)(m0 + srow) * K + koff + scol;
    const short* Ap1 = Ap0 + (size_t)64 * K;
    const short* Bp0 = BT + (size_t)(n0 + srow) * K + koff + scol;
    const short* Bp1 = Bp0 + (size_t)64 * K;
    const int d0 = (w * 64) * 8;
    const int d1 = (w * 64 + 256) * 8;

    f32x4 acc[4][4];
#pragma unroll
    for (int m = 0; m < 4; m++)
#pragma unroll
        for (int n = 0; n < 4; n++)
            acc[m][n] = (f32x4){0.f, 0.f, 0.f, 0.f};

    for (int kt = 0; kt < nkblk; kt++) {
        if (kt) __syncthreads();          // all waves done reading tile kt-1
        gload16(Ap0, As + d0); gload16(Ap1, As + d1);
        gload16(Bp0, Bs + d0); gload16(Bp1, Bs + d1);
        Ap0 += 32; Ap1 += 32; Bp0 += 32; Bp1 += 32;
        __syncthreads();                  // vmcnt(0) drain -> tile resident
        bf16x8 af[4], bfr[4];
#pragma unroll
        for (int m = 0; m < 4; m++) {
            int rml = wr + m * 16 + lr;
            af[m] = *(const bf16x8*)&As[rml * 32 + ((lg ^ ((rml >> 1) & 3)) << 3)];
        }
#pragma unroll
        for (int n = 0; n < 4; n++) {
            int rnl = wc + n * 16 + lr;
            bfr[n] = *(const bf16x8*)&Bs[rnl * 32 + ((lg ^ ((rnl >> 1) & 3)) << 3)];
        }
#pragma unroll
        for (int m = 0; m < 4; m++)
#pragma unroll
            for (int n = 0; n < 4; n++)
                acc[m][n] = mfma16(af[m], bfr[n], acc[m][n]);
    }

    if (EPI == 3) {
        const int sector = n0 >> 10;     // 0=q, 1=k, 2=v
        if (sector == 2) {
            // write v directly into vt[b][h][d][s]: lane stores short4 (4 consecutive s)
#pragma unroll
            for (int m = 0; m < 4; m++)
#pragma unroll
                for (int n = 0; n < 4; n++) {
                    int col = n0 + wc + n * 16 + lr - 2048;
                    int hh = col >> 6, d = col & 63;
                    int brow = m0 + wr + m * 16 + lg * 4;
                    int bb = brow >> 11, s = brow & 2047;
                    short4 o4;
                    o4.x = f2bf(acc[m][n][0]); o4.y = f2bf(acc[m][n][1]);
                    o4.z = f2bf(acc[m][n][2]); o4.w = f2bf(acc[m][n][3]);
                    *(short4*)&vtout[((size_t)((bb * 16 + hh) * 64 + d)) * 2048 + s] = o4;
                }
        } else {
            const int h = ((n0 + wc) >> 6) & 15;
            float eff[4];
#pragma unroll
            for (int n = 0; n < 4; n++)
                eff[n] = sqk[h * 64 + n * 16 + lr] * 32.0f;   // s_qk * sqrt(DIM)
            short* dst = (sector == 0) ? qn : kn;
            const float extra = (sector == 0) ? 8.0f : 1.0f;  // sqrt(HD) folded into q
#pragma unroll
            for (int m = 0; m < 4; m++)
#pragma unroll
                for (int i = 0; i < 4; i++) {
                    int row = m0 + wr + m * 16 + lg * 4 + i;
                    int b = row >> 11, s = row & 2047;
                    float cs0 = cost[s * 32 + lr],      sn0 = sint[s * 32 + lr];
                    float cs1 = cost[s * 32 + 16 + lr], sn1 = sint[s * 32 + 16 + lr];
                    float vr0 = acc[m][0][i] * cs0 - acc[m][2][i] * sn0;
                    float vr1 = acc[m][1][i] * cs1 - acc[m][3][i] * sn1;
                    float vr2 = acc[m][2][i] * cs0 + acc[m][0][i] * sn0;
                    float vr3 = acc[m][3][i] * cs1 + acc[m][1][i] * sn1;
                    float ss = vr0 * vr0 + vr1 * vr1 + vr2 * vr2 + vr3 * vr3;
#pragma unroll
                    for (int o = 1; o < 16; o <<= 1)
                        ss += __shfl_xor(ss, o, 64);
                    float sc = extra / fmaxf(sqrtf(ss), 1e-6f);
                    size_t base = ((size_t)(b * 16 + h) * 2048 + s) * 64;
                    dst[base + lr]      = f2bf(vr0 * eff[0] * sc);
                    dst[base + 16 + lr] = f2bf(vr1 * eff[1] * sc);
                    dst[base + 32 + lr] = f2bf(vr2 * eff[2] * sc);
                    dst[base + 48 + lr] = f2bf(vr3 * eff[3] * sc);
                }
        }
        return;
    }

#pragma unroll
    for (int m = 0; m < 4; m++)
#pragma unroll
        for (int n = 0; n < 4; n++) {
            int row = m0 + wr + m * 16 + lg * 4;
            int col = n0 + wc + n * 16 + lr;
            if (EPI == 2) {
                int j = col >> 1;
                int jc = j < 2730 ? j : 2729;
                float su = s_u[jc];
                float sg = s_v[jc] * 32.0f;
#pragma unroll
                for (int i = 0; i < 4; i++) {
                    float own = acc[m][n][i];
                    float oth = __shfl_xor(own, 1, 64);
                    float u = (lr & 1) ? oth : own;
                    float g = (lr & 1) ? own : oth;
                    float uu = u * su;
                    float vv = g * sg;
                    float wv = uu * vv / (1.0f + expf(-vv));
                    if (!(lr & 1))
                        ((short*)Cv)[(size_t)(row + i) * (N >> 1) + j] = f2bf(wv);
                }
            } else {
                void* outp = half ? Cv1 : Cv;
#pragma unroll
                for (int i = 0; i < 4; i++) {
                    if (EPI == 1)
                        ((short*)outp)[(size_t)(row + i) * N + col] = f2bf(acc[m][n][i]);
                    else
                        ((float*)outp)[(size_t)(row + i) * N + col] = acc[m][n][i];
                }
            }
        }
}

// ---------- flash attention (causal), static-max softmax, balanced pair split ----------
__launch_bounds__(512)
__global__ void k_attn(const short* __restrict__ qn, const short* __restrict__ kn,
                       const short* __restrict__ vt, short* __restrict__ opart,
                       float* __restrict__ lsump) {
    __shared__ __align__(16) short Ks[2][64 * 64];
    __shared__ __align__(16) short Vs[2][64 * 64];
    __shared__ __align__(16) short Ps[8][32 * 64];
    const int t = threadIdx.x;
    const int w = t >> 6, lane = t & 63;
    const int bid = blockIdx.x;
    const int xcd = bid & 7, idx = bid >> 3;
    const int bhg = xcd + ((idx >> 3) << 3);          // 0..31
    const int pslot = idx & 7;
    const int h = bhg & 15, b = bhg >> 4;
    const int bh = b * 16 + h;
    const int lr = lane & 15, lg = lane >> 4;
    const short* Qb = qn + (size_t)bh * 2048 * 64;
    const short* Kb = kn + (size_t)bh * 2048 * 64;
    const short* Vb = vt + (size_t)bh * 64 * 2048;
    char* pwc = (char*)&Ps[w][0];

#define STAGE_KV(bi, kbase)                                                          \
    {                                                                                \
        int row = w * 8 + (lane >> 3);                                               \
        int scol = (lane & 7) ^ (row & 7);                                           \
        gload16(Kb + (size_t)((kbase) + row) * 64 + scol * 8,                        \
                &Ks[bi][(w * 8) * 64]);                                              \
        gload16(Vb + (size_t)row * 2048 + (kbase) + scol * 8,                        \
                &Vs[bi][(w * 8) * 64]);                                              \
    }

    for (int pc = 0; pc < 2; pc++) {
        const int qb = pc == 0 ? pslot : 7 - pslot;
        const int hf = pc;
        const int ktn = 2 * qb + 2;
        const int kt0 = hf * ktn, kt1 = kt0 + ktn;
        const int qw = qb * 256 + w * 32;

        bf16x8 qf[2][2];
#pragma unroll
        for (int mi = 0; mi < 2; mi++)
#pragma unroll
            for (int kk = 0; kk < 2; kk++)
                qf[mi][kk] = *(const bf16x8*)&Qb[(size_t)(qw + mi * 16 + lr) * 64 + kk * 32 + lg * 8];

        f32x4 oacc[2][4];
#pragma unroll
        for (int mi = 0; mi < 2; mi++)
#pragma unroll
            for (int ct = 0; ct < 4; ct++) oacc[mi][ct] = (f32x4){0.f, 0.f, 0.f, 0.f};
        float psum[2][4];
#pragma unroll
        for (int mi = 0; mi < 2; mi++)
#pragma unroll
            for (int i = 0; i < 4; i++) psum[mi][i] = 0.0f;

        if (pc) __syncthreads();          // all waves done with piece-0 LDS
        STAGE_KV(0, kt0 << 6);

        for (int kt = kt0; kt < kt1; kt++) {
            const int kbase = kt << 6;
            const int cur = (kt - kt0) & 1;
            __syncthreads();
            if (kt + 1 < kt1) STAGE_KV(cur ^ 1, (kt + 1) << 6);

            bf16x8 kf[4][2];
#pragma unroll
            for (int ni = 0; ni < 4; ni++)
#pragma unroll
                for (int kk = 0; kk < 2; kk++) {
                    int row = ni * 16 + lr;
                    kf[ni][kk] = *(const bf16x8*)&Ks[cur][row * 64 + (((kk * 4 + lg) ^ (row & 7)) << 3)];
                }
            f32x4 sv[2][4];
#pragma unroll
            for (int mi = 0; mi < 2; mi++)
#pragma unroll
                for (int ni = 0; ni < 4; ni++) {
                    f32x4 s = (f32x4){0.f, 0.f, 0.f, 0.f};
                    s = mfma16(qf[mi][0], kf[ni][0], s);
                    s = mfma16(qf[mi][1], kf[ni][1], s);
                    sv[mi][ni] = s;
                }
            if (kbase + 63 > qw) {
#pragma unroll
                for (int mi = 0; mi < 2; mi++)
#pragma unroll
                    for (int ni = 0; ni < 4; ni++)
#pragma unroll
                        for (int i = 0; i < 4; i++) {
                            int qg = qw + mi * 16 + lg * 4 + i;
                            int kg = kbase + ni * 16 + lr;
                            if (kg > qg) sv[mi][ni][i] = -3.0e38f;
                        }
            }
#pragma unroll
            for (int mi = 0; mi < 2; mi++) {
#pragma unroll
                for (int ni = 0; ni < 4; ni++)
#pragma unroll
                    for (int i = 0; i < 4; i++) {
                        float p = exp2f((sv[mi][ni][i] - 9.0f) * 1.44269504f);
                        sv[mi][ni][i] = p;
                        psum[mi][i] += p;
                    }
#pragma unroll
                for (int ni = 0; ni < 4; ni++)
#pragma unroll
                    for (int i = 0; i < 4; i++) {
                        int row = mi * 16 + lg * 4 + i;
                        int col = ni * 16 + lr;
                        unsigned off = (unsigned)(row * 128 + col * 2) ^ ((unsigned)(row & 7) << 4);
                        *(short*)(pwc + off) = f2bf(sv[mi][ni][i]);
                    }
            }
            bf16x8 pa[2][2];
#pragma unroll
            for (int mi = 0; mi < 2; mi++)
#pragma unroll
                for (int kk = 0; kk < 2; kk++) {
                    int row = mi * 16 + lr;
                    unsigned off = (unsigned)(row * 128 + kk * 64 + lg * 16) ^ ((unsigned)(row & 7) << 4);
                    pa[mi][kk] = *(const bf16x8*)(pwc + off);
                }
            bf16x8 vf[4][2];
#pragma unroll
            for (int ct = 0; ct < 4; ct++)
#pragma unroll
                for (int kk = 0; kk < 2; kk++) {
                    int row = ct * 16 + lr;
                    vf[ct][kk] = *(const bf16x8*)&Vs[cur][row * 64 + (((kk * 4 + lg) ^ (row & 7)) << 3)];
                }
#pragma unroll
            for (int mi = 0; mi < 2; mi++)
#pragma unroll
                for (int ct = 0; ct < 4; ct++) {
                    oacc[mi][ct] = mfma16(pa[mi][0], vf[ct][0], oacc[mi][ct]);
                    oacc[mi][ct] = mfma16(pa[mi][1], vf[ct][1], oacc[mi][ct]);
                }
        }

#pragma unroll
        for (int o = 1; o < 16; o <<= 1)
#pragma unroll
            for (int mi = 0; mi < 2; mi++)
#pragma unroll
                for (int i = 0; i < 4; i++)
                    psum[mi][i] += __shfl_xor(psum[mi][i], o, 64);

        short* aob = opart + (size_t)hf * 4096 * 1024 + ((size_t)(b * 2048 + qw) * 1024) + h * 64;
#pragma unroll
        for (int mi = 0; mi < 2; mi++)
#pragma unroll
            for (int ct = 0; ct < 4; ct++)
#pragma unroll
                for (int i = 0; i < 4; i++) {
                    int q = mi * 16 + lg * 4 + i;
                    aob[(size_t)q * 1024 + ct * 16 + lr] = f2bf(oacc[mi][ct][i]);
                }
        if (lr == 0) {
#pragma unroll
            for (int mi = 0; mi < 2; mi++)
#pragma unroll
                for (int i = 0; i < 4; i++)
                    lsump[hf * 65536 + bh * 2048 + qw + mi * 16 + lg * 4 + i] = psum[mi][i];
        }
    }
#undef STAGE_KV
}

// ---------- combine split-K partials: ao = (O0+O1)/(l0+l1), bf16 ----------
__global__ void k_comb(const short* __restrict__ op, const float* __restrict__ ls,
                       short* __restrict__ ao) {
    int i = (blockIdx.x * 256 + threadIdx.x) * 4;
    int row = i >> 10, col = i & 1023;
    int idx = ((row >> 11) * 16 + (col >> 6)) * 2048 + (row & 2047);
    float rl = 1.0f / (ls[idx] + ls[65536 + idx]);
    short4 a = *(const short4*)(op + i);
    short4 c = *(const short4*)(op + 4194304 + i);
    short4 o;
    o.x = f2bf((bf2f(a.x) + bf2f(c.x)) * rl);
    o.y = f2bf((bf2f(a.y) + bf2f(c.y)) * rl);
    o.z = f2bf((bf2f(a.z) + bf2f(c.z)) * rl);
    o.w = f2bf((bf2f(a.w) + bf2f(c.w)) * rl);
    *(short4*)(ao + i) = o;
}

// ---------- residual + double cosine_norm; pre = pre0 + pre1 (bf16 partials) ----------
__global__ void k_resnorm(const float* base, const short* __restrict__ pre0,
                          const short* __restrict__ pre1,
                          const float* __restrict__ alpha, float* outf,
                          short* __restrict__ outb) {
    __shared__ float red1[4], red2[4];
    int row = blockIdx.x;
    int t = threadIdx.x;
    int w = t >> 6;
    float4 p;
    short4 a = *(const short4*)(pre0 + (size_t)row * 1024 + t * 4);
    short4 c = *(const short4*)(pre1 + (size_t)row * 1024 + t * 4);
    p.x = bf2f(a.x) + bf2f(c.x); p.y = bf2f(a.y) + bf2f(c.y);
    p.z = bf2f(a.z) + bf2f(c.z); p.w = bf2f(a.w) + bf2f(c.w);
    float ss = p.x * p.x + p.y * p.y + p.z * p.z + p.w * p.w;
#pragma unroll
    for (int o = 1; o < 64; o <<= 1) ss += __shfl_xor(ss, o, 64);
    if ((t & 63) == 0) red1[w] = ss;
    __syncthreads();
    float inv1 = 1.0f / fmaxf(sqrtf(red1[0] + red1[1] + red1[2] + red1[3]), 1e-6f);
    const float4 bx = *(const float4*)(base + (size_t)row * 1024 + t * 4);
    const float4 av = *(const float4*)(alpha + t * 4);
    float4 tm;
    tm.x = bx.x + av.x * (p.x * inv1 - bx.x);
    tm.y = bx.y + av.y * (p.y * inv1 - bx.y);
    tm.z = bx.z + av.z * (p.z * inv1 - bx.z);
    tm.w = bx.w + av.w * (p.w * inv1 - bx.w);
    float ss2 = tm.x * tm.x + tm.y * tm.y + tm.z * tm.z + tm.w * tm.w;
#pragma unroll
    for (int o = 1; o < 64; o <<= 1) ss2 += __shfl_xor(ss2, o, 64);
    if ((t & 63) == 0) red2[w] = ss2;
    __syncthreads();
    float inv2 = 1.0f / fmaxf(sqrtf(red2[0] + red2[1] + red2[2] + red2[3]), 1e-6f);
    float4 hv;
    hv.x = tm.x * inv2; hv.y = tm.y * inv2; hv.z = tm.z * inv2; hv.w = tm.w * inv2;
    if (outf) *(float4*)(outf + (size_t)row * 1024 + t * 4) = hv;
    if (outb) {
        short4 o4;
        o4.x = f2bf(hv.x); o4.y = f2bf(hv.y); o4.z = f2bf(hv.z); o4.w = f2bf(hv.w);
        *(short4*)(outb + (size_t)row * 1024 + t * 4) = o4;
    }
}

// ---------- launch ----------
// Workspace (lifetime-overlaid, peak ~75.9 MB; 76,152,832 known-safe):
//  [0, 25296896)  weights bf16^T                                     (whole launch)
//  25296896  cost/sint (prep->qkv) -> lsum 0.5MB (attn->comb)
//  25821184  xbf(prep->qkv) -> h1bf(rn1->swiglu)                               8 MB
//  34209792  qn(qkv->attn) -> ao(comb->wo) -> wmlp(swiglu->down, 22.5MB ..56754176)
//  42598400  kn(qkv->attn) -> hA0 bf16 8MB(wo->rn1)
//  50987008  vt(qkv->attn) -> hA1 bf16 8MB(wo->rn1)
//  59375616  opart[2] bf16 16MB(attn->comb) -> hM0 bf16 8MB(down->rn2)
//  67764224  hM1 bf16 8MB(down->rn2)
extern "C" void kernel_launch(void* const* d_in, const int* in_sizes, int n_in,
                              void* d_out, int out_size, void* d_ws, size_t ws_size,
                              hipStream_t stream) {
    (void)in_sizes; (void)n_in; (void)out_size; (void)ws_size;
    const float* x   = (const float*)d_in[0];
    const float* Wq  = (const float*)d_in[1];
    const float* Wk  = (const float*)d_in[2];
    const float* Wv  = (const float*)d_in[3];
    const float* Wo  = (const float*)d_in[4];
    const float* sqk = (const float*)d_in[5];
    const float* aA  = (const float*)d_in[6];
    const float* Wup = (const float*)d_in[7];
    const float* Wg  = (const float*)d_in[8];
    const float* Wd  = (const float*)d_in[9];
    const float* su  = (const float*)d_in[10];
    const float* sv  = (const float*)d_in[11];
    const float* aM  = (const float*)d_in[12];

    char* ws = (char*)d_ws;
    short* wqkvT  = (short*)(ws + 0);          // [3072][1024]
    short* woT    = (short*)(ws + 6291456);    // [1024][1024]
    short* wugT   = (short*)(ws + 8388608);    // [5504][1024] interleaved up/gate
    short* wdownT = (short*)(ws + 19660800);   // [1024][2752]
    float* cost   = (float*)(ws + 25296896);
    float* sint   = (float*)(ws + 25559040);
    short* xbf    = (short*)(ws + 25821184);
    short* qn     = (short*)(ws + 34209792);
    short* kn     = (short*)(ws + 42598400);
    short* vt     = (short*)(ws + 50987008);   // [B][H][64][2048] bf16, 8MB
    short* opart  = (short*)(ws + 59375616);   // [2][4096][1024] bf16
    float* lsum   = (float*)(ws + 25296896);   // overwrites cost/sint (dead after qkv)
    short* ao     = (short*)(ws + 34209792);   // reuse qn
    short* hA0    = (short*)(ws + 42598400);   // reuse kn, bf16 8MB
    short* hA1    = (short*)(ws + 50987008);   // reuse vt, bf16 8MB
    float* h1f    = (float*)d_out;
    short* h1bf   = (short*)(ws + 25821184);   // reuse xbf
    short* wmlp   = (short*)(ws + 34209792);   // [4096][2752] bf16
    short* hM0    = (short*)(ws + 59375616);   // bf16 8MB (opart dead)
    short* hM1    = (short*)(ws + 67764224);   // bf16 8MB

    k_prep<<<16704, 256, 0, stream>>>(x, xbf, cost, sint, Wq, Wk, Wv, Wo, Wup, Wg, Wd,
                                      wqkvT, woT, wugT, wdownT);

    // QKV GEMM with fused rope + cosine-norm epilogue; v written directly transposed
    k_gemm128<3><<<768, 256, 0, stream>>>(xbf, wqkvT, nullptr, nullptr, 4096, 3072, 1024,
                                          32, 1, nullptr, nullptr, cost, sint, sqk, qn, kn, vt);
    k_attn<<<256, 512, 0, stream>>>(qn, kn, vt, opart, lsum);
    k_comb<<<4096, 256, 0, stream>>>(opart, lsum, ao);
    // Wo: split-K x2, bf16 partials
    k_gemm128<1><<<512, 256, 0, stream>>>(ao, woT, hA0, hA1, 4096, 1024, 1024,
                                          16, 2, nullptr, nullptr, nullptr, nullptr, nullptr,
                                          nullptr, nullptr, nullptr);
    k_resnorm<<<4096, 256, 0, stream>>>(x, hA0, hA1, aA, h1f, h1bf);
    // up+gate fused SwiGLU
    k_gemm128<2><<<1376, 256, 0, stream>>>(h1bf, wugT, wmlp, nullptr, 4096, 5504, 1024,
                                           32, 1, su, sv, nullptr, nullptr, nullptr,
                                           nullptr, nullptr, nullptr);
    // down: split-K x2, bf16 partials
    k_gemm128<1><<<512, 256, 0, stream>>>(wmlp, wdownT, hM0, hM1, 4096, 1024, 2752,
                                          43, 2, nullptr, nullptr, nullptr, nullptr, nullptr,
                                          nullptr, nullptr, nullptr);
    k_resnorm<<<4096, 256, 0, stream>>>(h1f, hM0, hM1, aM, (float*)d_out, (short*)nullptr);
}

// Round 18
// 241.616 us; speedup vs baseline: 1.2130x; 1.0848x over previous
//
#include <hip/hip_runtime.h>
#include <math.h>

#define DEVI __device__ __forceinline__

typedef __attribute__((ext_vector_type(4))) float f32x4;
typedef __attribute__((ext_vector_type(8))) short bf16x8;

// ---------- helpers ----------
DEVI short f2bf(float f) {                    // f32 -> bf16 (RNE)
    union { float f; unsigned u; } v; v.f = f;
    unsigned r = v.u + 0x7fffu + ((v.u >> 16) & 1u);
    return (short)(r >> 16);
}
DEVI float bf2f(short s) {
    union { unsigned u; float f; } v; v.u = ((unsigned)(unsigned short)s) << 16;
    return v.f;
}

DEVI f32x4 mfma16(bf16x8 a, bf16x8 b, f32x4 c) {
    return __builtin_amdgcn_mfma_f32_16x16x32_bf16(a, b, c, 0, 0, 0);
}

DEVI void gload16(const short* g, short* l) {  // async global->LDS, 16B/lane
    __builtin_amdgcn_global_load_lds((__attribute__((address_space(1))) void*)(g),
                                     (__attribute__((address_space(3))) void*)(l),
                                     16, 0, 0);
}

// ---------- merged preprocessing: cvt + freqs + all 7 weight transposes ----------
DEVI void trans_tile(const float* in, short* out, int R, int C, int Rpad, int Cpad,
                     int rmul, int radd, int bx, int by) {
    __shared__ float tile[32][33];
    int c0 = bx * 32, r0 = by * 32;
    int tx = threadIdx.x & 31, ty = threadIdx.x >> 5;
#pragma unroll
    for (int i = 0; i < 4; i++) {
        int r = r0 + ty + 8 * i, c = c0 + tx;
        tile[ty + 8 * i][tx] = (r < R && c < C) ? in[(size_t)r * C + c] : 0.0f;
    }
    __syncthreads();
#pragma unroll
    for (int i = 0; i < 4; i++) {
        int oc = c0 + ty + 8 * i;
        int orr = r0 + tx;
        if (oc < Cpad && orr < Rpad)
            out[(size_t)(oc * rmul + radd) * Rpad + orr] = f2bf(tile[tx][ty + 8 * i]);
    }
}

__global__ void k_prep(const float* __restrict__ x, short* __restrict__ xbf,
                       float* __restrict__ cost, float* __restrict__ sint,
                       const float* __restrict__ Wq, const float* __restrict__ Wk,
                       const float* __restrict__ Wv, const float* __restrict__ Wo,
                       const float* __restrict__ Wup, const float* __restrict__ Wg,
                       const float* __restrict__ Wd,
                       short* __restrict__ wqkvT, short* __restrict__ woT,
                       short* __restrict__ wugT, short* __restrict__ wdownT) {
    int b = blockIdx.x;
    if (b < 4096) {                         // x f32 -> bf16
        int i = (b * 256 + threadIdx.x) * 4;
        float4 v = *(const float4*)(x + i);
        short4 o;
        o.x = f2bf(v.x); o.y = f2bf(v.y); o.z = f2bf(v.z); o.w = f2bf(v.w);
        *(short4*)(xbf + i) = o;
    } else if (b < 4352) {                  // rope tables (f64 fidelity)
        int i = (b - 4096) * 256 + threadIdx.x;
        int s = i >> 5, j = i & 31;
        double inv = pow(10000.0, -(double)j / 32.0);
        double f = (double)s * inv;
        cost[i] = (float)cos(f);
        sint[i] = (float)sin(f);
    } else {
        int bb = b - 4352;
        if (bb < 4096) {                    // Wq/Wk/Wv/Wo
            int seg = bb >> 10, idx = bb & 1023;
            const float* in = seg == 0 ? Wq : seg == 1 ? Wk : seg == 2 ? Wv : Wo;
            short* out = seg == 0 ? wqkvT : seg == 1 ? wqkvT + 1048576
                       : seg == 2 ? wqkvT + 2097152 : woT;
            trans_tile(in, out, 1024, 1024, 1024, 1024, 1, 0, idx & 31, idx >> 5);
        } else if (bb < 9600) {             // Wup/Wg -> interleaved [5504][1024]
            int idx = bb - 4096;
            int seg = idx >= 2752;
            idx -= seg * 2752;
            trans_tile(seg ? Wg : Wup, wugT, 1024, 2730, 1024, 2752, 2, seg, idx % 86, idx / 86);
        } else {                            // Wd -> [1024][2752]
            int idx = bb - 9600;
            trans_tile(Wd, wdownT, 2730, 1024, 2752, 1024, 1, 0, idx & 31, idx >> 5);
        }
    }
}

// ---------- GEMM 128x128xBK64, single-buffer 32KB LDS, bank-swizzled, XCD-chunked, split-K ----
// R18: BK 32->64 halves barrier-pairs per GEMM (drain amortization); one barrier pair
// per 64-wide K-tile, two K=32 MFMA sub-steps. Rows are 64 shorts (128 B): chunk c of
// row r stored at physical chunk c^(r&7) (8 chunks -> all 32 banks, reads 2-way=free);
// staging source pre-swizzled with the same involution (both-sides rule).
// __launch_bounds__(256,4): <=128 regs/wave -> 4 waves/SIMD (R17 win kept).
// nkblk counts 64-wide tiles; nsplit=2: half0 = nkblk tiles, half1 = K/64 - nkblk.
// EPI: 0 f32, 1 bf16 (honor split -> Cv1), 2 SwiGLU-interleaved, 3 fused QKV epilogue.
template <int EPI>
__launch_bounds__(256, 4)
__global__ void k_gemm128(const short* __restrict__ A, const short* __restrict__ BT,
                          void* __restrict__ Cv, void* __restrict__ Cv1,
                          int M, int N, int K, int nkblk, int nsplit,
                          const float* __restrict__ s_u, const float* __restrict__ s_v,
                          const float* __restrict__ cost, const float* __restrict__ sint,
                          const float* __restrict__ sqk,
                          short* __restrict__ qn, short* __restrict__ kn,
                          short* __restrict__ vtout) {
    __shared__ __align__(16) short As[128 * 64];
    __shared__ __align__(16) short Bs[128 * 64];
    const int t = threadIdx.x;
    const int w = t >> 6;
    const int lane = t & 63;
    const int lr = lane & 15, lg = lane >> 4;
    const int nwg = (int)gridDim.x;
    int wg = ((int)blockIdx.x & 7) * (nwg >> 3) + ((int)blockIdx.x >> 3);
    int half = 0;
    if (nsplit == 2) {
        const int per = nwg >> 1;
        half = wg >= per;
        wg -= half * per;
    }
    const int MT = M >> 7;
    const int m0 = (wg % MT) << 7;
    const int n0 = (wg / MT) << 7;
    const int koff = half * nkblk * 64;
    const int ntile = (nsplit == 2 && half) ? (K >> 6) - nkblk : nkblk;
    const int wr = (w >> 1) * 64, wc = (w & 1) * 64;

    // staging: thread t -> rows (t>>3)+j*32 (j=0..3), chunk cg=t&7, swizzled source col
    const int srow = t >> 3;
    const int scol = (((t & 7) ^ (srow & 7)) << 3);
    const short* Ap = A + (size_t)(m0 + srow) * K + koff + scol;
    const short* Bp = BT + (size_t)(n0 + srow) * K + koff + scol;
    const size_t rstep = (size_t)32 * K;
    const int dW = (w * 8) * 64;          // wave-uniform LDS dest (shorts), + lane*8 in HW

    f32x4 acc[4][4];
#pragma unroll
    for (int m = 0; m < 4; m++)
#pragma unroll
        for (int n = 0; n < 4; n++)
            acc[m][n] = (f32x4){0.f, 0.f, 0.f, 0.f};

    for (int kt = 0; kt < ntile; kt++) {
        if (kt) __syncthreads();          // all waves done reading tile kt-1
#pragma unroll
        for (int j = 0; j < 4; j++) {
            gload16(Ap + j * rstep, As + dW + j * 2048);
            gload16(Bp + j * rstep, Bs + dW + j * 2048);
        }
        Ap += 64; Bp += 64;
        __syncthreads();                  // vmcnt(0) drain -> tile resident
#pragma unroll
        for (int ks = 0; ks < 2; ks++) {
            bf16x8 af[4], bfr[4];
#pragma unroll
            for (int m = 0; m < 4; m++) {
                int rml = wr + m * 16 + lr;
                af[m] = *(const bf16x8*)&As[rml * 64 + (((ks * 4 + lg) ^ (rml & 7)) << 3)];
            }
#pragma unroll
            for (int n = 0; n < 4; n++) {
                int rnl = wc + n * 16 + lr;
                bfr[n] = *(const bf16x8*)&Bs[rnl * 64 + (((ks * 4 + lg) ^ (rnl & 7)) << 3)];
            }
#pragma unroll
            for (int m = 0; m < 4; m++)
#pragma unroll
                for (int n = 0; n < 4; n++)
                    acc[m][n] = mfma16(af[m], bfr[n], acc[m][n]);
        }
    }

    if (EPI == 3) {
        const int sector = n0 >> 10;     // 0=q, 1=k, 2=v
        if (sector == 2) {
            // write v directly into vt[b][h][d][s]: lane stores short4 (4 consecutive s)
#pragma unroll
            for (int m = 0; m < 4; m++)
#pragma unroll
                for (int n = 0; n < 4; n++) {
                    int col = n0 + wc + n * 16 + lr - 2048;
                    int hh = col >> 6, d = col & 63;
                    int brow = m0 + wr + m * 16 + lg * 4;
                    int bb = brow >> 11, s = brow & 2047;
                    short4 o4;
                    o4.x = f2bf(acc[m][n][0]); o4.y = f2bf(acc[m][n][1]);
                    o4.z = f2bf(acc[m][n][2]); o4.w = f2bf(acc[m][n][3]);
                    *(short4*)&vtout[((size_t)((bb * 16 + hh) * 64 + d)) * 2048 + s] = o4;
                }
        } else {
            const int h = ((n0 + wc) >> 6) & 15;
            float eff[4];
#pragma unroll
            for (int n = 0; n < 4; n++)
                eff[n] = sqk[h * 64 + n * 16 + lr] * 32.0f;   // s_qk * sqrt(DIM)
            short* dst = (sector == 0) ? qn : kn;
            const float extra = (sector == 0) ? 8.0f : 1.0f;  // sqrt(HD) folded into q
#pragma unroll
            for (int m = 0; m < 4; m++)
#pragma unroll
                for (int i = 0; i < 4; i++) {
                    int row = m0 + wr + m * 16 + lg * 4 + i;
                    int b = row >> 11, s = row & 2047;
                    float cs0 = cost[s * 32 + lr],      sn0 = sint[s * 32 + lr];
                    float cs1 = cost[s * 32 + 16 + lr], sn1 = sint[s * 32 + 16 + lr];
                    float vr0 = acc[m][0][i] * cs0 - acc[m][2][i] * sn0;
                    float vr1 = acc[m][1][i] * cs1 - acc[m][3][i] * sn1;
                    float vr2 = acc[m][2][i] * cs0 + acc[m][0][i] * sn0;
                    float vr3 = acc[m][3][i] * cs1 + acc[m][1][i] * sn1;
                    float ss = vr0 * vr0 + vr1 * vr1 + vr2 * vr2 + vr3 * vr3;
#pragma unroll
                    for (int o = 1; o < 16; o <<= 1)
                        ss += __shfl_xor(ss, o, 64);
                    float sc = extra / fmaxf(sqrtf(ss), 1e-6f);
                    size_t base = ((size_t)(b * 16 + h) * 2048 + s) * 64;
                    dst[base + lr]      = f2bf(vr0 * eff[0] * sc);
                    dst[base + 16 + lr] = f2bf(vr1 * eff[1] * sc);
                    dst[base + 32 + lr] = f2bf(vr2 * eff[2] * sc);
                    dst[base + 48 + lr] = f2bf(vr3 * eff[3] * sc);
                }
        }
        return;
    }

#pragma unroll
    for (int m = 0; m < 4; m++)
#pragma unroll
        for (int n = 0; n < 4; n++) {
            int row = m0 + wr + m * 16 + lg * 4;
            int col = n0 + wc + n * 16 + lr;
            if (EPI == 2) {
                int j = col >> 1;
                int jc = j < 2730 ? j : 2729;
                float su = s_u[jc];
                float sg = s_v[jc] * 32.0f;
#pragma unroll
                for (int i = 0; i < 4; i++) {
                    float own = acc[m][n][i];
                    float oth = __shfl_xor(own, 1, 64);
                    float u = (lr & 1) ? oth : own;
                    float g = (lr & 1) ? own : oth;
                    float uu = u * su;
                    float vv = g * sg;
                    float wv = uu * vv / (1.0f + expf(-vv));
                    if (!(lr & 1))
                        ((short*)Cv)[(size_t)(row + i) * (N >> 1) + j] = f2bf(wv);
                }
            } else {
                void* outp = half ? Cv1 : Cv;
#pragma unroll
                for (int i = 0; i < 4; i++) {
                    if (EPI == 1)
                        ((short*)outp)[(size_t)(row + i) * N + col] = f2bf(acc[m][n][i]);
                    else
                        ((float*)outp)[(size_t)(row + i) * N + col] = acc[m][n][i];
                }
            }
        }
}

// ---------- flash attention (causal), static-max softmax, balanced pair split ----------
__launch_bounds__(512)
__global__ void k_attn(const short* __restrict__ qn, const short* __restrict__ kn,
                       const short* __restrict__ vt, short* __restrict__ opart,
                       float* __restrict__ lsump) {
    __shared__ __align__(16) short Ks[2][64 * 64];
    __shared__ __align__(16) short Vs[2][64 * 64];
    __shared__ __align__(16) short Ps[8][32 * 64];
    const int t = threadIdx.x;
    const int w = t >> 6, lane = t & 63;
    const int bid = blockIdx.x;
    const int xcd = bid & 7, idx = bid >> 3;
    const int bhg = xcd + ((idx >> 3) << 3);          // 0..31
    const int pslot = idx & 7;
    const int h = bhg & 15, b = bhg >> 4;
    const int bh = b * 16 + h;
    const int lr = lane & 15, lg = lane >> 4;
    const short* Qb = qn + (size_t)bh * 2048 * 64;
    const short* Kb = kn + (size_t)bh * 2048 * 64;
    const short* Vb = vt + (size_t)bh * 64 * 2048;
    char* pwc = (char*)&Ps[w][0];

#define STAGE_KV(bi, kbase)                                                          \
    {                                                                                \
        int row = w * 8 + (lane >> 3);                                               \
        int scol = (lane & 7) ^ (row & 7);                                           \
        gload16(Kb + (size_t)((kbase) + row) * 64 + scol * 8,                        \
                &Ks[bi][(w * 8) * 64]);                                              \
        gload16(Vb + (size_t)row * 2048 + (kbase) + scol * 8,                        \
                &Vs[bi][(w * 8) * 64]);                                              \
    }

    for (int pc = 0; pc < 2; pc++) {
        const int qb = pc == 0 ? pslot : 7 - pslot;
        const int hf = pc;
        const int ktn = 2 * qb + 2;
        const int kt0 = hf * ktn, kt1 = kt0 + ktn;
        const int qw = qb * 256 + w * 32;

        bf16x8 qf[2][2];
#pragma unroll
        for (int mi = 0; mi < 2; mi++)
#pragma unroll
            for (int kk = 0; kk < 2; kk++)
                qf[mi][kk] = *(const bf16x8*)&Qb[(size_t)(qw + mi * 16 + lr) * 64 + kk * 32 + lg * 8];

        f32x4 oacc[2][4];
#pragma unroll
        for (int mi = 0; mi < 2; mi++)
#pragma unroll
            for (int ct = 0; ct < 4; ct++) oacc[mi][ct] = (f32x4){0.f, 0.f, 0.f, 0.f};
        float psum[2][4];
#pragma unroll
        for (int mi = 0; mi < 2; mi++)
#pragma unroll
            for (int i = 0; i < 4; i++) psum[mi][i] = 0.0f;

        if (pc) __syncthreads();          // all waves done with piece-0 LDS
        STAGE_KV(0, kt0 << 6);

        for (int kt = kt0; kt < kt1; kt++) {
            const int kbase = kt << 6;
            const int cur = (kt - kt0) & 1;
            __syncthreads();
            if (kt + 1 < kt1) STAGE_KV(cur ^ 1, (kt + 1) << 6);

            bf16x8 kf[4][2];
#pragma unroll
            for (int ni = 0; ni < 4; ni++)
#pragma unroll
                for (int kk = 0; kk < 2; kk++) {
                    int row = ni * 16 + lr;
                    kf[ni][kk] = *(const bf16x8*)&Ks[cur][row * 64 + (((kk * 4 + lg) ^ (row & 7)) << 3)];
                }
            f32x4 sv[2][4];
#pragma unroll
            for (int mi = 0; mi < 2; mi++)
#pragma unroll
                for (int ni = 0; ni < 4; ni++) {
                    f32x4 s = (f32x4){0.f, 0.f, 0.f, 0.f};
                    s = mfma16(qf[mi][0], kf[ni][0], s);
                    s = mfma16(qf[mi][1], kf[ni][1], s);
                    sv[mi][ni] = s;
                }
            if (kbase + 63 > qw) {
#pragma unroll
                for (int mi = 0; mi < 2; mi++)
#pragma unroll
                    for (int ni = 0; ni < 4; ni++)
#pragma unroll
                        for (int i = 0; i < 4; i++) {
                            int qg = qw + mi * 16 + lg * 4 + i;
                            int kg = kbase + ni * 16 + lr;
                            if (kg > qg) sv[mi][ni][i] = -3.0e38f;
                        }
            }
#pragma unroll
            for (int mi = 0; mi < 2; mi++) {
#pragma unroll
                for (int ni = 0; ni < 4; ni++)
#pragma unroll
                    for (int i = 0; i < 4; i++) {
                        float p = exp2f((sv[mi][ni][i] - 9.0f) * 1.44269504f);
                        sv[mi][ni][i] = p;
                        psum[mi][i] += p;
                    }
#pragma unroll
                for (int ni = 0; ni < 4; ni++)
#pragma unroll
                    for (int i = 0; i < 4; i++) {
                        int row = mi * 16 + lg * 4 + i;
                        int col = ni * 16 + lr;
                        unsigned off = (unsigned)(row * 128 + col * 2) ^ ((unsigned)(row & 7) << 4);
                        *(short*)(pwc + off) = f2bf(sv[mi][ni][i]);
                    }
            }
            bf16x8 pa[2][2];
#pragma unroll
            for (int mi = 0; mi < 2; mi++)
#pragma unroll
                for (int kk = 0; kk < 2; kk++) {
                    int row = mi * 16 + lr;
                    unsigned off = (unsigned)(row * 128 + kk * 64 + lg * 16) ^ ((unsigned)(row & 7) << 4);
                    pa[mi][kk] = *(const bf16x8*)(pwc + off);
                }
            bf16x8 vf[4][2];
#pragma unroll
            for (int ct = 0; ct < 4; ct++)
#pragma unroll
                for (int kk = 0; kk < 2; kk++) {
                    int row = ct * 16 + lr;
                    vf[ct][kk] = *(const bf16x8*)&Vs[cur][row * 64 + (((kk * 4 + lg) ^ (row & 7)) << 3)];
                }
#pragma unroll
            for (int mi = 0; mi < 2; mi++)
#pragma unroll
                for (int ct = 0; ct < 4; ct++) {
                    oacc[mi][ct] = mfma16(pa[mi][0], vf[ct][0], oacc[mi][ct]);
                    oacc[mi][ct] = mfma16(pa[mi][1], vf[ct][1], oacc[mi][ct]);
                }
        }

#pragma unroll
        for (int o = 1; o < 16; o <<= 1)
#pragma unroll
            for (int mi = 0; mi < 2; mi++)
#pragma unroll
                for (int i = 0; i < 4; i++)
                    psum[mi][i] += __shfl_xor(psum[mi][i], o, 64);

        short* aob = opart + (size_t)hf * 4096 * 1024 + ((size_t)(b * 2048 + qw) * 1024) + h * 64;
#pragma unroll
        for (int mi = 0; mi < 2; mi++)
#pragma unroll
            for (int ct = 0; ct < 4; ct++)
#pragma unroll
                for (int i = 0; i < 4; i++) {
                    int q = mi * 16 + lg * 4 + i;
                    aob[(size_t)q * 1024 + ct * 16 + lr] = f2bf(oacc[mi][ct][i]);
                }
        if (lr == 0) {
#pragma unroll
            for (int mi = 0; mi < 2; mi++)
#pragma unroll
                for (int i = 0; i < 4; i++)
                    lsump[hf * 65536 + bh * 2048 + qw + mi * 16 + lg * 4 + i] = psum[mi][i];
        }
    }
#undef STAGE_KV
}

// ---------- combine split-K partials: ao = (O0+O1)/(l0+l1), bf16 ----------
__global__ void k_comb(const short* __restrict__ op, const float* __restrict__ ls,
                       short* __restrict__ ao) {
    int i = (blockIdx.x * 256 + threadIdx.x) * 4;
    int row = i >> 10, col = i & 1023;
    int idx = ((row >> 11) * 16 + (col >> 6)) * 2048 + (row & 2047);
    float rl = 1.0f / (ls[idx] + ls[65536 + idx]);
    short4 a = *(const short4*)(op + i);
    short4 c = *(const short4*)(op + 4194304 + i);
    short4 o;
    o.x = f2bf((bf2f(a.x) + bf2f(c.x)) * rl);
    o.y = f2bf((bf2f(a.y) + bf2f(c.y)) * rl);
    o.z = f2bf((bf2f(a.z) + bf2f(c.z)) * rl);
    o.w = f2bf((bf2f(a.w) + bf2f(c.w)) * rl);
    *(short4*)(ao + i) = o;
}

// ---------- residual + double cosine_norm; pre = pre0 + pre1 (bf16 partials) ----------
__global__ void k_resnorm(const float* base, const short* __restrict__ pre0,
                          const short* __restrict__ pre1,
                          const float* __restrict__ alpha, float* outf,
                          short* __restrict__ outb) {
    __shared__ float red1[4], red2[4];
    int row = blockIdx.x;
    int t = threadIdx.x;
    int w = t >> 6;
    float4 p;
    short4 a = *(const short4*)(pre0 + (size_t)row * 1024 + t * 4);
    short4 c = *(const short4*)(pre1 + (size_t)row * 1024 + t * 4);
    p.x = bf2f(a.x) + bf2f(c.x); p.y = bf2f(a.y) + bf2f(c.y);
    p.z = bf2f(a.z) + bf2f(c.z); p.w = bf2f(a.w) + bf2f(c.w);
    float ss = p.x * p.x + p.y * p.y + p.z * p.z + p.w * p.w;
#pragma unroll
    for (int o = 1; o < 64; o <<= 1) ss += __shfl_xor(ss, o, 64);
    if ((t & 63) == 0) red1[w] = ss;
    __syncthreads();
    float inv1 = 1.0f / fmaxf(sqrtf(red1[0] + red1[1] + red1[2] + red1[3]), 1e-6f);
    const float4 bx = *(const float4*)(base + (size_t)row * 1024 + t * 4);
    const float4 av = *(const float4*)(alpha + t * 4);
    float4 tm;
    tm.x = bx.x + av.x * (p.x * inv1 - bx.x);
    tm.y = bx.y + av.y * (p.y * inv1 - bx.y);
    tm.z = bx.z + av.z * (p.z * inv1 - bx.z);
    tm.w = bx.w + av.w * (p.w * inv1 - bx.w);
    float ss2 = tm.x * tm.x + tm.y * tm.y + tm.z * tm.z + tm.w * tm.w;
#pragma unroll
    for (int o = 1; o < 64; o <<= 1) ss2 += __shfl_xor(ss2, o, 64);
    if ((t & 63) == 0) red2[w] = ss2;
    __syncthreads();
    float inv2 = 1.0f / fmaxf(sqrtf(red2[0] + red2[1] + red2[2] + red2[3]), 1e-6f);
    float4 hv;
    hv.x = tm.x * inv2; hv.y = tm.y * inv2; hv.z = tm.z * inv2; hv.w = tm.w * inv2;
    if (outf) *(float4*)(outf + (size_t)row * 1024 + t * 4) = hv;
    if (outb) {
        short4 o4;
        o4.x = f2bf(hv.x); o4.y = f2bf(hv.y); o4.z = f2bf(hv.z); o4.w = f2bf(hv.w);
        *(short4*)(outb + (size_t)row * 1024 + t * 4) = o4;
    }
}

// ---------- launch ----------
// Workspace (lifetime-overlaid, peak ~75.9 MB; 76,152,832 known-safe):
//  [0, 25296896)  weights bf16^T                                     (whole launch)
//  25296896  cost/sint (prep->qkv) -> lsum 0.5MB (attn->comb)
//  25821184  xbf(prep->qkv) -> h1bf(rn1->swiglu)                               8 MB
//  34209792  qn(qkv->attn) -> ao(comb->wo) -> wmlp(swiglu->down, 22.5MB ..56754176)
//  42598400  kn(qkv->attn) -> hA0 bf16 8MB(wo->rn1)
//  50987008  vt(qkv->attn) -> hA1 bf16 8MB(wo->rn1)
//  59375616  opart[2] bf16 16MB(attn->comb) -> hM0 bf16 8MB(down->rn2)
//  67764224  hM1 bf16 8MB(down->rn2)
extern "C" void kernel_launch(void* const* d_in, const int* in_sizes, int n_in,
                              void* d_out, int out_size, void* d_ws, size_t ws_size,
                              hipStream_t stream) {
    (void)in_sizes; (void)n_in; (void)out_size; (void)ws_size;
    const float* x   = (const float*)d_in[0];
    const float* Wq  = (const float*)d_in[1];
    const float* Wk  = (const float*)d_in[2];
    const float* Wv  = (const float*)d_in[3];
    const float* Wo  = (const float*)d_in[4];
    const float* sqk = (const float*)d_in[5];
    const float* aA  = (const float*)d_in[6];
    const float* Wup = (const float*)d_in[7];
    const float* Wg  = (const float*)d_in[8];
    const float* Wd  = (const float*)d_in[9];
    const float* su  = (const float*)d_in[10];
    const float* sv  = (const float*)d_in[11];
    const float* aM  = (const float*)d_in[12];

    char* ws = (char*)d_ws;
    short* wqkvT  = (short*)(ws + 0);          // [3072][1024]
    short* woT    = (short*)(ws + 6291456);    // [1024][1024]
    short* wugT   = (short*)(ws + 8388608);    // [5504][1024] interleaved up/gate
    short* wdownT = (short*)(ws + 19660800);   // [1024][2752]
    float* cost   = (float*)(ws + 25296896);
    float* sint   = (float*)(ws + 25559040);
    short* xbf    = (short*)(ws + 25821184);
    short* qn     = (short*)(ws + 34209792);
    short* kn     = (short*)(ws + 42598400);
    short* vt     = (short*)(ws + 50987008);   // [B][H][64][2048] bf16, 8MB
    short* opart  = (short*)(ws + 59375616);   // [2][4096][1024] bf16
    float* lsum   = (float*)(ws + 25296896);   // overwrites cost/sint (dead after qkv)
    short* ao     = (short*)(ws + 34209792);   // reuse qn
    short* hA0    = (short*)(ws + 42598400);   // reuse kn, bf16 8MB
    short* hA1    = (short*)(ws + 50987008);   // reuse vt, bf16 8MB
    float* h1f    = (float*)d_out;
    short* h1bf   = (short*)(ws + 25821184);   // reuse xbf
    short* wmlp   = (short*)(ws + 34209792);   // [4096][2752] bf16
    short* hM0    = (short*)(ws + 59375616);   // bf16 8MB (opart dead)
    short* hM1    = (short*)(ws + 67764224);   // bf16 8MB

    k_prep<<<16704, 256, 0, stream>>>(x, xbf, cost, sint, Wq, Wk, Wv, Wo, Wup, Wg, Wd,
                                      wqkvT, woT, wugT, wdownT);

    // QKV GEMM with fused rope + cosine-norm epilogue; v written directly transposed
    k_gemm128<3><<<768, 256, 0, stream>>>(xbf, wqkvT, nullptr, nullptr, 4096, 3072, 1024,
                                          16, 1, nullptr, nullptr, cost, sint, sqk, qn, kn, vt);
    k_attn<<<256, 512, 0, stream>>>(qn, kn, vt, opart, lsum);
    k_comb<<<4096, 256, 0, stream>>>(opart, lsum, ao);
    // Wo: split-K x2 (8+8 tiles), bf16 partials
    k_gemm128<1><<<512, 256, 0, stream>>>(ao, woT, hA0, hA1, 4096, 1024, 1024,
                                          8, 2, nullptr, nullptr, nullptr, nullptr, nullptr,
                                          nullptr, nullptr, nullptr);
    k_resnorm<<<4096, 256, 0, stream>>>(x, hA0, hA1, aA, h1f, h1bf);
    // up+gate fused SwiGLU
    k_gemm128<2><<<1376, 256, 0, stream>>>(h1bf, wugT, wmlp, nullptr, 4096, 5504, 1024,
                                           16, 1, su, sv, nullptr, nullptr, nullptr,
                                           nullptr, nullptr, nullptr);
    // down: split-K x2 (22+21 tiles), bf16 partials
    k_gemm128<1><<<512, 256, 0, stream>>>(wmlp, wdownT, hM0, hM1, 4096, 1024, 2752,
                                          22, 2, nullptr, nullptr, nullptr, nullptr, nullptr,
                                          nullptr, nullptr, nullptr);
    k_resnorm<<<4096, 256, 0, stream>>>(h1f, hM0, hM1, aM, (float*)d_out, (short*)nullptr);
}

// Round 19
// 241.101 us; speedup vs baseline: 1.2156x; 1.0021x over previous
//
#include <hip/hip_runtime.h>
#include <math.h>

#define DEVI __device__ __forceinline__

typedef __attribute__((ext_vector_type(4))) float f32x4;
typedef __attribute__((ext_vector_type(8))) short bf16x8;

// ---------- helpers ----------
DEVI short f2bf(float f) {                    // f32 -> bf16 (RNE)
    union { float f; unsigned u; } v; v.f = f;
    unsigned r = v.u + 0x7fffu + ((v.u >> 16) & 1u);
    return (short)(r >> 16);
}
DEVI float bf2f(short s) {
    union { unsigned u; float f; } v; v.u = ((unsigned)(unsigned short)s) << 16;
    return v.f;
}

DEVI f32x4 mfma16(bf16x8 a, bf16x8 b, f32x4 c) {
    return __builtin_amdgcn_mfma_f32_16x16x32_bf16(a, b, c, 0, 0, 0);
}

DEVI void gload16(const short* g, short* l) {  // async global->LDS, 16B/lane
    __builtin_amdgcn_global_load_lds((__attribute__((address_space(1))) void*)(g),
                                     (__attribute__((address_space(3))) void*)(l),
                                     16, 0, 0);
}

// ---------- merged preprocessing: cvt + freqs + all 7 weight transposes ----------
DEVI void trans_tile(const float* in, short* out, int R, int C, int Rpad, int Cpad,
                     int rmul, int radd, int bx, int by) {
    __shared__ float tile[32][33];
    int c0 = bx * 32, r0 = by * 32;
    int tx = threadIdx.x & 31, ty = threadIdx.x >> 5;
#pragma unroll
    for (int i = 0; i < 4; i++) {
        int r = r0 + ty + 8 * i, c = c0 + tx;
        tile[ty + 8 * i][tx] = (r < R && c < C) ? in[(size_t)r * C + c] : 0.0f;
    }
    __syncthreads();
#pragma unroll
    for (int i = 0; i < 4; i++) {
        int oc = c0 + ty + 8 * i;
        int orr = r0 + tx;
        if (oc < Cpad && orr < Rpad)
            out[(size_t)(oc * rmul + radd) * Rpad + orr] = f2bf(tile[tx][ty + 8 * i]);
    }
}

__global__ void k_prep(const float* __restrict__ x, short* __restrict__ xbf,
                       float* __restrict__ cost, float* __restrict__ sint,
                       const float* __restrict__ Wq, const float* __restrict__ Wk,
                       const float* __restrict__ Wv, const float* __restrict__ Wo,
                       const float* __restrict__ Wup, const float* __restrict__ Wg,
                       const float* __restrict__ Wd,
                       short* __restrict__ wqkvT, short* __restrict__ woT,
                       short* __restrict__ wugT, short* __restrict__ wdownT) {
    int b = blockIdx.x;
    if (b < 4096) {                         // x f32 -> bf16
        int i = (b * 256 + threadIdx.x) * 4;
        float4 v = *(const float4*)(x + i);
        short4 o;
        o.x = f2bf(v.x); o.y = f2bf(v.y); o.z = f2bf(v.z); o.w = f2bf(v.w);
        *(short4*)(xbf + i) = o;
    } else if (b < 4352) {                  // rope tables (f64 fidelity)
        int i = (b - 4096) * 256 + threadIdx.x;
        int s = i >> 5, j = i & 31;
        double inv = pow(10000.0, -(double)j / 32.0);
        double f = (double)s * inv;
        cost[i] = (float)cos(f);
        sint[i] = (float)sin(f);
    } else {
        int bb = b - 4352;
        if (bb < 4096) {                    // Wq/Wk/Wv/Wo
            int seg = bb >> 10, idx = bb & 1023;
            const float* in = seg == 0 ? Wq : seg == 1 ? Wk : seg == 2 ? Wv : Wo;
            short* out = seg == 0 ? wqkvT : seg == 1 ? wqkvT + 1048576
                       : seg == 2 ? wqkvT + 2097152 : woT;
            trans_tile(in, out, 1024, 1024, 1024, 1024, 1, 0, idx & 31, idx >> 5);
        } else if (bb < 9600) {             // Wup/Wg -> interleaved [5504][1024]
            int idx = bb - 4096;
            int seg = idx >= 2752;
            idx -= seg * 2752;
            trans_tile(seg ? Wg : Wup, wugT, 1024, 2730, 1024, 2752, 2, seg, idx % 86, idx / 86);
        } else {                            // Wd -> [1024][2752]
            int idx = bb - 9600;
            trans_tile(Wd, wdownT, 2730, 1024, 2752, 1024, 1, 0, idx & 31, idx >> 5);
        }
    }
}

// ---------- GEMM 128x128xBK64, single-buffer 32KB LDS, bank-swizzled, XCD-chunked, split-K ----
// R18: BK=64, one barrier pair per K-tile, two K=32 MFMA sub-steps; swizzle c^(r&7).
// R19: frag-read base pointers HOISTED out of the K-loop (single buffer -> loop-invariant;
// (rml&7) = (wr+lr)&7 is lane-const since 16,64 = 0 mod 8) -> all 16 ds_read_b128 become
// base+immediate, zero per-tile VALU addressing (attacks measured VALUBusy 45%).
// __launch_bounds__(256,4): <=128 regs/wave -> 4 waves/SIMD.
// EPI: 0 f32, 1 bf16 (honor split -> Cv1), 2 SwiGLU-interleaved, 3 fused QKV epilogue.
template <int EPI>
__launch_bounds__(256, 4)
__global__ void k_gemm128(const short* __restrict__ A, const short* __restrict__ BT,
                          void* __restrict__ Cv, void* __restrict__ Cv1,
                          int M, int N, int K, int nkblk, int nsplit,
                          const float* __restrict__ s_u, const float* __restrict__ s_v,
                          const float* __restrict__ cost, const float* __restrict__ sint,
                          const float* __restrict__ sqk,
                          short* __restrict__ qn, short* __restrict__ kn,
                          short* __restrict__ vtout) {
    __shared__ __align__(16) short As[128 * 64];
    __shared__ __align__(16) short Bs[128 * 64];
    const int t = threadIdx.x;
    const int w = t >> 6;
    const int lane = t & 63;
    const int lr = lane & 15, lg = lane >> 4;
    const int nwg = (int)gridDim.x;
    int wg = ((int)blockIdx.x & 7) * (nwg >> 3) + ((int)blockIdx.x >> 3);
    int half = 0;
    if (nsplit == 2) {
        const int per = nwg >> 1;
        half = wg >= per;
        wg -= half * per;
    }
    const int MT = M >> 7;
    const int m0 = (wg % MT) << 7;
    const int n0 = (wg / MT) << 7;
    const int koff = half * nkblk * 64;
    const int ntile = (nsplit == 2 && half) ? (K >> 6) - nkblk : nkblk;
    const int wr = (w >> 1) * 64, wc = (w & 1) * 64;

    // staging: thread t -> rows (t>>3)+j*32 (j=0..3), chunk cg=t&7, swizzled source col
    const int srow = t >> 3;
    const int scol = (((t & 7) ^ (srow & 7)) << 3);
    const short* Ap = A + (size_t)(m0 + srow) * K + koff + scol;
    const short* Bp = BT + (size_t)(n0 + srow) * K + koff + scol;
    const size_t rstep = (size_t)32 * K;
    const int dW = (w * 8) * 64;          // wave-uniform LDS dest (shorts), + lane*8 in HW

    // hoisted frag-read bases: (rml&7) == (wr+lr)&7 (lane-const), addr = base + m*1024
    const int ca = (wr + lr) & 7;
    const int cb = (wc + lr) & 7;
    const short* pa0 = &As[(wr + lr) * 64 + (((0 + lg) ^ ca) << 3)];
    const short* pa1 = &As[(wr + lr) * 64 + (((4 + lg) ^ ca) << 3)];
    const short* pb0 = &Bs[(wc + lr) * 64 + (((0 + lg) ^ cb) << 3)];
    const short* pb1 = &Bs[(wc + lr) * 64 + (((4 + lg) ^ cb) << 3)];

    f32x4 acc[4][4];
#pragma unroll
    for (int m = 0; m < 4; m++)
#pragma unroll
        for (int n = 0; n < 4; n++)
            acc[m][n] = (f32x4){0.f, 0.f, 0.f, 0.f};

    for (int kt = 0; kt < ntile; kt++) {
        if (kt) __syncthreads();          // all waves done reading tile kt-1
#pragma unroll
        for (int j = 0; j < 4; j++) {
            gload16(Ap + j * rstep, As + dW + j * 2048);
            gload16(Bp + j * rstep, Bs + dW + j * 2048);
        }
        Ap += 64; Bp += 64;
        __syncthreads();                  // vmcnt(0) drain -> tile resident
#pragma unroll
        for (int ks = 0; ks < 2; ks++) {
            const short* pa = ks ? pa1 : pa0;
            const short* pb = ks ? pb1 : pb0;
            bf16x8 af[4], bfr[4];
#pragma unroll
            for (int m = 0; m < 4; m++)
                af[m] = *(const bf16x8*)(pa + m * 1024);
#pragma unroll
            for (int n = 0; n < 4; n++)
                bfr[n] = *(const bf16x8*)(pb + n * 1024);
#pragma unroll
            for (int m = 0; m < 4; m++)
#pragma unroll
                for (int n = 0; n < 4; n++)
                    acc[m][n] = mfma16(af[m], bfr[n], acc[m][n]);
        }
    }

    if (EPI == 3) {
        const int sector = n0 >> 10;     // 0=q, 1=k, 2=v
        if (sector == 2) {
            // write v directly into vt[b][h][d][s]: lane stores short4 (4 consecutive s)
#pragma unroll
            for (int m = 0; m < 4; m++)
#pragma unroll
                for (int n = 0; n < 4; n++) {
                    int col = n0 + wc + n * 16 + lr - 2048;
                    int hh = col >> 6, d = col & 63;
                    int brow = m0 + wr + m * 16 + lg * 4;
                    int bb = brow >> 11, s = brow & 2047;
                    short4 o4;
                    o4.x = f2bf(acc[m][n][0]); o4.y = f2bf(acc[m][n][1]);
                    o4.z = f2bf(acc[m][n][2]); o4.w = f2bf(acc[m][n][3]);
                    *(short4*)&vtout[((size_t)((bb * 16 + hh) * 64 + d)) * 2048 + s] = o4;
                }
        } else {
            const int h = ((n0 + wc) >> 6) & 15;
            float eff[4];
#pragma unroll
            for (int n = 0; n < 4; n++)
                eff[n] = sqk[h * 64 + n * 16 + lr] * 32.0f;   // s_qk * sqrt(DIM)
            short* dst = (sector == 0) ? qn : kn;
            const float extra = (sector == 0) ? 8.0f : 1.0f;  // sqrt(HD) folded into q
#pragma unroll
            for (int m = 0; m < 4; m++)
#pragma unroll
                for (int i = 0; i < 4; i++) {
                    int row = m0 + wr + m * 16 + lg * 4 + i;
                    int b = row >> 11, s = row & 2047;
                    float cs0 = cost[s * 32 + lr],      sn0 = sint[s * 32 + lr];
                    float cs1 = cost[s * 32 + 16 + lr], sn1 = sint[s * 32 + 16 + lr];
                    float vr0 = acc[m][0][i] * cs0 - acc[m][2][i] * sn0;
                    float vr1 = acc[m][1][i] * cs1 - acc[m][3][i] * sn1;
                    float vr2 = acc[m][2][i] * cs0 + acc[m][0][i] * sn0;
                    float vr3 = acc[m][3][i] * cs1 + acc[m][1][i] * sn1;
                    float ss = vr0 * vr0 + vr1 * vr1 + vr2 * vr2 + vr3 * vr3;
#pragma unroll
                    for (int o = 1; o < 16; o <<= 1)
                        ss += __shfl_xor(ss, o, 64);
                    float sc = extra / fmaxf(sqrtf(ss), 1e-6f);
                    size_t base = ((size_t)(b * 16 + h) * 2048 + s) * 64;
                    dst[base + lr]      = f2bf(vr0 * eff[0] * sc);
                    dst[base + 16 + lr] = f2bf(vr1 * eff[1] * sc);
                    dst[base + 32 + lr] = f2bf(vr2 * eff[2] * sc);
                    dst[base + 48 + lr] = f2bf(vr3 * eff[3] * sc);
                }
        }
        return;
    }

#pragma unroll
    for (int m = 0; m < 4; m++)
#pragma unroll
        for (int n = 0; n < 4; n++) {
            int row = m0 + wr + m * 16 + lg * 4;
            int col = n0 + wc + n * 16 + lr;
            if (EPI == 2) {
                int j = col >> 1;
                int jc = j < 2730 ? j : 2729;
                float su = s_u[jc];
                float sg = s_v[jc] * 32.0f;
#pragma unroll
                for (int i = 0; i < 4; i++) {
                    float own = acc[m][n][i];
                    float oth = __shfl_xor(own, 1, 64);
                    float u = (lr & 1) ? oth : own;
                    float g = (lr & 1) ? own : oth;
                    float uu = u * su;
                    float vv = g * sg;
                    float wv = uu * vv / (1.0f + expf(-vv));
                    if (!(lr & 1))
                        ((short*)Cv)[(size_t)(row + i) * (N >> 1) + j] = f2bf(wv);
                }
            } else {
                void* outp = half ? Cv1 : Cv;
#pragma unroll
                for (int i = 0; i < 4; i++) {
                    if (EPI == 1)
                        ((short*)outp)[(size_t)(row + i) * N + col] = f2bf(acc[m][n][i]);
                    else
                        ((float*)outp)[(size_t)(row + i) * N + col] = acc[m][n][i];
                }
            }
        }
}

// ---------- flash attention (causal), static-max softmax, balanced pair split ----------
__launch_bounds__(512)
__global__ void k_attn(const short* __restrict__ qn, const short* __restrict__ kn,
                       const short* __restrict__ vt, short* __restrict__ opart,
                       float* __restrict__ lsump) {
    __shared__ __align__(16) short Ks[2][64 * 64];
    __shared__ __align__(16) short Vs[2][64 * 64];
    __shared__ __align__(16) short Ps[8][32 * 64];
    const int t = threadIdx.x;
    const int w = t >> 6, lane = t & 63;
    const int bid = blockIdx.x;
    const int xcd = bid & 7, idx = bid >> 3;
    const int bhg = xcd + ((idx >> 3) << 3);          // 0..31
    const int pslot = idx & 7;
    const int h = bhg & 15, b = bhg >> 4;
    const int bh = b * 16 + h;
    const int lr = lane & 15, lg = lane >> 4;
    const short* Qb = qn + (size_t)bh * 2048 * 64;
    const short* Kb = kn + (size_t)bh * 2048 * 64;
    const short* Vb = vt + (size_t)bh * 64 * 2048;
    char* pwc = (char*)&Ps[w][0];

#define STAGE_KV(bi, kbase)                                                          \
    {                                                                                \
        int row = w * 8 + (lane >> 3);                                               \
        int scol = (lane & 7) ^ (row & 7);                                           \
        gload16(Kb + (size_t)((kbase) + row) * 64 + scol * 8,                        \
                &Ks[bi][(w * 8) * 64]);                                              \
        gload16(Vb + (size_t)row * 2048 + (kbase) + scol * 8,                        \
                &Vs[bi][(w * 8) * 64]);                                              \
    }

    for (int pc = 0; pc < 2; pc++) {
        const int qb = pc == 0 ? pslot : 7 - pslot;
        const int hf = pc;
        const int ktn = 2 * qb + 2;
        const int kt0 = hf * ktn, kt1 = kt0 + ktn;
        const int qw = qb * 256 + w * 32;

        bf16x8 qf[2][2];
#pragma unroll
        for (int mi = 0; mi < 2; mi++)
#pragma unroll
            for (int kk = 0; kk < 2; kk++)
                qf[mi][kk] = *(const bf16x8*)&Qb[(size_t)(qw + mi * 16 + lr) * 64 + kk * 32 + lg * 8];

        f32x4 oacc[2][4];
#pragma unroll
        for (int mi = 0; mi < 2; mi++)
#pragma unroll
            for (int ct = 0; ct < 4; ct++) oacc[mi][ct] = (f32x4){0.f, 0.f, 0.f, 0.f};
        float psum[2][4];
#pragma unroll
        for (int mi = 0; mi < 2; mi++)
#pragma unroll
            for (int i = 0; i < 4; i++) psum[mi][i] = 0.0f;

        if (pc) __syncthreads();          // all waves done with piece-0 LDS
        STAGE_KV(0, kt0 << 6);

        for (int kt = kt0; kt < kt1; kt++) {
            const int kbase = kt << 6;
            const int cur = (kt - kt0) & 1;
            __syncthreads();
            if (kt + 1 < kt1) STAGE_KV(cur ^ 1, (kt + 1) << 6);

            bf16x8 kf[4][2];
#pragma unroll
            for (int ni = 0; ni < 4; ni++)
#pragma unroll
                for (int kk = 0; kk < 2; kk++) {
                    int row = ni * 16 + lr;
                    kf[ni][kk] = *(const bf16x8*)&Ks[cur][row * 64 + (((kk * 4 + lg) ^ (row & 7)) << 3)];
                }
            f32x4 sv[2][4];
#pragma unroll
            for (int mi = 0; mi < 2; mi++)
#pragma unroll
                for (int ni = 0; ni < 4; ni++) {
                    f32x4 s = (f32x4){0.f, 0.f, 0.f, 0.f};
                    s = mfma16(qf[mi][0], kf[ni][0], s);
                    s = mfma16(qf[mi][1], kf[ni][1], s);
                    sv[mi][ni] = s;
                }
            if (kbase + 63 > qw) {
#pragma unroll
                for (int mi = 0; mi < 2; mi++)
#pragma unroll
                    for (int ni = 0; ni < 4; ni++)
#pragma unroll
                        for (int i = 0; i < 4; i++) {
                            int qg = qw + mi * 16 + lg * 4 + i;
                            int kg = kbase + ni * 16 + lr;
                            if (kg > qg) sv[mi][ni][i] = -3.0e38f;
                        }
            }
#pragma unroll
            for (int mi = 0; mi < 2; mi++) {
#pragma unroll
                for (int ni = 0; ni < 4; ni++)
#pragma unroll
                    for (int i = 0; i < 4; i++) {
                        float p = exp2f((sv[mi][ni][i] - 9.0f) * 1.44269504f);
                        sv[mi][ni][i] = p;
                        psum[mi][i] += p;
                    }
#pragma unroll
                for (int ni = 0; ni < 4; ni++)
#pragma unroll
                    for (int i = 0; i < 4; i++) {
                        int row = mi * 16 + lg * 4 + i;
                        int col = ni * 16 + lr;
                        unsigned off = (unsigned)(row * 128 + col * 2) ^ ((unsigned)(row & 7) << 4);
                        *(short*)(pwc + off) = f2bf(sv[mi][ni][i]);
                    }
            }
            bf16x8 pa[2][2];
#pragma unroll
            for (int mi = 0; mi < 2; mi++)
#pragma unroll
                for (int kk = 0; kk < 2; kk++) {
                    int row = mi * 16 + lr;
                    unsigned off = (unsigned)(row * 128 + kk * 64 + lg * 16) ^ ((unsigned)(row & 7) << 4);
                    pa[mi][kk] = *(const bf16x8*)(pwc + off);
                }
            bf16x8 vf[4][2];
#pragma unroll
            for (int ct = 0; ct < 4; ct++)
#pragma unroll
                for (int kk = 0; kk < 2; kk++) {
                    int row = ct * 16 + lr;
                    vf[ct][kk] = *(const bf16x8*)&Vs[cur][row * 64 + (((kk * 4 + lg) ^ (row & 7)) << 3)];
                }
#pragma unroll
            for (int mi = 0; mi < 2; mi++)
#pragma unroll
                for (int ct = 0; ct < 4; ct++) {
                    oacc[mi][ct] = mfma16(pa[mi][0], vf[ct][0], oacc[mi][ct]);
                    oacc[mi][ct] = mfma16(pa[mi][1], vf[ct][1], oacc[mi][ct]);
                }
        }

#pragma unroll
        for (int o = 1; o < 16; o <<= 1)
#pragma unroll
            for (int mi = 0; mi < 2; mi++)
#pragma unroll
                for (int i = 0; i < 4; i++)
                    psum[mi][i] += __shfl_xor(psum[mi][i], o, 64);

        short* aob = opart + (size_t)hf * 4096 * 1024 + ((size_t)(b * 2048 + qw) * 1024) + h * 64;
#pragma unroll
        for (int mi = 0; mi < 2; mi++)
#pragma unroll
            for (int ct = 0; ct < 4; ct++)
#pragma unroll
                for (int i = 0; i < 4; i++) {
                    int q = mi * 16 + lg * 4 + i;
                    aob[(size_t)q * 1024 + ct * 16 + lr] = f2bf(oacc[mi][ct][i]);
                }
        if (lr == 0) {
#pragma unroll
            for (int mi = 0; mi < 2; mi++)
#pragma unroll
                for (int i = 0; i < 4; i++)
                    lsump[hf * 65536 + bh * 2048 + qw + mi * 16 + lg * 4 + i] = psum[mi][i];
        }
    }
#undef STAGE_KV
}

// ---------- combine split-K partials: ao = (O0+O1)/(l0+l1), bf16 ----------
__global__ void k_comb(const short* __restrict__ op, const float* __restrict__ ls,
                       short* __restrict__ ao) {
    int i = (blockIdx.x * 256 + threadIdx.x) * 4;
    int row = i >> 10, col = i & 1023;
    int idx = ((row >> 11) * 16 + (col >> 6)) * 2048 + (row & 2047);
    float rl = 1.0f / (ls[idx] + ls[65536 + idx]);
    short4 a = *(const short4*)(op + i);
    short4 c = *(const short4*)(op + 4194304 + i);
    short4 o;
    o.x = f2bf((bf2f(a.x) + bf2f(c.x)) * rl);
    o.y = f2bf((bf2f(a.y) + bf2f(c.y)) * rl);
    o.z = f2bf((bf2f(a.z) + bf2f(c.z)) * rl);
    o.w = f2bf((bf2f(a.w) + bf2f(c.w)) * rl);
    *(short4*)(ao + i) = o;
}

// ---------- residual + double cosine_norm; pre = pre0 + pre1 (bf16 partials) ----------
__global__ void k_resnorm(const float* base, const short* __restrict__ pre0,
                          const short* __restrict__ pre1,
                          const float* __restrict__ alpha, float* outf,
                          short* __restrict__ outb) {
    __shared__ float red1[4], red2[4];
    int row = blockIdx.x;
    int t = threadIdx.x;
    int w = t >> 6;
    float4 p;
    short4 a = *(const short4*)(pre0 + (size_t)row * 1024 + t * 4);
    short4 c = *(const short4*)(pre1 + (size_t)row * 1024 + t * 4);
    p.x = bf2f(a.x) + bf2f(c.x); p.y = bf2f(a.y) + bf2f(c.y);
    p.z = bf2f(a.z) + bf2f(c.z); p.w = bf2f(a.w) + bf2f(c.w);
    float ss = p.x * p.x + p.y * p.y + p.z * p.z + p.w * p.w;
#pragma unroll
    for (int o = 1; o < 64; o <<= 1) ss += __shfl_xor(ss, o, 64);
    if ((t & 63) == 0) red1[w] = ss;
    __syncthreads();
    float inv1 = 1.0f / fmaxf(sqrtf(red1[0] + red1[1] + red1[2] + red1[3]), 1e-6f);
    const float4 bx = *(const float4*)(base + (size_t)row * 1024 + t * 4);
    const float4 av = *(const float4*)(alpha + t * 4);
    float4 tm;
    tm.x = bx.x + av.x * (p.x * inv1 - bx.x);
    tm.y = bx.y + av.y * (p.y * inv1 - bx.y);
    tm.z = bx.z + av.z * (p.z * inv1 - bx.z);
    tm.w = bx.w + av.w * (p.w * inv1 - bx.w);
    float ss2 = tm.x * tm.x + tm.y * tm.y + tm.z * tm.z + tm.w * tm.w;
#pragma unroll
    for (int o = 1; o < 64; o <<= 1) ss2 += __shfl_xor(ss2, o, 64);
    if ((t & 63) == 0) red2[w] = ss2;
    __syncthreads();
    float inv2 = 1.0f / fmaxf(sqrtf(red2[0] + red2[1] + red2[2] + red2[3]), 1e-6f);
    float4 hv;
    hv.x = tm.x * inv2; hv.y = tm.y * inv2; hv.z = tm.z * inv2; hv.w = tm.w * inv2;
    if (outf) *(float4*)(outf + (size_t)row * 1024 + t * 4) = hv;
    if (outb) {
        short4 o4;
        o4.x = f2bf(hv.x); o4.y = f2bf(hv.y); o4.z = f2bf(hv.z); o4.w = f2bf(hv.w);
        *(short4*)(outb + (size_t)row * 1024 + t * 4) = o4;
    }
}

// ---------- launch ----------
// Workspace (lifetime-overlaid, peak ~75.9 MB; 76,152,832 known-safe):
//  [0, 25296896)  weights bf16^T                                     (whole launch)
//  25296896  cost/sint (prep->qkv) -> lsum 0.5MB (attn->comb)
//  25821184  xbf(prep->qkv) -> h1bf(rn1->swiglu)                               8 MB
//  34209792  qn(qkv->attn) -> ao(comb->wo) -> wmlp(swiglu->down, 22.5MB ..56754176)
//  42598400  kn(qkv->attn) -> hA0 bf16 8MB(wo->rn1)
//  50987008  vt(qkv->attn) -> hA1 bf16 8MB(wo->rn1)
//  59375616  opart[2] bf16 16MB(attn->comb) -> hM0 bf16 8MB(down->rn2)
//  67764224  hM1 bf16 8MB(down->rn2)
extern "C" void kernel_launch(void* const* d_in, const int* in_sizes, int n_in,
                              void* d_out, int out_size, void* d_ws, size_t ws_size,
                              hipStream_t stream) {
    (void)in_sizes; (void)n_in; (void)out_size; (void)ws_size;
    const float* x   = (const float*)d_in[0];
    const float* Wq  = (const float*)d_in[1];
    const float* Wk  = (const float*)d_in[2];
    const float* Wv  = (const float*)d_in[3];
    const float* Wo  = (const float*)d_in[4];
    const float* sqk = (const float*)d_in[5];
    const float* aA  = (const float*)d_in[6];
    const float* Wup = (const float*)d_in[7];
    const float* Wg  = (const float*)d_in[8];
    const float* Wd  = (const float*)d_in[9];
    const float* su  = (const float*)d_in[10];
    const float* sv  = (const float*)d_in[11];
    const float* aM  = (const float*)d_in[12];

    char* ws = (char*)d_ws;
    short* wqkvT  = (short*)(ws + 0);          // [3072][1024]
    short* woT    = (short*)(ws + 6291456);    // [1024][1024]
    short* wugT   = (short*)(ws + 8388608);    // [5504][1024] interleaved up/gate
    short* wdownT = (short*)(ws + 19660800);   // [1024][2752]
    float* cost   = (float*)(ws + 25296896);
    float* sint   = (float*)(ws + 25559040);
    short* xbf    = (short*)(ws + 25821184);
    short* qn     = (short*)(ws + 34209792);
    short* kn     = (short*)(ws + 42598400);
    short* vt     = (short*)(ws + 50987008);   // [B][H][64][2048] bf16, 8MB
    short* opart  = (short*)(ws + 59375616);   // [2][4096][1024] bf16
    float* lsum   = (float*)(ws + 25296896);   // overwrites cost/sint (dead after qkv)
    short* ao     = (short*)(ws + 34209792);   // reuse qn
    short* hA0    = (short*)(ws + 42598400);   // reuse kn, bf16 8MB
    short* hA1    = (short*)(ws + 50987008);   // reuse vt, bf16 8MB
    float* h1f    = (float*)d_out;
    short* h1bf   = (short*)(ws + 25821184);   // reuse xbf
    short* wmlp   = (short*)(ws + 34209792);   // [4096][2752] bf16
    short* hM0    = (short*)(ws + 59375616);   // bf16 8MB (opart dead)
    short* hM1    = (short*)(ws + 67764224);   // bf16 8MB

    k_prep<<<16704, 256, 0, stream>>>(x, xbf, cost, sint, Wq, Wk, Wv, Wo, Wup, Wg, Wd,
                                      wqkvT, woT, wugT, wdownT);

    // QKV GEMM with fused rope + cosine-norm epilogue; v written directly transposed
    k_gemm128<3><<<768, 256, 0, stream>>>(xbf, wqkvT, nullptr, nullptr, 4096, 3072, 1024,
                                          16, 1, nullptr, nullptr, cost, sint, sqk, qn, kn, vt);
    k_attn<<<256, 512, 0, stream>>>(qn, kn, vt, opart, lsum);
    k_comb<<<4096, 256, 0, stream>>>(opart, lsum, ao);
    // Wo: split-K x2 (8+8 tiles), bf16 partials
    k_gemm128<1><<<512, 256, 0, stream>>>(ao, woT, hA0, hA1, 4096, 1024, 1024,
                                          8, 2, nullptr, nullptr, nullptr, nullptr, nullptr,
                                          nullptr, nullptr, nullptr);
    k_resnorm<<<4096, 256, 0, stream>>>(x, hA0, hA1, aA, h1f, h1bf);
    // up+gate fused SwiGLU
    k_gemm128<2><<<1376, 256, 0, stream>>>(h1bf, wugT, wmlp, nullptr, 4096, 5504, 1024,
                                           16, 1, su, sv, nullptr, nullptr, nullptr,
                                           nullptr, nullptr, nullptr);
    // down: split-K x2 (22+21 tiles), bf16 partials
    k_gemm128<1><<<512, 256, 0, stream>>>(wmlp, wdownT, hM0, hM1, 4096, 1024, 2752,
                                          22, 2, nullptr, nullptr, nullptr, nullptr, nullptr,
                                          nullptr, nullptr, nullptr);
    k_resnorm<<<4096, 256, 0, stream>>>(h1f, hM0, hM1, aM, (float*)d_out, (short*)nullptr);
}

// Round 20
// 232.132 us; speedup vs baseline: 1.2626x; 1.0386x over previous
//
#include <hip/hip_runtime.h>
#include <math.h>

#define DEVI __device__ __forceinline__

typedef __attribute__((ext_vector_type(4))) float f32x4;
typedef __attribute__((ext_vector_type(8))) short bf16x8;

// ---------- helpers ----------
DEVI short f2bf(float f) {                    // f32 -> bf16 (RNE)
    union { float f; unsigned u; } v; v.f = f;
    unsigned r = v.u + 0x7fffu + ((v.u >> 16) & 1u);
    return (short)(r >> 16);
}
DEVI float bf2f(short s) {
    union { unsigned u; float f; } v; v.u = ((unsigned)(unsigned short)s) << 16;
    return v.f;
}

DEVI f32x4 mfma16(bf16x8 a, bf16x8 b, f32x4 c) {
    return __builtin_amdgcn_mfma_f32_16x16x32_bf16(a, b, c, 0, 0, 0);
}

DEVI void gload16(const short* g, short* l) {  // async global->LDS, 16B/lane
    __builtin_amdgcn_global_load_lds((__attribute__((address_space(1))) void*)(g),
                                     (__attribute__((address_space(3))) void*)(l),
                                     16, 0, 0);
}

// ---------- merged preprocessing: cvt + freqs + all 7 weight transposes ----------
DEVI void trans_tile(const float* in, short* out, int R, int C, int Rpad, int Cpad,
                     int rmul, int radd, int bx, int by) {
    __shared__ float tile[32][33];
    int c0 = bx * 32, r0 = by * 32;
    int tx = threadIdx.x & 31, ty = threadIdx.x >> 5;
#pragma unroll
    for (int i = 0; i < 4; i++) {
        int r = r0 + ty + 8 * i, c = c0 + tx;
        tile[ty + 8 * i][tx] = (r < R && c < C) ? in[(size_t)r * C + c] : 0.0f;
    }
    __syncthreads();
#pragma unroll
    for (int i = 0; i < 4; i++) {
        int oc = c0 + ty + 8 * i;
        int orr = r0 + tx;
        if (oc < Cpad && orr < Rpad)
            out[(size_t)(oc * rmul + radd) * Rpad + orr] = f2bf(tile[tx][ty + 8 * i]);
    }
}

__global__ void k_prep(const float* __restrict__ x, short* __restrict__ xbf,
                       float* __restrict__ cost, float* __restrict__ sint,
                       const float* __restrict__ Wq, const float* __restrict__ Wk,
                       const float* __restrict__ Wv, const float* __restrict__ Wo,
                       const float* __restrict__ Wup, const float* __restrict__ Wg,
                       const float* __restrict__ Wd,
                       short* __restrict__ wqkvT, short* __restrict__ woT,
                       short* __restrict__ wugT, short* __restrict__ wdownT) {
    int b = blockIdx.x;
    if (b < 4096) {                         // x f32 -> bf16
        int i = (b * 256 + threadIdx.x) * 4;
        float4 v = *(const float4*)(x + i);
        short4 o;
        o.x = f2bf(v.x); o.y = f2bf(v.y); o.z = f2bf(v.z); o.w = f2bf(v.w);
        *(short4*)(xbf + i) = o;
    } else if (b < 4352) {                  // rope tables (f64 fidelity)
        int i = (b - 4096) * 256 + threadIdx.x;
        int s = i >> 5, j = i & 31;
        double inv = pow(10000.0, -(double)j / 32.0);
        double f = (double)s * inv;
        cost[i] = (float)cos(f);
        sint[i] = (float)sin(f);
    } else {
        int bb = b - 4352;
        if (bb < 4096) {                    // Wq/Wk/Wv/Wo
            int seg = bb >> 10, idx = bb & 1023;
            const float* in = seg == 0 ? Wq : seg == 1 ? Wk : seg == 2 ? Wv : Wo;
            short* out = seg == 0 ? wqkvT : seg == 1 ? wqkvT + 1048576
                       : seg == 2 ? wqkvT + 2097152 : woT;
            trans_tile(in, out, 1024, 1024, 1024, 1024, 1, 0, idx & 31, idx >> 5);
        } else if (bb < 9600) {             // Wup/Wg -> interleaved [5504][1024]
            int idx = bb - 4096;
            int seg = idx >= 2752;
            idx -= seg * 2752;
            trans_tile(seg ? Wg : Wup, wugT, 1024, 2730, 1024, 2752, 2, seg, idx % 86, idx / 86);
        } else {                            // Wd -> [1024][2752]
            int idx = bb - 9600;
            trans_tile(Wd, wdownT, 2730, 1024, 2752, 1024, 1, 0, idx & 31, idx >> 5);
        }
    }
}

// ---------- GEMM 128x128xBK64, single-buffer 32KB LDS, bank-swizzled, XCD-chunked, split-K ----
// BK=64, one barrier pair per K-tile, two K=32 MFMA sub-steps; swizzle c^(r&7) both-sides;
// hoisted frag-read bases; __launch_bounds__(256,4) -> 4 waves/SIMD. (Engine frozen at
// R18/R19 plateau: MfmaUtil ~27%, barrier-drain structural.)
// EPI: 0 f32, 1 bf16 (honor split -> Cv1), 2 SwiGLU-interleaved, 3 fused QKV epilogue.
template <int EPI>
__launch_bounds__(256, 4)
__global__ void k_gemm128(const short* __restrict__ A, const short* __restrict__ BT,
                          void* __restrict__ Cv, void* __restrict__ Cv1,
                          int M, int N, int K, int nkblk, int nsplit,
                          const float* __restrict__ s_u, const float* __restrict__ s_v,
                          const float* __restrict__ cost, const float* __restrict__ sint,
                          const float* __restrict__ sqk,
                          short* __restrict__ qn, short* __restrict__ kn,
                          short* __restrict__ vtout) {
    __shared__ __align__(16) short As[128 * 64];
    __shared__ __align__(16) short Bs[128 * 64];
    const int t = threadIdx.x;
    const int w = t >> 6;
    const int lane = t & 63;
    const int lr = lane & 15, lg = lane >> 4;
    const int nwg = (int)gridDim.x;
    int wg = ((int)blockIdx.x & 7) * (nwg >> 3) + ((int)blockIdx.x >> 3);
    int half = 0;
    if (nsplit == 2) {
        const int per = nwg >> 1;
        half = wg >= per;
        wg -= half * per;
    }
    const int MT = M >> 7;
    const int m0 = (wg % MT) << 7;
    const int n0 = (wg / MT) << 7;
    const int koff = half * nkblk * 64;
    const int ntile = (nsplit == 2 && half) ? (K >> 6) - nkblk : nkblk;
    const int wr = (w >> 1) * 64, wc = (w & 1) * 64;

    const int srow = t >> 3;
    const int scol = (((t & 7) ^ (srow & 7)) << 3);
    const short* Ap = A + (size_t)(m0 + srow) * K + koff + scol;
    const short* Bp = BT + (size_t)(n0 + srow) * K + koff + scol;
    const size_t rstep = (size_t)32 * K;
    const int dW = (w * 8) * 64;

    const int ca = (wr + lr) & 7;
    const int cb = (wc + lr) & 7;
    const short* pa0 = &As[(wr + lr) * 64 + (((0 + lg) ^ ca) << 3)];
    const short* pa1 = &As[(wr + lr) * 64 + (((4 + lg) ^ ca) << 3)];
    const short* pb0 = &Bs[(wc + lr) * 64 + (((0 + lg) ^ cb) << 3)];
    const short* pb1 = &Bs[(wc + lr) * 64 + (((4 + lg) ^ cb) << 3)];

    f32x4 acc[4][4];
#pragma unroll
    for (int m = 0; m < 4; m++)
#pragma unroll
        for (int n = 0; n < 4; n++)
            acc[m][n] = (f32x4){0.f, 0.f, 0.f, 0.f};

    for (int kt = 0; kt < ntile; kt++) {
        if (kt) __syncthreads();
#pragma unroll
        for (int j = 0; j < 4; j++) {
            gload16(Ap + j * rstep, As + dW + j * 2048);
            gload16(Bp + j * rstep, Bs + dW + j * 2048);
        }
        Ap += 64; Bp += 64;
        __syncthreads();
#pragma unroll
        for (int ks = 0; ks < 2; ks++) {
            const short* pa = ks ? pa1 : pa0;
            const short* pb = ks ? pb1 : pb0;
            bf16x8 af[4], bfr[4];
#pragma unroll
            for (int m = 0; m < 4; m++)
                af[m] = *(const bf16x8*)(pa + m * 1024);
#pragma unroll
            for (int n = 0; n < 4; n++)
                bfr[n] = *(const bf16x8*)(pb + n * 1024);
#pragma unroll
            for (int m = 0; m < 4; m++)
#pragma unroll
                for (int n = 0; n < 4; n++)
                    acc[m][n] = mfma16(af[m], bfr[n], acc[m][n]);
        }
    }

    if (EPI == 3) {
        const int sector = n0 >> 10;     // 0=q, 1=k, 2=v
        if (sector == 2) {
#pragma unroll
            for (int m = 0; m < 4; m++)
#pragma unroll
                for (int n = 0; n < 4; n++) {
                    int col = n0 + wc + n * 16 + lr - 2048;
                    int hh = col >> 6, d = col & 63;
                    int brow = m0 + wr + m * 16 + lg * 4;
                    int bb = brow >> 11, s = brow & 2047;
                    short4 o4;
                    o4.x = f2bf(acc[m][n][0]); o4.y = f2bf(acc[m][n][1]);
                    o4.z = f2bf(acc[m][n][2]); o4.w = f2bf(acc[m][n][3]);
                    *(short4*)&vtout[((size_t)((bb * 16 + hh) * 64 + d)) * 2048 + s] = o4;
                }
        } else {
            const int h = ((n0 + wc) >> 6) & 15;
            float eff[4];
#pragma unroll
            for (int n = 0; n < 4; n++)
                eff[n] = sqk[h * 64 + n * 16 + lr] * 32.0f;   // s_qk * sqrt(DIM)
            short* dst = (sector == 0) ? qn : kn;
            const float extra = (sector == 0) ? 8.0f : 1.0f;  // sqrt(HD) folded into q
#pragma unroll
            for (int m = 0; m < 4; m++)
#pragma unroll
                for (int i = 0; i < 4; i++) {
                    int row = m0 + wr + m * 16 + lg * 4 + i;
                    int b = row >> 11, s = row & 2047;
                    float cs0 = cost[s * 32 + lr],      sn0 = sint[s * 32 + lr];
                    float cs1 = cost[s * 32 + 16 + lr], sn1 = sint[s * 32 + 16 + lr];
                    float vr0 = acc[m][0][i] * cs0 - acc[m][2][i] * sn0;
                    float vr1 = acc[m][1][i] * cs1 - acc[m][3][i] * sn1;
                    float vr2 = acc[m][2][i] * cs0 + acc[m][0][i] * sn0;
                    float vr3 = acc[m][3][i] * cs1 + acc[m][1][i] * sn1;
                    float ss = vr0 * vr0 + vr1 * vr1 + vr2 * vr2 + vr3 * vr3;
#pragma unroll
                    for (int o = 1; o < 16; o <<= 1)
                        ss += __shfl_xor(ss, o, 64);
                    float sc = extra / fmaxf(sqrtf(ss), 1e-6f);
                    size_t base = ((size_t)(b * 16 + h) * 2048 + s) * 64;
                    dst[base + lr]      = f2bf(vr0 * eff[0] * sc);
                    dst[base + 16 + lr] = f2bf(vr1 * eff[1] * sc);
                    dst[base + 32 + lr] = f2bf(vr2 * eff[2] * sc);
                    dst[base + 48 + lr] = f2bf(vr3 * eff[3] * sc);
                }
        }
        return;
    }

#pragma unroll
    for (int m = 0; m < 4; m++)
#pragma unroll
        for (int n = 0; n < 4; n++) {
            int row = m0 + wr + m * 16 + lg * 4;
            int col = n0 + wc + n * 16 + lr;
            if (EPI == 2) {
                int j = col >> 1;
                int jc = j < 2730 ? j : 2729;
                float su = s_u[jc];
                float sg = s_v[jc] * 32.0f;
#pragma unroll
                for (int i = 0; i < 4; i++) {
                    float own = acc[m][n][i];
                    float oth = __shfl_xor(own, 1, 64);
                    float u = (lr & 1) ? oth : own;
                    float g = (lr & 1) ? own : oth;
                    float uu = u * su;
                    float vv = g * sg;
                    float wv = uu * vv / (1.0f + expf(-vv));
                    if (!(lr & 1))
                        ((short*)Cv)[(size_t)(row + i) * (N >> 1) + j] = f2bf(wv);
                }
            } else {
                void* outp = half ? Cv1 : Cv;
#pragma unroll
                for (int i = 0; i < 4; i++) {
                    if (EPI == 1)
                        ((short*)outp)[(size_t)(row + i) * N + col] = f2bf(acc[m][n][i]);
                    else
                        ((float*)outp)[(size_t)(row + i) * N + col] = acc[m][n][i];
                }
            }
        }
}

// ---------- flash attention (causal), static-max softmax, balanced pair split ----------
// R20: QBLK 256->128 (8 waves x 16 q-rows) -> grid 512 = 2 blocks/CU = 4 waves/SIMD
// (was 1 block/CU = 2 waves/SIMD; attacks barrier-drain with cross-block overlap).
// Pieces (qb in [0,16), hf in {0,1}); pairing (pslot,0)+(15-pslot,1) = 17 tiles/block.
// bid: xcd=bid&7, idx=bid>>3; bhg = xcd + 8*(idx>>4); pslot = idx&15.
__launch_bounds__(512)
__global__ void k_attn(const short* __restrict__ qn, const short* __restrict__ kn,
                       const short* __restrict__ vt, short* __restrict__ opart,
                       float* __restrict__ lsump) {
    __shared__ __align__(16) short Ks[2][64 * 64];
    __shared__ __align__(16) short Vs[2][64 * 64];
    __shared__ __align__(16) short Ps[8][16 * 64];
    const int t = threadIdx.x;
    const int w = t >> 6, lane = t & 63;
    const int bid = blockIdx.x;
    const int xcd = bid & 7, idx = bid >> 3;
    const int bhg = xcd + ((idx >> 4) << 3);          // 0..31
    const int pslot = idx & 15;
    const int h = bhg & 15, b = bhg >> 4;
    const int bh = b * 16 + h;
    const int lr = lane & 15, lg = lane >> 4;
    const short* Qb = qn + (size_t)bh * 2048 * 64;
    const short* Kb = kn + (size_t)bh * 2048 * 64;
    const short* Vb = vt + (size_t)bh * 64 * 2048;
    char* pwc = (char*)&Ps[w][0];

#define STAGE_KV(bi, kbase)                                                          \
    {                                                                                \
        int row = w * 8 + (lane >> 3);                                               \
        int scol = (lane & 7) ^ (row & 7);                                           \
        gload16(Kb + (size_t)((kbase) + row) * 64 + scol * 8,                        \
                &Ks[bi][(w * 8) * 64]);                                              \
        gload16(Vb + (size_t)row * 2048 + (kbase) + scol * 8,                        \
                &Vs[bi][(w * 8) * 64]);                                              \
    }

    for (int pc = 0; pc < 2; pc++) {
        const int qb = pc == 0 ? pslot : 15 - pslot;
        const int hf = pc;
        const int ktn = qb + 1;
        const int kt0 = hf * ktn, kt1 = kt0 + ktn;
        const int qw = qb * 128 + w * 16;

        bf16x8 qf[2];
#pragma unroll
        for (int kk = 0; kk < 2; kk++)
            qf[kk] = *(const bf16x8*)&Qb[(size_t)(qw + lr) * 64 + kk * 32 + lg * 8];

        f32x4 oacc[4];
#pragma unroll
        for (int ct = 0; ct < 4; ct++) oacc[ct] = (f32x4){0.f, 0.f, 0.f, 0.f};
        float psum[4] = {0.f, 0.f, 0.f, 0.f};

        if (pc) __syncthreads();          // all waves done with piece-0 LDS
        STAGE_KV(0, kt0 << 6);

        for (int kt = kt0; kt < kt1; kt++) {
            const int kbase = kt << 6;
            const int cur = (kt - kt0) & 1;
            __syncthreads();
            if (kt + 1 < kt1) STAGE_KV(cur ^ 1, (kt + 1) << 6);

            bf16x8 kf[4][2];
#pragma unroll
            for (int ni = 0; ni < 4; ni++)
#pragma unroll
                for (int kk = 0; kk < 2; kk++) {
                    int row = ni * 16 + lr;
                    kf[ni][kk] = *(const bf16x8*)&Ks[cur][row * 64 + (((kk * 4 + lg) ^ (row & 7)) << 3)];
                }
            f32x4 sv[4];
#pragma unroll
            for (int ni = 0; ni < 4; ni++) {
                f32x4 s = (f32x4){0.f, 0.f, 0.f, 0.f};
                s = mfma16(qf[0], kf[ni][0], s);
                s = mfma16(qf[1], kf[ni][1], s);
                sv[ni] = s;
            }
            if (kbase + 63 > qw) {
#pragma unroll
                for (int ni = 0; ni < 4; ni++)
#pragma unroll
                    for (int i = 0; i < 4; i++) {
                        int qg = qw + lg * 4 + i;
                        int kg = kbase + ni * 16 + lr;
                        if (kg > qg) sv[ni][i] = -3.0e38f;
                    }
            }
#pragma unroll
            for (int ni = 0; ni < 4; ni++)
#pragma unroll
                for (int i = 0; i < 4; i++) {
                    float p = exp2f((sv[ni][i] - 9.0f) * 1.44269504f);
                    sv[ni][i] = p;
                    psum[i] += p;
                }
#pragma unroll
            for (int ni = 0; ni < 4; ni++)
#pragma unroll
                for (int i = 0; i < 4; i++) {
                    int row = lg * 4 + i;
                    int col = ni * 16 + lr;
                    unsigned off = (unsigned)(row * 128 + col * 2) ^ ((unsigned)(row & 7) << 4);
                    *(short*)(pwc + off) = f2bf(sv[ni][i]);
                }
            bf16x8 pa[2];
#pragma unroll
            for (int kk = 0; kk < 2; kk++) {
                unsigned off = (unsigned)(lr * 128 + kk * 64 + lg * 16) ^ ((unsigned)(lr & 7) << 4);
                pa[kk] = *(const bf16x8*)(pwc + off);
            }
            bf16x8 vf[4][2];
#pragma unroll
            for (int ct = 0; ct < 4; ct++)
#pragma unroll
                for (int kk = 0; kk < 2; kk++) {
                    int row = ct * 16 + lr;
                    vf[ct][kk] = *(const bf16x8*)&Vs[cur][row * 64 + (((kk * 4 + lg) ^ (row & 7)) << 3)];
                }
#pragma unroll
            for (int ct = 0; ct < 4; ct++) {
                oacc[ct] = mfma16(pa[0], vf[ct][0], oacc[ct]);
                oacc[ct] = mfma16(pa[1], vf[ct][1], oacc[ct]);
            }
        }

#pragma unroll
        for (int o = 1; o < 16; o <<= 1)
#pragma unroll
            for (int i = 0; i < 4; i++)
                psum[i] += __shfl_xor(psum[i], o, 64);

        short* aob = opart + (size_t)hf * 4096 * 1024 + ((size_t)(b * 2048 + qw) * 1024) + h * 64;
#pragma unroll
        for (int ct = 0; ct < 4; ct++)
#pragma unroll
            for (int i = 0; i < 4; i++) {
                int q = lg * 4 + i;
                aob[(size_t)q * 1024 + ct * 16 + lr] = f2bf(oacc[ct][i]);
            }
        if (lr == 0) {
#pragma unroll
            for (int i = 0; i < 4; i++)
                lsump[hf * 65536 + bh * 2048 + qw + lg * 4 + i] = psum[i];
        }
    }
#undef STAGE_KV
}

// ---------- combine split-K partials: ao = (O0+O1)/(l0+l1), bf16 ----------
__global__ void k_comb(const short* __restrict__ op, const float* __restrict__ ls,
                       short* __restrict__ ao) {
    int i = (blockIdx.x * 256 + threadIdx.x) * 4;
    int row = i >> 10, col = i & 1023;
    int idx = ((row >> 11) * 16 + (col >> 6)) * 2048 + (row & 2047);
    float rl = 1.0f / (ls[idx] + ls[65536 + idx]);
    short4 a = *(const short4*)(op + i);
    short4 c = *(const short4*)(op + 4194304 + i);
    short4 o;
    o.x = f2bf((bf2f(a.x) + bf2f(c.x)) * rl);
    o.y = f2bf((bf2f(a.y) + bf2f(c.y)) * rl);
    o.z = f2bf((bf2f(a.z) + bf2f(c.z)) * rl);
    o.w = f2bf((bf2f(a.w) + bf2f(c.w)) * rl);
    *(short4*)(ao + i) = o;
}

// ---------- residual + double cosine_norm; pre = pre0 + pre1 (bf16 partials) ----------
__global__ void k_resnorm(const float* base, const short* __restrict__ pre0,
                          const short* __restrict__ pre1,
                          const float* __restrict__ alpha, float* outf,
                          short* __restrict__ outb) {
    __shared__ float red1[4], red2[4];
    int row = blockIdx.x;
    int t = threadIdx.x;
    int w = t >> 6;
    float4 p;
    short4 a = *(const short4*)(pre0 + (size_t)row * 1024 + t * 4);
    short4 c = *(const short4*)(pre1 + (size_t)row * 1024 + t * 4);
    p.x = bf2f(a.x) + bf2f(c.x); p.y = bf2f(a.y) + bf2f(c.y);
    p.z = bf2f(a.z) + bf2f(c.z); p.w = bf2f(a.w) + bf2f(c.w);
    float ss = p.x * p.x + p.y * p.y + p.z * p.z + p.w * p.w;
#pragma unroll
    for (int o = 1; o < 64; o <<= 1) ss += __shfl_xor(ss, o, 64);
    if ((t & 63) == 0) red1[w] = ss;
    __syncthreads();
    float inv1 = 1.0f / fmaxf(sqrtf(red1[0] + red1[1] + red1[2] + red1[3]), 1e-6f);
    const float4 bx = *(const float4*)(base + (size_t)row * 1024 + t * 4);
    const float4 av = *(const float4*)(alpha + t * 4);
    float4 tm;
    tm.x = bx.x + av.x * (p.x * inv1 - bx.x);
    tm.y = bx.y + av.y * (p.y * inv1 - bx.y);
    tm.z = bx.z + av.z * (p.z * inv1 - bx.z);
    tm.w = bx.w + av.w * (p.w * inv1 - bx.w);
    float ss2 = tm.x * tm.x + tm.y * tm.y + tm.z * tm.z + tm.w * tm.w;
#pragma unroll
    for (int o = 1; o < 64; o <<= 1) ss2 += __shfl_xor(ss2, o, 64);
    if ((t & 63) == 0) red2[w] = ss2;
    __syncthreads();
    float inv2 = 1.0f / fmaxf(sqrtf(red2[0] + red2[1] + red2[2] + red2[3]), 1e-6f);
    float4 hv;
    hv.x = tm.x * inv2; hv.y = tm.y * inv2; hv.z = tm.z * inv2; hv.w = tm.w * inv2;
    if (outf) *(float4*)(outf + (size_t)row * 1024 + t * 4) = hv;
    if (outb) {
        short4 o4;
        o4.x = f2bf(hv.x); o4.y = f2bf(hv.y); o4.z = f2bf(hv.z); o4.w = f2bf(hv.w);
        *(short4*)(outb + (size_t)row * 1024 + t * 4) = o4;
    }
}

// ---------- launch ----------
// Workspace (lifetime-overlaid, peak ~75.9 MB; 76,152,832 known-safe):
//  [0, 25296896)  weights bf16^T                                     (whole launch)
//  25296896  cost/sint (prep->qkv) -> lsum 0.5MB (attn->comb)
//  25821184  xbf(prep->qkv) -> h1bf(rn1->swiglu)                               8 MB
//  34209792  qn(qkv->attn) -> ao(comb->wo) -> wmlp(swiglu->down, 22.5MB ..56754176)
//  42598400  kn(qkv->attn) -> hA0 bf16 8MB(wo->rn1)
//  50987008  vt(qkv->attn) -> hA1 bf16 8MB(wo->rn1)
//  59375616  opart[2] bf16 16MB(attn->comb) -> hM0 bf16 8MB(down->rn2)
//  67764224  hM1 bf16 8MB(down->rn2)
extern "C" void kernel_launch(void* const* d_in, const int* in_sizes, int n_in,
                              void* d_out, int out_size, void* d_ws, size_t ws_size,
                              hipStream_t stream) {
    (void)in_sizes; (void)n_in; (void)out_size; (void)ws_size;
    const float* x   = (const float*)d_in[0];
    const float* Wq  = (const float*)d_in[1];
    const float* Wk  = (const float*)d_in[2];
    const float* Wv  = (const float*)d_in[3];
    const float* Wo  = (const float*)d_in[4];
    const float* sqk = (const float*)d_in[5];
    const float* aA  = (const float*)d_in[6];
    const float* Wup = (const float*)d_in[7];
    const float* Wg  = (const float*)d_in[8];
    const float* Wd  = (const float*)d_in[9];
    const float* su  = (const float*)d_in[10];
    const float* sv  = (const float*)d_in[11];
    const float* aM  = (const float*)d_in[12];

    char* ws = (char*)d_ws;
    short* wqkvT  = (short*)(ws + 0);          // [3072][1024]
    short* woT    = (short*)(ws + 6291456);    // [1024][1024]
    short* wugT   = (short*)(ws + 8388608);    // [5504][1024] interleaved up/gate
    short* wdownT = (short*)(ws + 19660800);   // [1024][2752]
    float* cost   = (float*)(ws + 25296896);
    float* sint   = (float*)(ws + 25559040);
    short* xbf    = (short*)(ws + 25821184);
    short* qn     = (short*)(ws + 34209792);
    short* kn     = (short*)(ws + 42598400);
    short* vt     = (short*)(ws + 50987008);   // [B][H][64][2048] bf16, 8MB
    short* opart  = (short*)(ws + 59375616);   // [2][4096][1024] bf16
    float* lsum   = (float*)(ws + 25296896);   // overwrites cost/sint (dead after qkv)
    short* ao     = (short*)(ws + 34209792);   // reuse qn
    short* hA0    = (short*)(ws + 42598400);   // reuse kn, bf16 8MB
    short* hA1    = (short*)(ws + 50987008);   // reuse vt, bf16 8MB
    float* h1f    = (float*)d_out;
    short* h1bf   = (short*)(ws + 25821184);   // reuse xbf
    short* wmlp   = (short*)(ws + 34209792);   // [4096][2752] bf16
    short* hM0    = (short*)(ws + 59375616);   // bf16 8MB (opart dead)
    short* hM1    = (short*)(ws + 67764224);   // bf16 8MB

    k_prep<<<16704, 256, 0, stream>>>(x, xbf, cost, sint, Wq, Wk, Wv, Wo, Wup, Wg, Wd,
                                      wqkvT, woT, wugT, wdownT);

    // QKV GEMM with fused rope + cosine-norm epilogue; v written directly transposed
    k_gemm128<3><<<768, 256, 0, stream>>>(xbf, wqkvT, nullptr, nullptr, 4096, 3072, 1024,
                                          16, 1, nullptr, nullptr, cost, sint, sqk, qn, kn, vt);
    k_attn<<<512, 512, 0, stream>>>(qn, kn, vt, opart, lsum);
    k_comb<<<4096, 256, 0, stream>>>(opart, lsum, ao);
    // Wo: split-K x2 (8+8 tiles), bf16 partials
    k_gemm128<1><<<512, 256, 0, stream>>>(ao, woT, hA0, hA1, 4096, 1024, 1024,
                                          8, 2, nullptr, nullptr, nullptr, nullptr, nullptr,
                                          nullptr, nullptr, nullptr);
    k_resnorm<<<4096, 256, 0, stream>>>(x, hA0, hA1, aA, h1f, h1bf);
    // up+gate fused SwiGLU
    k_gemm128<2><<<1376, 256, 0, stream>>>(h1bf, wugT, wmlp, nullptr, 4096, 5504, 1024,
                                           16, 1, su, sv, nullptr, nullptr, nullptr,
                                           nullptr, nullptr, nullptr);
    // down: split-K x2 (22+21 tiles), bf16 partials
    k_gemm128<1><<<512, 256, 0, stream>>>(wmlp, wdownT, hM0, hM1, 4096, 1024, 2752,
                                          22, 2, nullptr, nullptr, nullptr, nullptr, nullptr,
                                          nullptr, nullptr, nullptr);
    k_resnorm<<<4096, 256, 0, stream>>>(h1f, hM0, hM1, aM, (float*)d_out, (short*)nullptr);
}

// Round 21
// 231.996 us; speedup vs baseline: 1.2633x; 1.0006x over previous
//
#include <hip/hip_runtime.h>
#include <math.h>

#define DEVI __device__ __forceinline__

typedef __attribute__((ext_vector_type(4))) float f32x4;
typedef __attribute__((ext_vector_type(8))) short bf16x8;

// ---------- helpers ----------
DEVI short f2bf(float f) {                    // f32 -> bf16 (RNE)
    union { float f; unsigned u; } v; v.f = f;
    unsigned r = v.u + 0x7fffu + ((v.u >> 16) & 1u);
    return (short)(r >> 16);
}
DEVI float bf2f(short s) {
    union { unsigned u; float f; } v; v.u = ((unsigned)(unsigned short)s) << 16;
    return v.f;
}

DEVI f32x4 mfma16(bf16x8 a, bf16x8 b, f32x4 c) {
    return __builtin_amdgcn_mfma_f32_16x16x32_bf16(a, b, c, 0, 0, 0);
}

DEVI void gload16(const short* g, short* l) {  // async global->LDS, 16B/lane
    __builtin_amdgcn_global_load_lds((__attribute__((address_space(1))) void*)(g),
                                     (__attribute__((address_space(3))) void*)(l),
                                     16, 0, 0);
}

// ---------- merged preprocessing: cvt + freqs + all 7 weight transposes ----------
DEVI void trans_tile(const float* in, short* out, int R, int C, int Rpad, int Cpad,
                     int rmul, int radd, int bx, int by) {
    __shared__ float tile[32][33];
    int c0 = bx * 32, r0 = by * 32;
    int tx = threadIdx.x & 31, ty = threadIdx.x >> 5;
#pragma unroll
    for (int i = 0; i < 4; i++) {
        int r = r0 + ty + 8 * i, c = c0 + tx;
        tile[ty + 8 * i][tx] = (r < R && c < C) ? in[(size_t)r * C + c] : 0.0f;
    }
    __syncthreads();
#pragma unroll
    for (int i = 0; i < 4; i++) {
        int oc = c0 + ty + 8 * i;
        int orr = r0 + tx;
        if (oc < Cpad && orr < Rpad)
            out[(size_t)(oc * rmul + radd) * Rpad + orr] = f2bf(tile[tx][ty + 8 * i]);
    }
}

__global__ void k_prep(const float* __restrict__ x, short* __restrict__ xbf,
                       float* __restrict__ cost, float* __restrict__ sint,
                       const float* __restrict__ Wq, const float* __restrict__ Wk,
                       const float* __restrict__ Wv, const float* __restrict__ Wo,
                       const float* __restrict__ Wup, const float* __restrict__ Wg,
                       const float* __restrict__ Wd,
                       short* __restrict__ wqkvT, short* __restrict__ woT,
                       short* __restrict__ wugT, short* __restrict__ wdownT) {
    int b = blockIdx.x;
    if (b < 4096) {                         // x f32 -> bf16
        int i = (b * 256 + threadIdx.x) * 4;
        float4 v = *(const float4*)(x + i);
        short4 o;
        o.x = f2bf(v.x); o.y = f2bf(v.y); o.z = f2bf(v.z); o.w = f2bf(v.w);
        *(short4*)(xbf + i) = o;
    } else if (b < 4352) {                  // rope tables (f64 fidelity)
        int i = (b - 4096) * 256 + threadIdx.x;
        int s = i >> 5, j = i & 31;
        double inv = pow(10000.0, -(double)j / 32.0);
        double f = (double)s * inv;
        cost[i] = (float)cos(f);
        sint[i] = (float)sin(f);
    } else {
        int bb = b - 4352;
        if (bb < 4096) {                    // Wq/Wk/Wv/Wo
            int seg = bb >> 10, idx = bb & 1023;
            const float* in = seg == 0 ? Wq : seg == 1 ? Wk : seg == 2 ? Wv : Wo;
            short* out = seg == 0 ? wqkvT : seg == 1 ? wqkvT + 1048576
                       : seg == 2 ? wqkvT + 2097152 : woT;
            trans_tile(in, out, 1024, 1024, 1024, 1024, 1, 0, idx & 31, idx >> 5);
        } else if (bb < 9600) {             // Wup/Wg -> interleaved [5504][1024]
            int idx = bb - 4096;
            int seg = idx >= 2752;
            idx -= seg * 2752;
            trans_tile(seg ? Wg : Wup, wugT, 1024, 2730, 1024, 2752, 2, seg, idx % 86, idx / 86);
        } else {                            // Wd -> [1024][2752]
            int idx = bb - 9600;
            trans_tile(Wd, wdownT, 2730, 1024, 2752, 1024, 1, 0, idx & 31, idx >> 5);
        }
    }
}

// ---------- GEMM 128x128xBK64, single-buffer 32KB LDS, bank-swizzled, XCD-chunked, split-K ----
// BK=64, one barrier pair per K-tile, two K=32 MFMA sub-steps; swizzle c^(r&7) both-sides;
// hoisted frag-read bases; __launch_bounds__(256,4) -> 4 waves/SIMD. (Engine frozen at
// R18/R19 plateau: MfmaUtil ~27%, barrier-drain structural.)
// EPI: 0 f32, 1 bf16 (honor split -> Cv1), 2 SwiGLU-interleaved, 3 fused QKV epilogue.
template <int EPI>
__launch_bounds__(256, 4)
__global__ void k_gemm128(const short* __restrict__ A, const short* __restrict__ BT,
                          void* __restrict__ Cv, void* __restrict__ Cv1,
                          int M, int N, int K, int nkblk, int nsplit,
                          const float* __restrict__ s_u, const float* __restrict__ s_v,
                          const float* __restrict__ cost, const float* __restrict__ sint,
                          const float* __restrict__ sqk,
                          short* __restrict__ qn, short* __restrict__ kn,
                          short* __restrict__ vtout) {
    __shared__ __align__(16) short As[128 * 64];
    __shared__ __align__(16) short Bs[128 * 64];
    const int t = threadIdx.x;
    const int w = t >> 6;
    const int lane = t & 63;
    const int lr = lane & 15, lg = lane >> 4;
    const int nwg = (int)gridDim.x;
    int wg = ((int)blockIdx.x & 7) * (nwg >> 3) + ((int)blockIdx.x >> 3);
    int half = 0;
    if (nsplit == 2) {
        const int per = nwg >> 1;
        half = wg >= per;
        wg -= half * per;
    }
    const int MT = M >> 7;
    const int m0 = (wg % MT) << 7;
    const int n0 = (wg / MT) << 7;
    const int koff = half * nkblk * 64;
    const int ntile = (nsplit == 2 && half) ? (K >> 6) - nkblk : nkblk;
    const int wr = (w >> 1) * 64, wc = (w & 1) * 64;

    const int srow = t >> 3;
    const int scol = (((t & 7) ^ (srow & 7)) << 3);
    const short* Ap = A + (size_t)(m0 + srow) * K + koff + scol;
    const short* Bp = BT + (size_t)(n0 + srow) * K + koff + scol;
    const size_t rstep = (size_t)32 * K;
    const int dW = (w * 8) * 64;

    const int ca = (wr + lr) & 7;
    const int cb = (wc + lr) & 7;
    const short* pa0 = &As[(wr + lr) * 64 + (((0 + lg) ^ ca) << 3)];
    const short* pa1 = &As[(wr + lr) * 64 + (((4 + lg) ^ ca) << 3)];
    const short* pb0 = &Bs[(wc + lr) * 64 + (((0 + lg) ^ cb) << 3)];
    const short* pb1 = &Bs[(wc + lr) * 64 + (((4 + lg) ^ cb) << 3)];

    f32x4 acc[4][4];
#pragma unroll
    for (int m = 0; m < 4; m++)
#pragma unroll
        for (int n = 0; n < 4; n++)
            acc[m][n] = (f32x4){0.f, 0.f, 0.f, 0.f};

    for (int kt = 0; kt < ntile; kt++) {
        if (kt) __syncthreads();
#pragma unroll
        for (int j = 0; j < 4; j++) {
            gload16(Ap + j * rstep, As + dW + j * 2048);
            gload16(Bp + j * rstep, Bs + dW + j * 2048);
        }
        Ap += 64; Bp += 64;
        __syncthreads();
#pragma unroll
        for (int ks = 0; ks < 2; ks++) {
            const short* pa = ks ? pa1 : pa0;
            const short* pb = ks ? pb1 : pb0;
            bf16x8 af[4], bfr[4];
#pragma unroll
            for (int m = 0; m < 4; m++)
                af[m] = *(const bf16x8*)(pa + m * 1024);
#pragma unroll
            for (int n = 0; n < 4; n++)
                bfr[n] = *(const bf16x8*)(pb + n * 1024);
#pragma unroll
            for (int m = 0; m < 4; m++)
#pragma unroll
                for (int n = 0; n < 4; n++)
                    acc[m][n] = mfma16(af[m], bfr[n], acc[m][n]);
        }
    }

    if (EPI == 3) {
        const int sector = n0 >> 10;     // 0=q, 1=k, 2=v
        if (sector == 2) {
#pragma unroll
            for (int m = 0; m < 4; m++)
#pragma unroll
                for (int n = 0; n < 4; n++) {
                    int col = n0 + wc + n * 16 + lr - 2048;
                    int hh = col >> 6, d = col & 63;
                    int brow = m0 + wr + m * 16 + lg * 4;
                    int bb = brow >> 11, s = brow & 2047;
                    short4 o4;
                    o4.x = f2bf(acc[m][n][0]); o4.y = f2bf(acc[m][n][1]);
                    o4.z = f2bf(acc[m][n][2]); o4.w = f2bf(acc[m][n][3]);
                    *(short4*)&vtout[((size_t)((bb * 16 + hh) * 64 + d)) * 2048 + s] = o4;
                }
        } else {
            const int h = ((n0 + wc) >> 6) & 15;
            float eff[4];
#pragma unroll
            for (int n = 0; n < 4; n++)
                eff[n] = sqk[h * 64 + n * 16 + lr] * 32.0f;   // s_qk * sqrt(DIM)
            short* dst = (sector == 0) ? qn : kn;
            const float extra = (sector == 0) ? 8.0f : 1.0f;  // sqrt(HD) folded into q
#pragma unroll
            for (int m = 0; m < 4; m++)
#pragma unroll
                for (int i = 0; i < 4; i++) {
                    int row = m0 + wr + m * 16 + lg * 4 + i;
                    int b = row >> 11, s = row & 2047;
                    float cs0 = cost[s * 32 + lr],      sn0 = sint[s * 32 + lr];
                    float cs1 = cost[s * 32 + 16 + lr], sn1 = sint[s * 32 + 16 + lr];
                    float vr0 = acc[m][0][i] * cs0 - acc[m][2][i] * sn0;
                    float vr1 = acc[m][1][i] * cs1 - acc[m][3][i] * sn1;
                    float vr2 = acc[m][2][i] * cs0 + acc[m][0][i] * sn0;
                    float vr3 = acc[m][3][i] * cs1 + acc[m][1][i] * sn1;
                    float ss = vr0 * vr0 + vr1 * vr1 + vr2 * vr2 + vr3 * vr3;
#pragma unroll
                    for (int o = 1; o < 16; o <<= 1)
                        ss += __shfl_xor(ss, o, 64);
                    float sc = extra / fmaxf(sqrtf(ss), 1e-6f);
                    size_t base = ((size_t)(b * 16 + h) * 2048 + s) * 64;
                    dst[base + lr]      = f2bf(vr0 * eff[0] * sc);
                    dst[base + 16 + lr] = f2bf(vr1 * eff[1] * sc);
                    dst[base + 32 + lr] = f2bf(vr2 * eff[2] * sc);
                    dst[base + 48 + lr] = f2bf(vr3 * eff[3] * sc);
                }
        }
        return;
    }

#pragma unroll
    for (int m = 0; m < 4; m++)
#pragma unroll
        for (int n = 0; n < 4; n++) {
            int row = m0 + wr + m * 16 + lg * 4;
            int col = n0 + wc + n * 16 + lr;
            if (EPI == 2) {
                int j = col >> 1;
                int jc = j < 2730 ? j : 2729;
                float su = s_u[jc];
                float sg = s_v[jc] * 32.0f;
#pragma unroll
                for (int i = 0; i < 4; i++) {
                    float own = acc[m][n][i];
                    float oth = __shfl_xor(own, 1, 64);
                    float u = (lr & 1) ? oth : own;
                    float g = (lr & 1) ? own : oth;
                    float uu = u * su;
                    float vv = g * sg;
                    float wv = uu * vv / (1.0f + expf(-vv));
                    if (!(lr & 1))
                        ((short*)Cv)[(size_t)(row + i) * (N >> 1) + j] = f2bf(wv);
                }
            } else {
                void* outp = half ? Cv1 : Cv;
#pragma unroll
                for (int i = 0; i < 4; i++) {
                    if (EPI == 1)
                        ((short*)outp)[(size_t)(row + i) * N + col] = f2bf(acc[m][n][i]);
                    else
                        ((float*)outp)[(size_t)(row + i) * N + col] = acc[m][n][i];
                }
            }
        }
}

// ---------- flash attention (causal), static-max softmax, balanced pair split ----------
// R20: QBLK 256->128 (8 waves x 16 q-rows) -> grid 512 = 2 blocks/CU = 4 waves/SIMD
// (was 1 block/CU = 2 waves/SIMD; attacks barrier-drain with cross-block overlap).
// Pieces (qb in [0,16), hf in {0,1}); pairing (pslot,0)+(15-pslot,1) = 17 tiles/block.
// bid: xcd=bid&7, idx=bid>>3; bhg = xcd + 8*(idx>>4); pslot = idx&15.
__launch_bounds__(512)
__global__ void k_attn(const short* __restrict__ qn, const short* __restrict__ kn,
                       const short* __restrict__ vt, short* __restrict__ opart,
                       float* __restrict__ lsump) {
    __shared__ __align__(16) short Ks[2][64 * 64];
    __shared__ __align__(16) short Vs[2][64 * 64];
    __shared__ __align__(16) short Ps[8][16 * 64];
    const int t = threadIdx.x;
    const int w = t >> 6, lane = t & 63;
    const int bid = blockIdx.x;
    const int xcd = bid & 7, idx = bid >> 3;
    const int bhg = xcd + ((idx >> 4) << 3);          // 0..31
    const int pslot = idx & 15;
    const int h = bhg & 15, b = bhg >> 4;
    const int bh = b * 16 + h;
    const int lr = lane & 15, lg = lane >> 4;
    const short* Qb = qn + (size_t)bh * 2048 * 64;
    const short* Kb = kn + (size_t)bh * 2048 * 64;
    const short* Vb = vt + (size_t)bh * 64 * 2048;
    char* pwc = (char*)&Ps[w][0];

#define STAGE_KV(bi, kbase)                                                          \
    {                                                                                \
        int row = w * 8 + (lane >> 3);                                               \
        int scol = (lane & 7) ^ (row & 7);                                           \
        gload16(Kb + (size_t)((kbase) + row) * 64 + scol * 8,                        \
                &Ks[bi][(w * 8) * 64]);                                              \
        gload16(Vb + (size_t)row * 2048 + (kbase) + scol * 8,                        \
                &Vs[bi][(w * 8) * 64]);                                              \
    }

    for (int pc = 0; pc < 2; pc++) {
        const int qb = pc == 0 ? pslot : 15 - pslot;
        const int hf = pc;
        const int ktn = qb + 1;
        const int kt0 = hf * ktn, kt1 = kt0 + ktn;
        const int qw = qb * 128 + w * 16;

        bf16x8 qf[2];
#pragma unroll
        for (int kk = 0; kk < 2; kk++)
            qf[kk] = *(const bf16x8*)&Qb[(size_t)(qw + lr) * 64 + kk * 32 + lg * 8];

        f32x4 oacc[4];
#pragma unroll
        for (int ct = 0; ct < 4; ct++) oacc[ct] = (f32x4){0.f, 0.f, 0.f, 0.f};
        float psum[4] = {0.f, 0.f, 0.f, 0.f};

        if (pc) __syncthreads();          // all waves done with piece-0 LDS
        STAGE_KV(0, kt0 << 6);

        for (int kt = kt0; kt < kt1; kt++) {
            const int kbase = kt << 6;
            const int cur = (kt - kt0) & 1;
            __syncthreads();
            if (kt + 1 < kt1) STAGE_KV(cur ^ 1, (kt + 1) << 6);

            bf16x8 kf[4][2];
#pragma unroll
            for (int ni = 0; ni < 4; ni++)
#pragma unroll
                for (int kk = 0; kk < 2; kk++) {
                    int row = ni * 16 + lr;
                    kf[ni][kk] = *(const bf16x8*)&Ks[cur][row * 64 + (((kk * 4 + lg) ^ (row & 7)) << 3)];
                }
            f32x4 sv[4];
#pragma unroll
            for (int ni = 0; ni < 4; ni++) {
                f32x4 s = (f32x4){0.f, 0.f, 0.f, 0.f};
                s = mfma16(qf[0], kf[ni][0], s);
                s = mfma16(qf[1], kf[ni][1], s);
                sv[ni] = s;
            }
            if (kbase + 63 > qw) {
#pragma unroll
                for (int ni = 0; ni < 4; ni++)
#pragma unroll
                    for (int i = 0; i < 4; i++) {
                        int qg = qw + lg * 4 + i;
                        int kg = kbase + ni * 16 + lr;
                        if (kg > qg) sv[ni][i] = -3.0e38f;
                    }
            }
#pragma unroll
            for (int ni = 0; ni < 4; ni++)
#pragma unroll
                for (int i = 0; i < 4; i++) {
                    float p = exp2f((sv[ni][i] - 9.0f) * 1.44269504f);
                    sv[ni][i] = p;
                    psum[i] += p;
                }
#pragma unroll
            for (int ni = 0; ni < 4; ni++)
#pragma unroll
                for (int i = 0; i < 4; i++) {
                    int row = lg * 4 + i;
                    int col = ni * 16 + lr;
                    unsigned off = (unsigned)(row * 128 + col * 2) ^ ((unsigned)(row & 7) << 4);
                    *(short*)(pwc + off) = f2bf(sv[ni][i]);
                }
            bf16x8 pa[2];
#pragma unroll
            for (int kk = 0; kk < 2; kk++) {
                unsigned off = (unsigned)(lr * 128 + kk * 64 + lg * 16) ^ ((unsigned)(lr & 7) << 4);
                pa[kk] = *(const bf16x8*)(pwc + off);
            }
            bf16x8 vf[4][2];
#pragma unroll
            for (int ct = 0; ct < 4; ct++)
#pragma unroll
                for (int kk = 0; kk < 2; kk++) {
                    int row = ct * 16 + lr;
                    vf[ct][kk] = *(const bf16x8*)&Vs[cur][row * 64 + (((kk * 4 + lg) ^ (row & 7)) << 3)];
                }
#pragma unroll
            for (int ct = 0; ct < 4; ct++) {
                oacc[ct] = mfma16(pa[0], vf[ct][0], oacc[ct]);
                oacc[ct] = mfma16(pa[1], vf[ct][1], oacc[ct]);
            }
        }

#pragma unroll
        for (int o = 1; o < 16; o <<= 1)
#pragma unroll
            for (int i = 0; i < 4; i++)
                psum[i] += __shfl_xor(psum[i], o, 64);

        short* aob = opart + (size_t)hf * 4096 * 1024 + ((size_t)(b * 2048 + qw) * 1024) + h * 64;
#pragma unroll
        for (int ct = 0; ct < 4; ct++)
#pragma unroll
            for (int i = 0; i < 4; i++) {
                int q = lg * 4 + i;
                aob[(size_t)q * 1024 + ct * 16 + lr] = f2bf(oacc[ct][i]);
            }
        if (lr == 0) {
#pragma unroll
            for (int i = 0; i < 4; i++)
                lsump[hf * 65536 + bh * 2048 + qw + lg * 4 + i] = psum[i];
        }
    }
#undef STAGE_KV
}

// ---------- combine split-K partials: ao = (O0+O1)/(l0+l1), bf16 ----------
__global__ void k_comb(const short* __restrict__ op, const float* __restrict__ ls,
                       short* __restrict__ ao) {
    int i = (blockIdx.x * 256 + threadIdx.x) * 4;
    int row = i >> 10, col = i & 1023;
    int idx = ((row >> 11) * 16 + (col >> 6)) * 2048 + (row & 2047);
    float rl = 1.0f / (ls[idx] + ls[65536 + idx]);
    short4 a = *(const short4*)(op + i);
    short4 c = *(const short4*)(op + 4194304 + i);
    short4 o;
    o.x = f2bf((bf2f(a.x) + bf2f(c.x)) * rl);
    o.y = f2bf((bf2f(a.y) + bf2f(c.y)) * rl);
    o.z = f2bf((bf2f(a.z) + bf2f(c.z)) * rl);
    o.w = f2bf((bf2f(a.w) + bf2f(c.w)) * rl);
    *(short4*)(ao + i) = o;
}

// ---------- residual + double cosine_norm; pre = pre0 + pre1 (bf16 partials) ----------
__global__ void k_resnorm(const float* base, const short* __restrict__ pre0,
                          const short* __restrict__ pre1,
                          const float* __restrict__ alpha, float* outf,
                          short* __restrict__ outb) {
    __shared__ float red1[4], red2[4];
    int row = blockIdx.x;
    int t = threadIdx.x;
    int w = t >> 6;
    float4 p;
    short4 a = *(const short4*)(pre0 + (size_t)row * 1024 + t * 4);
    short4 c = *(const short4*)(pre1 + (size_t)row * 1024 + t * 4);
    p.x = bf2f(a.x) + bf2f(c.x); p.y = bf2f(a.y) + bf2f(c.y);
    p.z = bf2f(a.z) + bf2f(c.z); p.w = bf2f(a.w) + bf2f(c.w);
    float ss = p.x * p.x + p.y * p.y + p.z * p.z + p.w * p.w;
#pragma unroll
    for (int o = 1; o < 64; o <<= 1) ss += __shfl_xor(ss, o, 64);
    if ((t & 63) == 0) red1[w] = ss;
    __syncthreads();
    float inv1 = 1.0f / fmaxf(sqrtf(red1[0] + red1[1] + red1[2] + red1[3]), 1e-6f);
    const float4 bx = *(const float4*)(base + (size_t)row * 1024 + t * 4);
    const float4 av = *(const float4*)(alpha + t * 4);
    float4 tm;
    tm.x = bx.x + av.x * (p.x * inv1 - bx.x);
    tm.y = bx.y + av.y * (p.y * inv1 - bx.y);
    tm.z = bx.z + av.z * (p.z * inv1 - bx.z);
    tm.w = bx.w + av.w * (p.w * inv1 - bx.w);
    float ss2 = tm.x * tm.x + tm.y * tm.y + tm.z * tm.z + tm.w * tm.w;
#pragma unroll
    for (int o = 1; o < 64; o <<= 1) ss2 += __shfl_xor(ss2, o, 64);
    if ((t & 63) == 0) red2[w] = ss2;
    __syncthreads();
    float inv2 = 1.0f / fmaxf(sqrtf(red2[0] + red2[1] + red2[2] + red2[3]), 1e-6f);
    float4 hv;
    hv.x = tm.x * inv2; hv.y = tm.y * inv2; hv.z = tm.z * inv2; hv.w = tm.w * inv2;
    if (outf) *(float4*)(outf + (size_t)row * 1024 + t * 4) = hv;
    if (outb) {
        short4 o4;
        o4.x = f2bf(hv.x); o4.y = f2bf(hv.y); o4.z = f2bf(hv.z); o4.w = f2bf(hv.w);
        *(short4*)(outb + (size_t)row * 1024 + t * 4) = o4;
    }
}

// ---------- launch ----------
// Workspace (lifetime-overlaid, peak ~75.9 MB; 76,152,832 known-safe):
//  [0, 25296896)  weights bf16^T                                     (whole launch)
//  25296896  cost/sint (prep->qkv) -> lsum 0.5MB (attn->comb)
//  25821184  xbf(prep->qkv) -> h1bf(rn1->swiglu)                               8 MB
//  34209792  qn(qkv->attn) -> ao(comb->wo) -> wmlp(swiglu->down, 22.5MB ..56754176)
//  42598400  kn(qkv->attn) -> hA0 bf16 8MB(wo->rn1)
//  50987008  vt(qkv->attn) -> hA1 bf16 8MB(wo->rn1)
//  59375616  opart[2] bf16 16MB(attn->comb) -> hM0 bf16 8MB(down->rn2)
//  67764224  hM1 bf16 8MB(down->rn2)
extern "C" void kernel_launch(void* const* d_in, const int* in_sizes, int n_in,
                              void* d_out, int out_size, void* d_ws, size_t ws_size,
                              hipStream_t stream) {
    (void)in_sizes; (void)n_in; (void)out_size; (void)ws_size;
    const float* x   = (const float*)d_in[0];
    const float* Wq  = (const float*)d_in[1];
    const float* Wk  = (const float*)d_in[2];
    const float* Wv  = (const float*)d_in[3];
    const float* Wo  = (const float*)d_in[4];
    const float* sqk = (const float*)d_in[5];
    const float* aA  = (const float*)d_in[6];
    const float* Wup = (const float*)d_in[7];
    const float* Wg  = (const float*)d_in[8];
    const float* Wd  = (const float*)d_in[9];
    const float* su  = (const float*)d_in[10];
    const float* sv  = (const float*)d_in[11];
    const float* aM  = (const float*)d_in[12];

    char* ws = (char*)d_ws;
    short* wqkvT  = (short*)(ws + 0);          // [3072][1024]
    short* woT    = (short*)(ws + 6291456);    // [1024][1024]
    short* wugT   = (short*)(ws + 8388608);    // [5504][1024] interleaved up/gate
    short* wdownT = (short*)(ws + 19660800);   // [1024][2752]
    float* cost   = (float*)(ws + 25296896);
    float* sint   = (float*)(ws + 25559040);
    short* xbf    = (short*)(ws + 25821184);
    short* qn     = (short*)(ws + 34209792);
    short* kn     = (short*)(ws + 42598400);
    short* vt     = (short*)(ws + 50987008);   // [B][H][64][2048] bf16, 8MB
    short* opart  = (short*)(ws + 59375616);   // [2][4096][1024] bf16
    float* lsum   = (float*)(ws + 25296896);   // overwrites cost/sint (dead after qkv)
    short* ao     = (short*)(ws + 34209792);   // reuse qn
    short* hA0    = (short*)(ws + 42598400);   // reuse kn, bf16 8MB
    short* hA1    = (short*)(ws + 50987008);   // reuse vt, bf16 8MB
    float* h1f    = (float*)d_out;
    short* h1bf   = (short*)(ws + 25821184);   // reuse xbf
    short* wmlp   = (short*)(ws + 34209792);   // [4096][2752] bf16
    short* hM0    = (short*)(ws + 59375616);   // bf16 8MB (opart dead)
    short* hM1    = (short*)(ws + 67764224);   // bf16 8MB

    k_prep<<<16704, 256, 0, stream>>>(x, xbf, cost, sint, Wq, Wk, Wv, Wo, Wup, Wg, Wd,
                                      wqkvT, woT, wugT, wdownT);

    // QKV GEMM with fused rope + cosine-norm epilogue; v written directly transposed
    k_gemm128<3><<<768, 256, 0, stream>>>(xbf, wqkvT, nullptr, nullptr, 4096, 3072, 1024,
                                          16, 1, nullptr, nullptr, cost, sint, sqk, qn, kn, vt);
    k_attn<<<512, 512, 0, stream>>>(qn, kn, vt, opart, lsum);
    k_comb<<<4096, 256, 0, stream>>>(opart, lsum, ao);
    // Wo: split-K x2 (8+8 tiles), bf16 partials
    k_gemm128<1><<<512, 256, 0, stream>>>(ao, woT, hA0, hA1, 4096, 1024, 1024,
                                          8, 2, nullptr, nullptr, nullptr, nullptr, nullptr,
                                          nullptr, nullptr, nullptr);
    k_resnorm<<<4096, 256, 0, stream>>>(x, hA0, hA1, aA, h1f, h1bf);
    // up+gate fused SwiGLU
    k_gemm128<2><<<1376, 256, 0, stream>>>(h1bf, wugT, wmlp, nullptr, 4096, 5504, 1024,
                                           16, 1, su, sv, nullptr, nullptr, nullptr,
                                           nullptr, nullptr, nullptr);
    // down: split-K x2 (22+21 tiles), bf16 partials
    k_gemm128<1><<<512, 256, 0, stream>>>(wmlp, wdownT, hM0, hM1, 4096, 1024, 2752,
                                          22, 2, nullptr, nullptr, nullptr, nullptr, nullptr,
                                          nullptr, nullptr, nullptr);
    k_resnorm<<<4096, 256, 0, stream>>>(h1f, hM0, hM1, aM, (float*)d_out, (short*)nullptr);
}